// Round 5
// baseline (4961.726 us; speedup 1.0000x reference)
//
#include <hip/hip_runtime.h>
#include <math.h>

#define B_ 128
#define S_ 128
#define T_ 127
#define D_ 100
#define QN_ 4
#define SN_ 4
#define KC_ 4
#define RK_ 10
#define NEGV -1000000000.0f

__device__ __forceinline__ float sigmf(float x) { return 1.0f / (1.0f + expf(-x)); }

// ---------------------------------------------------------------------------
// Setup: transposed copies of W_ih1a, Wagg, W_last, W_key for coalesced
// matvecs; fold Er@W_ih1b + b_ih1 into erw; scalars.
// ---------------------------------------------------------------------------
__global__ __launch_bounds__(256) void setupk(
    const float* Er, const float* W_ih1, const float* b_ih1,
    const float* Wagg, const float* W_last, const float* W_key,
    const float* b_query, const float* W_W,
    float* wih1aT, float* erw, float* waggT, float* wlastT, float* wkeyT,
    float* scal)
{
  int gid = blockIdx.x * blockDim.x + threadIdx.x;
  int gsz = gridDim.x * blockDim.x;

  for (int x = gid; x < 30000; x += gsz) {
    int j = x / 300, i = x % 300;
    wih1aT[j * 300 + i] = W_ih1[i * 200 + j];
  }
  for (int x = gid; x < 600; x += gsz) {
    int r = x / 300, i = x % 300;
    float acc = b_ih1[i];
    for (int j = 0; j < 100; j++) acc += Er[r * 100 + j] * W_ih1[i * 200 + 100 + j];
    erw[x] = acc;
  }
  for (int x = gid; x < 30000; x += gsz) {
    int h = x / 10000, rr = x % 10000, j = rr / 100, i = rr % 100;
    waggT[h * 10000 + j * 100 + i] = Wagg[h * 10000 + i * 100 + j];
  }
  for (int x = gid; x < 10000; x += gsz) {
    int j = x / 100, i = x % 100;
    wlastT[j * 100 + i] = W_last[i * 100 + j];
    wkeyT[j * 100 + i] = W_key[i * 100 + j];
  }
  if (gid == 0) {
    float acc = 0.f;  // kw of the all-zero hist state: dot(tanh(b_query), Wk_part)
    for (int i = 0; i < 100; i++) acc += tanhf(b_query[i]) * W_W[100 + i];
    scal[0] = acc;
  }
}

// ---------------------------------------------------------------------------
// Phase A (unchanged from R4): per (b,t) 3-hop aggregate -> gi1[b,t,0:300]
// ---------------------------------------------------------------------------
__global__ __launch_bounds__(256) void phaseA(
    const float* Eq, const float* Ec, const int* question, const int* response, const int* mask,
    const int* qnb, const int* snb,
    const float* wih1aT, const float* erw, const float* waggT, const float* wlastT,
    const float* baggf, const float* blastf, float* gi1_all)
{
  const int t = blockIdx.x, b = blockIdx.y, tid = threadIdx.x;
  __shared__ float e0[100], ne0[100], e1[400], ne1[400];
  __shared__ float e2[1600], ne2[1600], m3[1600];
  __shared__ float sum4[400], sum1[100], emq[100];
  __shared__ int l1[4], l2[16], l3[64];

  const int qt = question[b * S_ + t];
  const int mt = mask[b * S_ + t];
  const int rt = response[b * S_ + t];

  if (mt != 0) {
    if (tid < 4) l1[tid] = qnb[qt * QN_ + tid];
    for (int x = tid; x < 100; x += 256) e0[x] = Eq[(size_t)qt * 100 + x];
    __syncthreads();
    if (tid < 16) l2[tid] = snb[l1[tid >> 2] * SN_ + (tid & 3)];
    for (int x = tid; x < 400; x += 256) e1[x] = Ec[(size_t)l1[x / 100] * 100 + (x % 100)];
    __syncthreads();
    if (tid < 64) l3[tid] = qnb[l2[tid >> 2] * QN_ + (tid & 3)];
    for (int x = tid; x < 1600; x += 256) e2[x] = Eq[(size_t)l2[x / 100] * 100 + (x % 100)];
    __syncthreads();
    for (int x = tid; x < 1600; x += 256) {
      int r = x / 100, j = x % 100;
      const int* lr = l3 + r * 4;
      float s = Ec[(size_t)lr[0] * 100 + j] + Ec[(size_t)lr[1] * 100 + j] +
                Ec[(size_t)lr[2] * 100 + j] + Ec[(size_t)lr[3] * 100 + j];
      m3[x] = e2[x] + 0.25f * s;
    }
    for (int x = tid; x < 100; x += 256)
      sum1[x] = e0[x] + 0.25f * (e1[x] + e1[100 + x] + e1[200 + x] + e1[300 + x]);
    for (int x = tid; x < 400; x += 256) {
      int k = x / 100, j = x % 100;
      const float* e2k = e2 + k * 400;
      sum4[x] = e1[x] + 0.25f * (e2k[j] + e2k[100 + j] + e2k[200 + j] + e2k[300 + j]);
    }
    __syncthreads();
    for (int o = tid; o < 2100; o += 256) {
      const float *in, *W;
      float bia;
      float* dst;
      int i = o % 100;
      if (o < 100)      { in = sum1;                           W = waggT;          bia = baggf[i];       dst = ne0 + o; }
      else if (o < 500) { in = sum4 + ((o - 100) / 100) * 100; W = waggT + 10000;  bia = baggf[100 + i]; dst = ne1 + (o - 100); }
      else              { in = m3 + ((o - 500) / 100) * 100;   W = waggT + 20000;  bia = baggf[200 + i]; dst = ne2 + (o - 500); }
      float acc = bia;
      for (int j = 0; j < 100; j++) acc += in[j] * W[j * 100 + i];
      *dst = tanhf(acc);
    }
    __syncthreads();
    for (int x = tid; x < 100; x += 256)
      sum1[x] = ne0[x] + 0.25f * (ne1[x] + ne1[100 + x] + ne1[200 + x] + ne1[300 + x]);
    for (int x = tid; x < 400; x += 256) {
      int k = x / 100, j = x % 100;
      const float* n2k = ne2 + k * 400;
      sum4[x] = ne1[x] + 0.25f * (n2k[j] + n2k[100 + j] + n2k[200 + j] + n2k[300 + j]);
    }
    __syncthreads();
    for (int o = tid; o < 500; o += 256) {
      int i = o % 100;
      if (o < 100) {
        float acc = baggf[i];
        for (int j = 0; j < 100; j++) acc += sum1[j] * waggT[j * 100 + i];
        e0[i] = tanhf(acc);
      } else {
        const float* in = sum4 + ((o - 100) / 100) * 100;
        float acc = baggf[100 + i];
        for (int j = 0; j < 100; j++) acc += in[j] * waggT[10000 + j * 100 + i];
        e1[o - 100] = tanhf(acc);
      }
    }
    __syncthreads();
    for (int x = tid; x < 100; x += 256)
      sum1[x] = e0[x] + 0.25f * (e1[x] + e1[100 + x] + e1[200 + x] + e1[300 + x]);
    __syncthreads();
    for (int o = tid; o < 100; o += 256) {
      float acc = baggf[o];
      for (int j = 0; j < 100; j++) acc += sum1[j] * waggT[j * 100 + o];
      ne0[o] = tanhf(acc);
    }
    __syncthreads();
    for (int o = tid; o < 100; o += 256) {
      float acc = blastf[o];
      for (int j = 0; j < 100; j++) acc += ne0[j] * wlastT[j * 100 + o];
      emq[o] = tanhf(acc);
    }
    __syncthreads();
  } else {
    for (int x = tid; x < 100; x += 256) emq[x] = Eq[(size_t)qt * 100 + x];
    __syncthreads();
  }

  const size_t bt = (size_t)b * T_ + t;
  for (int o = tid; o < 300; o += 256) {
    float acc = erw[rt * 300 + o];
    for (int j = 0; j < 100; j++) acc += emq[j] * wih1aT[j * 300 + o];
    gi1_all[bt * 300 + o] = acc;
  }
}

// ---------------------------------------------------------------------------
// Phase B (unchanged from R4): qw[5] and top-10 indices per (b,t).
// ---------------------------------------------------------------------------
__global__ __launch_bounds__(128) void phaseB(
    const float* Eq, const float* Ec, const int* question, const int* cidx, const int* cmask,
    const float* wkeyT, const float* b_key, const float* W_W,
    float* qw_all, int* top10_all)
{
  const int t = blockIdx.x, b = blockIdx.y, tid = threadIdx.x;
  const size_t bt = (size_t)b * T_ + t;
  __shared__ float qcf[500];
  __shared__ float qtl[500];
  __shared__ float qwp[20];
  __shared__ float orig[128];
  __shared__ float sval[128];
  __shared__ int sidx[128];
  __shared__ int ci[4], cm[4];

  const int qn = question[b * S_ + t + 1];
  if (tid < 4) { ci[tid] = cidx[qn * KC_ + tid]; cm[tid] = cmask[qn * KC_ + tid]; }
  __syncthreads();

  for (int u = tid; u < 500; u += 128) {
    int row = u / 100, j = u % 100;
    float v;
    if (row == 0) v = Eq[(size_t)qn * 100 + j];
    else {
      int k = row - 1;
      v = cm[k] ? Ec[(size_t)ci[k] * 100 + j] : 0.f;
    }
    qcf[u] = v;
  }
  __syncthreads();
  for (int o = tid; o < 500; o += 128) {
    int q = o / 100, i = o % 100;
    float acc = b_key[i];
    const float* src = qcf + q * 100;
    for (int j = 0; j < 100; j++) acc += src[j] * wkeyT[j * 100 + i];
    qtl[o] = tanhf(acc);
  }
  __syncthreads();
  if (tid < 20) {
    int q = tid / 4, part = tid % 4;
    float acc = 0.f;
    for (int j = part * 25; j < part * 25 + 25; j++) acc += qtl[q * 100 + j] * W_W[j];
    qwp[tid] = acc;
  }
  __syncthreads();
  if (tid < 5) qw_all[bt * 5 + tid] = qwp[tid * 4] + qwp[tid * 4 + 1] + qwp[tid * 4 + 2] + qwp[tid * 4 + 3];

  if (t > RK_) {
    float sc = -__builtin_inff();
    if (tid < t) {
      int qs = question[b * S_ + tid];
      float acc = 0.f;
      for (int j = 0; j < 100; j++) acc += Eq[(size_t)qs * 100 + j] * qcf[j];
      sc = acc;
    }
    orig[tid] = sc;
    __syncthreads();
    for (int pass = 0; pass < 10; pass++) {
      sval[tid] = orig[tid];
      sidx[tid] = tid;
      __syncthreads();
      for (int offt = 64; offt > 0; offt >>= 1) {
        if (tid < offt) {
          float v2 = sval[tid + offt];
          int i2 = sidx[tid + offt];
          if (v2 > sval[tid] || (v2 == sval[tid] && i2 < sidx[tid])) { sval[tid] = v2; sidx[tid] = i2; }
        }
        __syncthreads();
      }
      if (tid == 0) top10_all[bt * 10 + pass] = sidx[0];
      if (tid == sidx[0]) orig[tid] = -__builtin_inff();
      __syncthreads();
    }
  }
}

// ---------------------------------------------------------------------------
// Sequential scan, SINGLE WAVE per batch row (64 threads): zero inter-wave
// barriers (syncthreads on a 1-wave block is ~free), weights streamed f32
// from L2 (shared by all blocks on an XCD), matvecs as 4-lane-group coalesced
// dots with shuffle reduction, t+1 data prefetched at step top and committed
// to LDS double-buffers at step bottom. LDS ~13 KB.
// ---------------------------------------------------------------------------
__global__ __launch_bounds__(64, 1) void seqk(
    const float* gi1_all, const float* W_hh1, const float* W_hh2, const float* W_ih2,
    const float* b_hh1, const float* b_hh2, const float* b_ih2, const float* b_query,
    const float* W_query, const float* W_W, const float* b_W,
    const float* qw_all, const int* top10_all,
    const float* Eq, const float* Ec, const int* question, const int* cidx, const int* cmask,
    const float* h1_init, const float* h2_init, const float* scal,
    float* g2h, float* out)
{
  const int b = blockIdx.x, lane = threadIdx.x;
  const int grp = lane >> 2, sub = lane & 3;

  __shared__ __align__(16) float h1[100], h2[100], h1n[100], g2vS[100];
  __shared__ float gh[600];
  __shared__ float gi2v[300];
  __shared__ __align__(16) float gi1d[2][300];
  __shared__ __align__(16) float qcd[2][500];
  __shared__ float qwd[2][5];
  __shared__ int   topd[2][10];
  __shared__ int   cidS[8];
  __shared__ float kwhist[128];
  __shared__ float ogs[55];
  __shared__ float pqS[5];

  const float bWv = b_W[0];
  const float kw0 = scal[0];
  float* g2hb = g2h + (size_t)b * (T_ * 100);

  // ---- init ----
  for (int r = 0; r < 2; ++r) {
    int j = lane + 64 * r;
    if (j < 100) { h1[j] = h1_init[b * 100 + j]; h2[j] = h2_init[b * 100 + j]; g2hb[j] = 0.f; }
  }
  kwhist[lane] = kw0; kwhist[lane + 64] = kw0;
  {
    const float* g0 = gi1_all + (size_t)b * T_ * 300;
    for (int k = 0; k < 5; ++k) { int idx = lane + 64 * k; if (idx < 300) gi1d[0][idx] = g0[idx]; }
    if (lane < 5) qwd[0][lane] = qw_all[(size_t)b * T_ * 5 + lane];
    int qn0 = question[b * S_ + 1];
    if (lane < 4) cidS[lane] = cidx[qn0 * KC_ + lane];
    else if (lane < 8) cidS[lane] = cmask[qn0 * KC_ + lane - 4];
    __syncthreads();
    for (int k = 0; k < 8; ++k) {
      int idx = lane + 64 * k;
      if (idx < 500) {
        int q = idx / 100, j = idx % 100;
        float v;
        if (q == 0) v = Eq[(size_t)qn0 * 100 + j];
        else v = cidS[4 + q - 1] ? Ec[(size_t)cidS[q - 1] * 100 + j] : 0.f;
        qcd[0][idx] = v;
      }
    }
  }
  int qn_nx = question[b * S_ + 2];  // q_next index for step 1's qc (S_=128 > 2)
  __syncthreads();

  for (int t = 0; t < T_; ++t) {
    const size_t bt = (size_t)b * T_ + t;
    const int cur = t & 1, nxt = cur ^ 1;
    const bool pf = (t + 1) < T_;

    // ---- prefetch issue for t+1 (values land in regs; committed at bottom) ----
    float pgi[5]; float pqw = 0.f; int ptop = 0; int pci = 0;
    if (pf) {
      const float* g1 = gi1_all + (bt + 1) * 300;
#pragma unroll
      for (int k = 0; k < 5; ++k) { int idx = lane + 64 * k; pgi[k] = (idx < 300) ? g1[idx] : 0.f; }
      if (lane < 5) pqw = qw_all[(bt + 1) * 5 + lane];
      if (lane < 10 && (t + 1) > RK_) ptop = top10_all[(bt + 1) * 10 + lane];
      if (lane < 4) pci = cidx[qn_nx * KC_ + lane];
      else if (lane < 8) pci = cmask[qn_nx * KC_ + lane - 4];
    }
    int qn_n2 = (t + 3 < S_) ? question[b * S_ + t + 3] : 0;

    // ---- gh = [W_hh1@h1+b ; W_hh2@h2+b]  (600 rows, 16/iter, 4-lane groups) ----
    for (int it2 = 0; it2 < 38; ++it2) {
      int row = it2 * 16 + grp;
      if (row < 600) {
        const float* wrow = (row < 300) ? (W_hh1 + (size_t)row * 100) : (W_hh2 + (size_t)(row - 300) * 100);
        const float* hS = (row < 300) ? h1 : h2;
        float2 acc = make_float2(0.f, 0.f);
#pragma unroll
        for (int c = 0; c < 7; ++c) {
          int k4 = sub + 4 * c;
          if (k4 < 25) {
            float4 w = *(const float4*)(wrow + 4 * k4);
            float4 hv = *(const float4*)(hS + 4 * k4);
            acc.x = fmaf(w.x, hv.x, acc.x); acc.y = fmaf(w.y, hv.y, acc.y);
            acc.x = fmaf(w.z, hv.z, acc.x); acc.y = fmaf(w.w, hv.w, acc.y);
          }
        }
        float a = acc.x + acc.y;
        a += __shfl_xor(a, 1);
        a += __shfl_xor(a, 2);
        if (sub == 0) {
          float bias = (row < 300) ? b_hh1[row] : b_hh2[row - 300];
          gh[row] = a + bias;
        }
      }
    }
    __syncthreads();  // S1: gh visible

    // ---- GRU1 combine -> h1n; publish ci/cm for t+1 gather ----
    for (int r = 0; r < 2; ++r) {
      int j = lane + 64 * r;
      if (j < 100) {
        float rg = sigmf(gi1d[cur][j] + gh[j]);
        float z  = sigmf(gi1d[cur][100 + j] + gh[100 + j]);
        float n  = tanhf(gi1d[cur][200 + j] + rg * gh[200 + j]);
        h1n[j] = (1.f - z) * n + z * h1[j];
      }
    }
    if (pf && lane < 8) cidS[lane] = pci;
    __syncthreads();  // S2: h1n + cidS visible

    // ---- gi2 = W_ih2@h1n + b_ih2 (300 rows) ----
    for (int it2 = 0; it2 < 19; ++it2) {
      int row = it2 * 16 + grp;
      if (row < 300) {
        const float* wrow = W_ih2 + (size_t)row * 100;
        float2 acc = make_float2(0.f, 0.f);
#pragma unroll
        for (int c = 0; c < 7; ++c) {
          int k4 = sub + 4 * c;
          if (k4 < 25) {
            float4 w = *(const float4*)(wrow + 4 * k4);
            float4 hv = *(const float4*)(h1n + 4 * k4);
            acc.x = fmaf(w.x, hv.x, acc.x); acc.y = fmaf(w.y, hv.y, acc.y);
            acc.x = fmaf(w.z, hv.z, acc.x); acc.y = fmaf(w.w, hv.w, acc.y);
          }
        }
        float a = acc.x + acc.y;
        a += __shfl_xor(a, 1);
        a += __shfl_xor(a, 2);
        if (sub == 0) gi2v[row] = a + b_ih2[row];
      }
    }
    // qc gather for t+1 (needs cidS; loads consumed at bottom commit)
    float pqc[8];
    if (pf) {
#pragma unroll
      for (int k = 0; k < 8; ++k) {
        int idx = lane + 64 * k;
        float v = 0.f;
        if (idx < 500) {
          int q = idx / 100, j = idx % 100;
          if (q == 0) v = Eq[(size_t)qn_nx * 100 + j];
          else v = cidS[4 + q - 1] ? Ec[(size_t)cidS[q - 1] * 100 + j] : 0.f;
        }
        pqc[k] = v;
      }
    }
    __syncthreads();  // S3: gi2 visible

    // ---- GRU2 combine -> g2vS ----
    for (int r = 0; r < 2; ++r) {
      int j = lane + 64 * r;
      if (j < 100) {
        float rg = sigmf(gi2v[j] + gh[300 + j]);
        float z  = sigmf(gi2v[100 + j] + gh[400 + j]);
        float n  = tanhf(gi2v[200 + j] + rg * gh[500 + j]);
        g2vS[j] = (1.f - z) * n + z * h2[j];
      }
    }
    __syncthreads();  // S4: g2vS visible

    // ---- og partials (55 lanes: s in 0..10, q in 0..4) ----
    if (lane < 55) {
      int s = lane / 5, q = lane % 5;
      const float* qcr = &qcd[cur][q * 100];
      float acc = 0.f;
      if (s == 0) {
#pragma unroll
        for (int c = 0; c < 25; ++c) {
          float4 qv = *(const float4*)(qcr + 4 * c);
          float4 gv = *(const float4*)(g2vS + 4 * c);
          acc = fmaf(qv.x, gv.x, acc); acc = fmaf(qv.y, gv.y, acc);
          acc = fmaf(qv.z, gv.z, acc); acc = fmaf(qv.w, gv.w, acc);
        }
      } else {
        bool valid = (t > RK_) || (s - 1 < t);
        if (valid) {
          int idx = (t > RK_) ? topd[cur][s - 1] : (s - 1);
          const float4* hr = (const float4*)(g2hb + (size_t)idx * 100);
#pragma unroll
          for (int c = 0; c < 25; ++c) {
            float4 hv = hr[c];
            acc = fmaf(qcr[4 * c], hv.x, acc); acc = fmaf(qcr[4 * c + 1], hv.y, acc);
            acc = fmaf(qcr[4 * c + 2], hv.z, acc); acc = fmaf(qcr[4 * c + 3], hv.w, acc);
          }
        }
      }
      ogs[lane] = acc;
    }

    // ---- kq/kw: kw = sum_i Wk[i]*tanh(W_query[i]@g2 + bq[i]) ----
    float kwacc = 0.f;
    for (int it2 = 0; it2 < 7; ++it2) {
      int i = it2 * 16 + grp;
      if (i < 100) {
        const float* wrow = W_query + (size_t)i * 100;
        float2 acc = make_float2(0.f, 0.f);
#pragma unroll
        for (int c = 0; c < 7; ++c) {
          int k4 = sub + 4 * c;
          if (k4 < 25) {
            float4 w = *(const float4*)(wrow + 4 * k4);
            float4 gv = *(const float4*)(g2vS + 4 * k4);
            acc.x = fmaf(w.x, gv.x, acc.x); acc.y = fmaf(w.y, gv.y, acc.y);
            acc.x = fmaf(w.z, gv.z, acc.x); acc.y = fmaf(w.w, gv.w, acc.y);
          }
        }
        float a = acc.x + acc.y;
        a += __shfl_xor(a, 1);
        a += __shfl_xor(a, 2);
        if (sub == 0) kwacc += tanhf(a + b_query[i]) * W_W[100 + i];
      }
    }
    kwacc += __shfl_xor(kwacc, 1);
    kwacc += __shfl_xor(kwacc, 2);
    kwacc += __shfl_xor(kwacc, 4);
    kwacc += __shfl_xor(kwacc, 8);
    kwacc += __shfl_xor(kwacc, 16);
    kwacc += __shfl_xor(kwacc, 32);
    const float kw = kwacc;  // all lanes
    __syncthreads();  // S5: ogs visible

    // ---- softmax (5 lanes) + state updates + buffer commits ----
    if (lane < 5) {
      const int q = lane;
      const float qw = qwd[cur][q];
      float tmp[11];
      float m = -__builtin_inff();
#pragma unroll
      for (int s = 0; s < 11; ++s) {
        float kws;
        bool valid;
        if (s == 0) { kws = kw; valid = true; }
        else if (t > RK_) { kws = kwhist[topd[cur][s - 1]]; valid = true; }
        else { valid = (s - 1 < t); kws = kwhist[s - 1]; }
        float tv = valid ? (qw + kws + bWv) : NEGV;
        tmp[s] = tv;
        m = fmaxf(m, tv);
      }
      float den = 0.f, num = 0.f;
#pragma unroll
      for (int s = 0; s < 11; ++s) {
        float e = expf(tmp[s] - m);
        den += e;
        num += e * ogs[s * 5 + q];
      }
      pqS[q] = num / den;
    }
    for (int r = 0; r < 2; ++r) {
      int j = lane + 64 * r;
      if (j < 100) {
        h1[j] = h1n[j];
        if (t > 0) { h2[j] = g2vS[j]; g2hb[t * 100 + j] = g2vS[j]; }
      }
    }
    if (t > 0 && lane == 0) kwhist[t] = kw;
    if (pf) {
#pragma unroll
      for (int k = 0; k < 5; ++k) { int idx = lane + 64 * k; if (idx < 300) gi1d[nxt][idx] = pgi[k]; }
      if (lane < 5) qwd[nxt][lane] = pqw;
      if (lane < 10 && (t + 1) > RK_) topd[nxt][lane] = min(T_ - 1, max(0, ptop));
#pragma unroll
      for (int k = 0; k < 8; ++k) { int idx = lane + 64 * k; if (idx < 500) qcd[nxt][idx] = pqc[k]; }
      qn_nx = qn_n2;
    }
    __syncthreads();  // S6: pqS/h/buffers visible for next step

    if (lane == 0) {
      float p = pqS[0] + pqS[1] + pqS[2] + pqS[3] + pqS[4];
      int col = (t == 0) ? 0 : (t + 1);
      out[b * S_ + col] = p;
      if (t == 0) out[b * S_ + 1] = 0.f;  // col 1 never written by ref (yhat stays 0)
    }
  }
}

// ---------------------------------------------------------------------------
extern "C" void kernel_launch(void* const* d_in, const int* in_sizes, int n_in,
                              void* d_out, int out_size, void* d_ws, size_t ws_size,
                              hipStream_t stream)
{
  (void)in_sizes; (void)n_in; (void)out_size; (void)ws_size;
  const float* Eq     = (const float*)d_in[0];
  const float* Ec     = (const float*)d_in[1];
  const float* Er     = (const float*)d_in[2];
  const float* W_ih1  = (const float*)d_in[3];
  const float* W_hh1  = (const float*)d_in[4];
  const float* b_ih1  = (const float*)d_in[5];
  const float* b_hh1  = (const float*)d_in[6];
  const float* W_ih2  = (const float*)d_in[7];
  const float* W_hh2  = (const float*)d_in[8];
  const float* b_ih2  = (const float*)d_in[9];
  const float* b_hh2  = (const float*)d_in[10];
  const float* Wagg   = (const float*)d_in[11];
  const float* bagg   = (const float*)d_in[12];
  const float* W_last = (const float*)d_in[13];
  const float* b_last = (const float*)d_in[14];
  const float* W_query= (const float*)d_in[15];
  const float* b_query= (const float*)d_in[16];
  const float* W_key  = (const float*)d_in[17];
  const float* b_key  = (const float*)d_in[18];
  const float* W_W    = (const float*)d_in[19];
  const float* b_W    = (const float*)d_in[20];
  const float* h1_init= (const float*)d_in[21];
  const float* h2_init= (const float*)d_in[22];
  const int* question = (const int*)d_in[23];
  const int* response = (const int*)d_in[24];
  const int* mask     = (const int*)d_in[25];
  const int* qnb      = (const int*)d_in[26];
  const int* snb      = (const int*)d_in[27];
  const int* cidx     = (const int*)d_in[28];
  const int* cmask    = (const int*)d_in[29];
  float* out = (float*)d_out;

  char* ws = (char*)d_ws;
  size_t off = 0;
  auto alloc = [&](size_t bytes) -> void* {
    void* p = ws + off;
    off += (bytes + 255) & ~(size_t)255;
    return p;
  };
  float* wih1aT = (float*)alloc(30000 * 4);
  float* erw    = (float*)alloc(600 * 4);
  float* waggT  = (float*)alloc(30000 * 4);
  float* wlastT = (float*)alloc(10000 * 4);
  float* wkeyT  = (float*)alloc(10000 * 4);
  float* scal   = (float*)alloc(4);
  float* gi1_all = (float*)alloc((size_t)B_ * T_ * 300 * 4);
  float* qw_all  = (float*)alloc((size_t)B_ * T_ * 5 * 4);
  int*   top10   = (int*)alloc((size_t)B_ * T_ * 10 * 4);
  float* g2h     = (float*)alloc((size_t)B_ * T_ * 100 * 4);

  hipLaunchKernelGGL(setupk, dim3(128), dim3(256), 0, stream,
      Er, W_ih1, b_ih1, Wagg, W_last, W_key, b_query, W_W,
      wih1aT, erw, waggT, wlastT, wkeyT, scal);

  hipLaunchKernelGGL(phaseA, dim3(T_, B_), dim3(256), 0, stream,
      Eq, Ec, question, response, mask, qnb, snb,
      wih1aT, erw, waggT, wlastT, bagg, b_last, gi1_all);

  hipLaunchKernelGGL(phaseB, dim3(T_, B_), dim3(128), 0, stream,
      Eq, Ec, question, cidx, cmask, wkeyT, b_key, W_W,
      qw_all, top10);

  hipLaunchKernelGGL(seqk, dim3(B_), dim3(64), 0, stream,
      gi1_all, W_hh1, W_hh2, W_ih2, b_hh1, b_hh2, b_ih2, b_query,
      W_query, W_W, b_W, qw_all, top10,
      Eq, Ec, question, cidx, cmask,
      h1_init, h2_init, scal, g2h, out);
}

// Round 6
// 2385.204 us; speedup vs baseline: 2.0802x; 2.0802x over previous
//
#include <hip/hip_runtime.h>
#include <math.h>

#define B_ 128
#define S_ 128
#define T_ 127
#define D_ 100
#define QN_ 4
#define SN_ 4
#define KC_ 4
#define RK_ 10
#define NEGV -1000000000.0f

__device__ __forceinline__ float sigmf(float x) { return 1.0f / (1.0f + expf(-x)); }

// ---------------------------------------------------------------------------
// Setup (unchanged): transposed weights for phaseA/B; erw fold; kw0 scalar.
// ---------------------------------------------------------------------------
__global__ __launch_bounds__(256) void setupk(
    const float* Er, const float* W_ih1, const float* b_ih1,
    const float* Wagg, const float* W_last, const float* W_key,
    const float* b_query, const float* W_W,
    float* wih1aT, float* erw, float* waggT, float* wlastT, float* wkeyT,
    float* scal)
{
  int gid = blockIdx.x * blockDim.x + threadIdx.x;
  int gsz = gridDim.x * blockDim.x;

  for (int x = gid; x < 30000; x += gsz) {
    int j = x / 300, i = x % 300;
    wih1aT[j * 300 + i] = W_ih1[i * 200 + j];
  }
  for (int x = gid; x < 600; x += gsz) {
    int r = x / 300, i = x % 300;
    float acc = b_ih1[i];
    for (int j = 0; j < 100; j++) acc += Er[r * 100 + j] * W_ih1[i * 200 + 100 + j];
    erw[x] = acc;
  }
  for (int x = gid; x < 30000; x += gsz) {
    int h = x / 10000, rr = x % 10000, j = rr / 100, i = rr % 100;
    waggT[h * 10000 + j * 100 + i] = Wagg[h * 10000 + i * 100 + j];
  }
  for (int x = gid; x < 10000; x += gsz) {
    int j = x / 100, i = x % 100;
    wlastT[j * 100 + i] = W_last[i * 100 + j];
    wkeyT[j * 100 + i] = W_key[i * 100 + j];
  }
  if (gid == 0) {
    float acc = 0.f;  // kw of the all-zero hist state: dot(tanh(b_query), Wk_part)
    for (int i = 0; i < 100; i++) acc += tanhf(b_query[i]) * W_W[100 + i];
    scal[0] = acc;
  }
}

// ---------------------------------------------------------------------------
// Phase A (unchanged): per (b,t) 3-hop aggregate -> gi1[b,t,0:300]
// ---------------------------------------------------------------------------
__global__ __launch_bounds__(256) void phaseA(
    const float* Eq, const float* Ec, const int* question, const int* response, const int* mask,
    const int* qnb, const int* snb,
    const float* wih1aT, const float* erw, const float* waggT, const float* wlastT,
    const float* baggf, const float* blastf, float* gi1_all)
{
  const int t = blockIdx.x, b = blockIdx.y, tid = threadIdx.x;
  __shared__ float e0[100], ne0[100], e1[400], ne1[400];
  __shared__ float e2[1600], ne2[1600], m3[1600];
  __shared__ float sum4[400], sum1[100], emq[100];
  __shared__ int l1[4], l2[16], l3[64];

  const int qt = question[b * S_ + t];
  const int mt = mask[b * S_ + t];
  const int rt = response[b * S_ + t];

  if (mt != 0) {
    if (tid < 4) l1[tid] = qnb[qt * QN_ + tid];
    for (int x = tid; x < 100; x += 256) e0[x] = Eq[(size_t)qt * 100 + x];
    __syncthreads();
    if (tid < 16) l2[tid] = snb[l1[tid >> 2] * SN_ + (tid & 3)];
    for (int x = tid; x < 400; x += 256) e1[x] = Ec[(size_t)l1[x / 100] * 100 + (x % 100)];
    __syncthreads();
    if (tid < 64) l3[tid] = qnb[l2[tid >> 2] * QN_ + (tid & 3)];
    for (int x = tid; x < 1600; x += 256) e2[x] = Eq[(size_t)l2[x / 100] * 100 + (x % 100)];
    __syncthreads();
    for (int x = tid; x < 1600; x += 256) {
      int r = x / 100, j = x % 100;
      const int* lr = l3 + r * 4;
      float s = Ec[(size_t)lr[0] * 100 + j] + Ec[(size_t)lr[1] * 100 + j] +
                Ec[(size_t)lr[2] * 100 + j] + Ec[(size_t)lr[3] * 100 + j];
      m3[x] = e2[x] + 0.25f * s;
    }
    for (int x = tid; x < 100; x += 256)
      sum1[x] = e0[x] + 0.25f * (e1[x] + e1[100 + x] + e1[200 + x] + e1[300 + x]);
    for (int x = tid; x < 400; x += 256) {
      int k = x / 100, j = x % 100;
      const float* e2k = e2 + k * 400;
      sum4[x] = e1[x] + 0.25f * (e2k[j] + e2k[100 + j] + e2k[200 + j] + e2k[300 + j]);
    }
    __syncthreads();
    for (int o = tid; o < 2100; o += 256) {
      const float *in, *W;
      float bia;
      float* dst;
      int i = o % 100;
      if (o < 100)      { in = sum1;                           W = waggT;          bia = baggf[i];       dst = ne0 + o; }
      else if (o < 500) { in = sum4 + ((o - 100) / 100) * 100; W = waggT + 10000;  bia = baggf[100 + i]; dst = ne1 + (o - 100); }
      else              { in = m3 + ((o - 500) / 100) * 100;   W = waggT + 20000;  bia = baggf[200 + i]; dst = ne2 + (o - 500); }
      float acc = bia;
      for (int j = 0; j < 100; j++) acc += in[j] * W[j * 100 + i];
      *dst = tanhf(acc);
    }
    __syncthreads();
    for (int x = tid; x < 100; x += 256)
      sum1[x] = ne0[x] + 0.25f * (ne1[x] + ne1[100 + x] + ne1[200 + x] + ne1[300 + x]);
    for (int x = tid; x < 400; x += 256) {
      int k = x / 100, j = x % 100;
      const float* n2k = ne2 + k * 400;
      sum4[x] = ne1[x] + 0.25f * (n2k[j] + n2k[100 + j] + n2k[200 + j] + n2k[300 + j]);
    }
    __syncthreads();
    for (int o = tid; o < 500; o += 256) {
      int i = o % 100;
      if (o < 100) {
        float acc = baggf[i];
        for (int j = 0; j < 100; j++) acc += sum1[j] * waggT[j * 100 + i];
        e0[i] = tanhf(acc);
      } else {
        const float* in = sum4 + ((o - 100) / 100) * 100;
        float acc = baggf[100 + i];
        for (int j = 0; j < 100; j++) acc += in[j] * waggT[10000 + j * 100 + i];
        e1[o - 100] = tanhf(acc);
      }
    }
    __syncthreads();
    for (int x = tid; x < 100; x += 256)
      sum1[x] = e0[x] + 0.25f * (e1[x] + e1[100 + x] + e1[200 + x] + e1[300 + x]);
    __syncthreads();
    for (int o = tid; o < 100; o += 256) {
      float acc = baggf[o];
      for (int j = 0; j < 100; j++) acc += sum1[j] * waggT[j * 100 + o];
      ne0[o] = tanhf(acc);
    }
    __syncthreads();
    for (int o = tid; o < 100; o += 256) {
      float acc = blastf[o];
      for (int j = 0; j < 100; j++) acc += ne0[j] * wlastT[j * 100 + o];
      emq[o] = tanhf(acc);
    }
    __syncthreads();
  } else {
    for (int x = tid; x < 100; x += 256) emq[x] = Eq[(size_t)qt * 100 + x];
    __syncthreads();
  }

  const size_t bt = (size_t)b * T_ + t;
  for (int o = tid; o < 300; o += 256) {
    float acc = erw[rt * 300 + o];
    for (int j = 0; j < 100; j++) acc += emq[j] * wih1aT[j * 300 + o];
    gi1_all[bt * 300 + o] = acc;
  }
}

// ---------------------------------------------------------------------------
// Phase B (unchanged): qw[5] and top-10 indices per (b,t).
// ---------------------------------------------------------------------------
__global__ __launch_bounds__(128) void phaseB(
    const float* Eq, const float* Ec, const int* question, const int* cidx, const int* cmask,
    const float* wkeyT, const float* b_key, const float* W_W,
    float* qw_all, int* top10_all)
{
  const int t = blockIdx.x, b = blockIdx.y, tid = threadIdx.x;
  const size_t bt = (size_t)b * T_ + t;
  __shared__ float qcf[500];
  __shared__ float qtl[500];
  __shared__ float qwp[20];
  __shared__ float orig[128];
  __shared__ float sval[128];
  __shared__ int sidx[128];
  __shared__ int ci[4], cm[4];

  const int qn = question[b * S_ + t + 1];
  if (tid < 4) { ci[tid] = cidx[qn * KC_ + tid]; cm[tid] = cmask[qn * KC_ + tid]; }
  __syncthreads();

  for (int u = tid; u < 500; u += 128) {
    int row = u / 100, j = u % 100;
    float v;
    if (row == 0) v = Eq[(size_t)qn * 100 + j];
    else {
      int k = row - 1;
      v = cm[k] ? Ec[(size_t)ci[k] * 100 + j] : 0.f;
    }
    qcf[u] = v;
  }
  __syncthreads();
  for (int o = tid; o < 500; o += 128) {
    int q = o / 100, i = o % 100;
    float acc = b_key[i];
    const float* src = qcf + q * 100;
    for (int j = 0; j < 100; j++) acc += src[j] * wkeyT[j * 100 + i];
    qtl[o] = tanhf(acc);
  }
  __syncthreads();
  if (tid < 20) {
    int q = tid / 4, part = tid % 4;
    float acc = 0.f;
    for (int j = part * 25; j < part * 25 + 25; j++) acc += qtl[q * 100 + j] * W_W[j];
    qwp[tid] = acc;
  }
  __syncthreads();
  if (tid < 5) qw_all[bt * 5 + tid] = qwp[tid * 4] + qwp[tid * 4 + 1] + qwp[tid * 4 + 2] + qwp[tid * 4 + 3];

  if (t > RK_) {
    float sc = -__builtin_inff();
    if (tid < t) {
      int qs = question[b * S_ + tid];
      float acc = 0.f;
      for (int j = 0; j < 100; j++) acc += Eq[(size_t)qs * 100 + j] * qcf[j];
      sc = acc;
    }
    orig[tid] = sc;
    __syncthreads();
    for (int pass = 0; pass < 10; pass++) {
      sval[tid] = orig[tid];
      sidx[tid] = tid;
      __syncthreads();
      for (int offt = 64; offt > 0; offt >>= 1) {
        if (tid < offt) {
          float v2 = sval[tid + offt];
          int i2 = sidx[tid + offt];
          if (v2 > sval[tid] || (v2 == sval[tid] && i2 < sidx[tid])) { sval[tid] = v2; sidx[tid] = i2; }
        }
        __syncthreads();
      }
      if (tid == 0) top10_all[bt * 10 + pass] = sidx[0];
      if (tid == sidx[0]) orig[tid] = -__builtin_inff();
      __syncthreads();
    }
  }
}

// ---------------------------------------------------------------------------
// Sequential scan v3: 512 threads/block (8 waves -> 2 waves/SIMD -> 256 VGPR
// cap). ALL weight rows live in per-thread registers, PINNED with inline asm
// so the compiler cannot rematerialize (the R3/R4/R5 failure). Combined row
// space: [0,300)=W_hh1, [300,600)=W_hh2, [600,900)=W_ih2, [900,1000)=W_query;
// thread t holds rows 2t,2t+1 (t<500) = 200 VGPRs, rows of the SAME matrix so
// one broadcast LDS read of h serves both dots. g2 history in LDS (50.8 KB);
// per-step global traffic is only ~3.3 KB of prefetch. LDS ~64 KB.
// ---------------------------------------------------------------------------
#define PIN(x) asm volatile("" : "+v"(x))

__global__ __launch_bounds__(512, 2) void seqk(
    const float* gi1_all, const float* W_hh1, const float* W_hh2, const float* W_ih2,
    const float* b_hh1, const float* b_hh2, const float* b_ih2, const float* b_query,
    const float* W_query, const float* W_W, const float* b_W,
    const float* qw_all, const int* top10_all,
    const float* Eq, const float* Ec, const int* question, const int* cidx, const int* cmask,
    const float* h1_init, const float* h2_init, const float* scal,
    float* out)
{
  const int b = blockIdx.x, tid = threadIdx.x;

  __shared__ __align__(16) float g2hist[T_ * 100];   // 50.8 KB, row 0 = zeros
  __shared__ __align__(16) float gi1d[2][300];
  __shared__ __align__(16) float qcd[2][500];
  __shared__ __align__(16) float h1[100], h2[100], h1n[100], g2vS[100];
  __shared__ __align__(16) float gh[600];
  __shared__ float gi2v[300];
  __shared__ float kqv[100];
  __shared__ float kwhist[128];
  __shared__ float ogs[55];
  __shared__ float pqS[5];
  __shared__ float qwd[2][5];
  __shared__ int topd[2][10];
  __shared__ int cidS[8];
  __shared__ int qnS, qn0S;
  __shared__ float kwcur;

  // ---- one-time: weight rows -> pinned registers ----
  float wa[100], wb[100];
  float b0 = 0.f, b1 = 0.f, wk0 = 0.f, wk1 = 0.f;
  if (tid < 500) {
    const int r0 = 2 * tid, r1 = r0 + 1;
    const float* p0;
    const float* p1;
    if (r0 < 300)      { p0 = W_hh1 + (size_t)r0 * 100;        b0 = b_hh1[r0]; }
    else if (r0 < 600) { p0 = W_hh2 + (size_t)(r0 - 300) * 100; b0 = b_hh2[r0 - 300]; }
    else if (r0 < 900) { p0 = W_ih2 + (size_t)(r0 - 600) * 100; b0 = b_ih2[r0 - 600]; }
    else               { p0 = W_query + (size_t)(r0 - 900) * 100; b0 = b_query[r0 - 900]; wk0 = W_W[100 + (r0 - 900)]; }
    if (r1 < 300)      { p1 = W_hh1 + (size_t)r1 * 100;        b1 = b_hh1[r1]; }
    else if (r1 < 600) { p1 = W_hh2 + (size_t)(r1 - 300) * 100; b1 = b_hh2[r1 - 300]; }
    else if (r1 < 900) { p1 = W_ih2 + (size_t)(r1 - 600) * 100; b1 = b_ih2[r1 - 600]; }
    else               { p1 = W_query + (size_t)(r1 - 900) * 100; b1 = b_query[r1 - 900]; wk1 = W_W[100 + (r1 - 900)]; }
#pragma unroll
    for (int c = 0; c < 25; ++c) {
      float4 v0 = *(const float4*)(p0 + 4 * c);
      float4 v1 = *(const float4*)(p1 + 4 * c);
      wa[4 * c] = v0.x; wa[4 * c + 1] = v0.y; wa[4 * c + 2] = v0.z; wa[4 * c + 3] = v0.w;
      wb[4 * c] = v1.x; wb[4 * c + 1] = v1.y; wb[4 * c + 2] = v1.z; wb[4 * c + 3] = v1.w;
    }
#pragma unroll
    for (int k = 0; k < 100; ++k) { PIN(wa[k]); PIN(wb[k]); }
    PIN(b0); PIN(b1); PIN(wk0); PIN(wk1);
  }

  const float bWv = b_W[0];
  const float kw0 = scal[0];

  // ---- init LDS state ----
  if (tid < 100) {
    h1[tid] = h1_init[b * 100 + tid];
    h2[tid] = h2_init[b * 100 + tid];
    g2hist[tid] = 0.f;
  }
  if (tid < 128) kwhist[tid] = kw0;
  if (tid >= 300 && tid < 450) {
    int i = 2 * (tid - 300);
    const float* g0 = gi1_all + (size_t)b * T_ * 300;
    gi1d[0][i] = g0[i]; gi1d[0][i + 1] = g0[i + 1];
  }
  if (tid >= 450 && tid < 455) qwd[0][tid - 450] = qw_all[(size_t)b * T_ * 5 + (tid - 450)];
  if (tid == 473) qnS = question[b * S_ + 2];
  if (tid < 8) {
    int qn0 = question[b * S_ + 1];
    if (tid == 0) qn0S = qn0;
    cidS[tid] = (tid < 4) ? cidx[qn0 * KC_ + tid] : cmask[qn0 * KC_ + tid - 4];
  }
  __syncthreads();
  if (tid < 250) {
    int qn0 = qn0S;
#pragma unroll
    for (int e = 0; e < 2; ++e) {
      int idx = 2 * tid + e;
      int q = idx / 100, j = idx % 100;
      float v;
      if (q == 0) v = Eq[(size_t)qn0 * 100 + j];
      else v = cidS[4 + q - 1] ? Ec[(size_t)cidS[q - 1] * 100 + j] : 0.f;
      qcd[0][idx] = v;
    }
  }
  __syncthreads();

  for (int t = 0; t < T_; ++t) {
    const size_t bt = (size_t)b * T_ + t;
    const int cur = t & 1, nxt = cur ^ 1;
    const bool pf = (t + 1) < T_;

    // ---- S1: gh (600 rows, threads 0-299) | prefetch issue (threads 300+) ----
    float pgi0 = 0.f, pgi1 = 0.f, pqw = 0.f;
    int ptop = 0, pci = 0, pqn2 = 0;
    if (tid < 300) {
      const float* hS = (tid < 150) ? h1 : h2;
      float a0 = 0.f, a1 = 0.f;
#pragma unroll
      for (int c = 0; c < 25; ++c) {
        float4 hv = *(const float4*)(hS + 4 * c);
        a0 = fmaf(wa[4 * c], hv.x, a0); a0 = fmaf(wa[4 * c + 1], hv.y, a0);
        a0 = fmaf(wa[4 * c + 2], hv.z, a0); a0 = fmaf(wa[4 * c + 3], hv.w, a0);
        a1 = fmaf(wb[4 * c], hv.x, a1); a1 = fmaf(wb[4 * c + 1], hv.y, a1);
        a1 = fmaf(wb[4 * c + 2], hv.z, a1); a1 = fmaf(wb[4 * c + 3], hv.w, a1);
      }
      *(float2*)&gh[2 * tid] = make_float2(a0 + b0, a1 + b1);
    } else if (pf) {
      if (tid < 450) {
        int i = 2 * (tid - 300);
        const float* g1 = gi1_all + (bt + 1) * 300;
        pgi0 = g1[i]; pgi1 = g1[i + 1];
      } else if (tid < 455) {
        pqw = qw_all[(bt + 1) * 5 + (tid - 450)];
      } else if (tid < 465) {
        if ((t + 1) > RK_) ptop = top10_all[(bt + 1) * 10 + (tid - 455)];
      } else if (tid < 473) {
        int k = tid - 465;
        int qn = qnS;
        pci = (k < 4) ? cidx[qn * KC_ + k] : cmask[qn * KC_ + k - 4];
      } else if (tid == 473) {
        if (t + 3 < S_) pqn2 = question[b * S_ + t + 3];
      }
    }
    __syncthreads();  // b1

    // ---- S2: GRU1 combine -> h1n | publish cidS for t+1 ----
    if (tid < 100) {
      int j = tid;
      float rg = sigmf(gi1d[cur][j] + gh[j]);
      float z  = sigmf(gi1d[cur][100 + j] + gh[100 + j]);
      float n  = tanhf(gi1d[cur][200 + j] + rg * gh[200 + j]);
      h1n[j] = (1.f - z) * n + z * h1[j];
    } else if (tid >= 465 && tid < 473 && pf) {
      cidS[tid - 465] = pci;
    }
    __syncthreads();  // b2

    // ---- S3: gi2 (rows 600-899, threads 300-449) | qc gather issue (0-249) ----
    float pqc0 = 0.f, pqc1 = 0.f;
    if (tid >= 300 && tid < 450) {
      float a0 = 0.f, a1 = 0.f;
#pragma unroll
      for (int c = 0; c < 25; ++c) {
        float4 hv = *(const float4*)(h1n + 4 * c);
        a0 = fmaf(wa[4 * c], hv.x, a0); a0 = fmaf(wa[4 * c + 1], hv.y, a0);
        a0 = fmaf(wa[4 * c + 2], hv.z, a0); a0 = fmaf(wa[4 * c + 3], hv.w, a0);
        a1 = fmaf(wb[4 * c], hv.x, a1); a1 = fmaf(wb[4 * c + 1], hv.y, a1);
        a1 = fmaf(wb[4 * c + 2], hv.z, a1); a1 = fmaf(wb[4 * c + 3], hv.w, a1);
      }
      int i = 2 * (tid - 300);
      *(float2*)&gi2v[i] = make_float2(a0 + b0, a1 + b1);
    } else if (tid < 250 && pf) {
      int qn = qnS;
#pragma unroll
      for (int e = 0; e < 2; ++e) {
        int idx = 2 * tid + e;
        int q = idx / 100, j = idx % 100;
        float v;
        if (q == 0) v = Eq[(size_t)qn * 100 + j];
        else v = cidS[4 + q - 1] ? Ec[(size_t)cidS[q - 1] * 100 + j] : 0.f;
        if (e == 0) pqc0 = v; else pqc1 = v;
      }
    }
    __syncthreads();  // b3

    // ---- S4: GRU2 combine -> g2vS ----
    if (tid < 100) {
      int j = tid;
      float rg = sigmf(gi2v[j] + gh[300 + j]);
      float z  = sigmf(gi2v[100 + j] + gh[400 + j]);
      float n  = tanhf(gi2v[200 + j] + rg * gh[500 + j]);
      g2vS[j] = (1.f - z) * n + z * h2[j];
    }
    __syncthreads();  // b4

    // ---- S5: og partials (0-54) | state copies (100-299) | kq (450-499) ----
    if (tid < 55) {
      int s = tid / 5, q = tid % 5;
      const float* qcr = &qcd[cur][q * 100];
      float acc = 0.f;
      if (s == 0) {
#pragma unroll
        for (int c = 0; c < 25; ++c) {
          float4 qv = *(const float4*)(qcr + 4 * c);
          float4 gv = *(const float4*)(g2vS + 4 * c);
          acc = fmaf(qv.x, gv.x, acc); acc = fmaf(qv.y, gv.y, acc);
          acc = fmaf(qv.z, gv.z, acc); acc = fmaf(qv.w, gv.w, acc);
        }
      } else {
        bool valid = (t > RK_) || (s - 1 < t);
        if (valid) {
          int idx = (t > RK_) ? topd[cur][s - 1] : (s - 1);
          const float4* hr = (const float4*)(g2hist + (size_t)idx * 100);
#pragma unroll
          for (int c = 0; c < 25; ++c) {
            float4 qv = *(const float4*)(qcr + 4 * c);
            float4 hv = hr[c];
            acc = fmaf(qv.x, hv.x, acc); acc = fmaf(qv.y, hv.y, acc);
            acc = fmaf(qv.z, hv.z, acc); acc = fmaf(qv.w, hv.w, acc);
          }
        }
      }
      ogs[tid] = acc;
    } else if (tid >= 100 && tid < 200) {
      h1[tid - 100] = h1n[tid - 100];
    } else if (tid >= 200 && tid < 300) {
      if (t > 0) {
        int j = tid - 200;
        h2[j] = g2vS[j];
        g2hist[t * 100 + j] = g2vS[j];
      }
    } else if (tid >= 450 && tid < 500) {
      float a0 = 0.f, a1 = 0.f;
#pragma unroll
      for (int c = 0; c < 25; ++c) {
        float4 gv = *(const float4*)(g2vS + 4 * c);
        a0 = fmaf(wa[4 * c], gv.x, a0); a0 = fmaf(wa[4 * c + 1], gv.y, a0);
        a0 = fmaf(wa[4 * c + 2], gv.z, a0); a0 = fmaf(wa[4 * c + 3], gv.w, a0);
        a1 = fmaf(wb[4 * c], gv.x, a1); a1 = fmaf(wb[4 * c + 1], gv.y, a1);
        a1 = fmaf(wb[4 * c + 2], gv.z, a1); a1 = fmaf(wb[4 * c + 3], gv.w, a1);
      }
      int i = 2 * (tid - 450);
      kqv[i] = tanhf(a0 + b0) * wk0;
      kqv[i + 1] = tanhf(a1 + b1) * wk1;
    }
    __syncthreads();  // b5

    // ---- S6: kw reduce (wave 0) ----
    if (tid < 64) {
      float v = (tid < 50) ? (kqv[tid] + kqv[tid + 50]) : 0.f;
      v += __shfl_xor(v, 1);
      v += __shfl_xor(v, 2);
      v += __shfl_xor(v, 4);
      v += __shfl_xor(v, 8);
      v += __shfl_xor(v, 16);
      v += __shfl_xor(v, 32);
      if (tid == 0) kwcur = v;
    }
    __syncthreads();  // b6

    // ---- S7: softmax (0-4) | kwhist | dbuf commits ----
    if (tid < 5) {
      const int q = tid;
      const float qw = qwd[cur][q];
      float tmp[11];
      float m = -__builtin_inff();
#pragma unroll
      for (int s = 0; s < 11; ++s) {
        float kws;
        bool valid;
        if (s == 0) { kws = kwcur; valid = true; }
        else if (t > RK_) { kws = kwhist[topd[cur][s - 1]]; valid = true; }
        else { valid = (s - 1 < t); kws = kwhist[s - 1]; }
        float tv = valid ? (qw + kws + bWv) : NEGV;
        tmp[s] = tv;
        m = fmaxf(m, tv);
      }
      float den = 0.f, num = 0.f;
#pragma unroll
      for (int s = 0; s < 11; ++s) {
        float e = expf(tmp[s] - m);
        den += e;
        num += e * ogs[s * 5 + q];
      }
      pqS[q] = num / den;
    } else if (tid == 8) {
      if (t > 0) kwhist[t] = kwcur;
    }
    if (pf) {
      if (tid < 250) {
        qcd[nxt][2 * tid] = pqc0;
        qcd[nxt][2 * tid + 1] = pqc1;
      } else if (tid >= 300 && tid < 450) {
        int i = 2 * (tid - 300);
        gi1d[nxt][i] = pgi0; gi1d[nxt][i + 1] = pgi1;
      } else if (tid >= 450 && tid < 455) {
        qwd[nxt][tid - 450] = pqw;
      } else if (tid >= 455 && tid < 465) {
        if ((t + 1) > RK_) topd[nxt][tid - 455] = min(T_ - 1, max(0, ptop));
      } else if (tid == 473) {
        if (t + 3 < S_) qnS = pqn2;
      }
    }
    __syncthreads();  // b7

    // ---- S8: final sum + store ----
    if (tid == 0) {
      float p = pqS[0] + pqS[1] + pqS[2] + pqS[3] + pqS[4];
      int col = (t == 0) ? 0 : (t + 1);
      out[b * S_ + col] = p;
      if (t == 0) out[b * S_ + 1] = 0.f;  // col 1 never written by ref
    }
  }
}

// ---------------------------------------------------------------------------
extern "C" void kernel_launch(void* const* d_in, const int* in_sizes, int n_in,
                              void* d_out, int out_size, void* d_ws, size_t ws_size,
                              hipStream_t stream)
{
  (void)in_sizes; (void)n_in; (void)out_size; (void)ws_size;
  const float* Eq     = (const float*)d_in[0];
  const float* Ec     = (const float*)d_in[1];
  const float* Er     = (const float*)d_in[2];
  const float* W_ih1  = (const float*)d_in[3];
  const float* W_hh1  = (const float*)d_in[4];
  const float* b_ih1  = (const float*)d_in[5];
  const float* b_hh1  = (const float*)d_in[6];
  const float* W_ih2  = (const float*)d_in[7];
  const float* W_hh2  = (const float*)d_in[8];
  const float* b_ih2  = (const float*)d_in[9];
  const float* b_hh2  = (const float*)d_in[10];
  const float* Wagg   = (const float*)d_in[11];
  const float* bagg   = (const float*)d_in[12];
  const float* W_last = (const float*)d_in[13];
  const float* b_last = (const float*)d_in[14];
  const float* W_query= (const float*)d_in[15];
  const float* b_query= (const float*)d_in[16];
  const float* W_key  = (const float*)d_in[17];
  const float* b_key  = (const float*)d_in[18];
  const float* W_W    = (const float*)d_in[19];
  const float* b_W    = (const float*)d_in[20];
  const float* h1_init= (const float*)d_in[21];
  const float* h2_init= (const float*)d_in[22];
  const int* question = (const int*)d_in[23];
  const int* response = (const int*)d_in[24];
  const int* mask     = (const int*)d_in[25];
  const int* qnb      = (const int*)d_in[26];
  const int* snb      = (const int*)d_in[27];
  const int* cidx     = (const int*)d_in[28];
  const int* cmask    = (const int*)d_in[29];
  float* out = (float*)d_out;

  char* ws = (char*)d_ws;
  size_t off = 0;
  auto alloc = [&](size_t bytes) -> void* {
    void* p = ws + off;
    off += (bytes + 255) & ~(size_t)255;
    return p;
  };
  float* wih1aT = (float*)alloc(30000 * 4);
  float* erw    = (float*)alloc(600 * 4);
  float* waggT  = (float*)alloc(30000 * 4);
  float* wlastT = (float*)alloc(10000 * 4);
  float* wkeyT  = (float*)alloc(10000 * 4);
  float* scal   = (float*)alloc(4);
  float* gi1_all = (float*)alloc((size_t)B_ * T_ * 300 * 4);
  float* qw_all  = (float*)alloc((size_t)B_ * T_ * 5 * 4);
  int*   top10   = (int*)alloc((size_t)B_ * T_ * 10 * 4);

  hipLaunchKernelGGL(setupk, dim3(128), dim3(256), 0, stream,
      Er, W_ih1, b_ih1, Wagg, W_last, W_key, b_query, W_W,
      wih1aT, erw, waggT, wlastT, wkeyT, scal);

  hipLaunchKernelGGL(phaseA, dim3(T_, B_), dim3(256), 0, stream,
      Eq, Ec, question, response, mask, qnb, snb,
      wih1aT, erw, waggT, wlastT, bagg, b_last, gi1_all);

  hipLaunchKernelGGL(phaseB, dim3(T_, B_), dim3(128), 0, stream,
      Eq, Ec, question, cidx, cmask, wkeyT, b_key, W_W,
      qw_all, top10);

  hipLaunchKernelGGL(seqk, dim3(B_), dim3(512), 0, stream,
      gi1_all, W_hh1, W_hh2, W_ih2, b_hh1, b_hh2, b_ih2, b_query,
      W_query, W_W, b_W, qw_all, top10,
      Eq, Ec, question, cidx, cmask,
      h1_init, h2_init, scal, out);
}

// Round 8
// 1880.214 us; speedup vs baseline: 2.6389x; 1.2686x over previous
//
#include <hip/hip_runtime.h>
#include <math.h>

#define B_ 128
#define S_ 128
#define T_ 127
#define D_ 100
#define QN_ 4
#define SN_ 4
#define KC_ 4
#define RK_ 10
#define NEGV -1000000000.0f

__device__ __forceinline__ float sigmf(float x) { return 1.0f / (1.0f + expf(-x)); }

// ---------------------------------------------------------------------------
// Setup: transposed weights for phaseA/B; erw fold; kw0 scalar; and the
// lane-swizzled concatenated weight image for seqk:
//   wcat[r][sub][c] = W[r][sub*25+c] (c<25; c=25..27 zero pad), rows:
//   [0,300)=W_hh1, [300,600)=W_hh2, [600,900)=W_ih2, [900,1000)=W_query.
//   bcat[r] = matching bias.
// ---------------------------------------------------------------------------
__global__ __launch_bounds__(256) void setupk(
    const float* Er, const float* W_ih1, const float* b_ih1,
    const float* Wagg, const float* W_last, const float* W_key,
    const float* b_query, const float* W_W, const float* W_query,
    const float* W_hh1, const float* W_hh2, const float* W_ih2,
    const float* b_hh1, const float* b_hh2, const float* b_ih2,
    float* wih1aT, float* erw, float* waggT, float* wlastT, float* wkeyT,
    float* scal, float* wcat, float* bcat)
{
  int gid = blockIdx.x * blockDim.x + threadIdx.x;
  int gsz = gridDim.x * blockDim.x;

  for (int x = gid; x < 30000; x += gsz) {
    int j = x / 300, i = x % 300;
    wih1aT[j * 300 + i] = W_ih1[i * 200 + j];
  }
  for (int x = gid; x < 600; x += gsz) {
    int r = x / 300, i = x % 300;
    float acc = b_ih1[i];
    for (int j = 0; j < 100; j++) acc += Er[r * 100 + j] * W_ih1[i * 200 + 100 + j];
    erw[x] = acc;
  }
  for (int x = gid; x < 30000; x += gsz) {
    int h = x / 10000, rr = x % 10000, j = rr / 100, i = rr % 100;
    waggT[h * 10000 + j * 100 + i] = Wagg[h * 10000 + i * 100 + j];
  }
  for (int x = gid; x < 10000; x += gsz) {
    int j = x / 100, i = x % 100;
    wlastT[j * 100 + i] = W_last[i * 100 + j];
    wkeyT[j * 100 + i] = W_key[i * 100 + j];
  }
  // swizzled weight image (1000 x 112)
  for (int x = gid; x < 112000; x += gsz) {
    int r = x / 112, rem = x % 112, s = rem / 28, c = rem % 28;
    float v = 0.f;
    if (c < 25) {
      int col = s * 25 + c;
      if (r < 300)      v = W_hh1[r * 100 + col];
      else if (r < 600) v = W_hh2[(r - 300) * 100 + col];
      else if (r < 900) v = W_ih2[(r - 600) * 100 + col];
      else              v = W_query[(r - 900) * 100 + col];
    }
    wcat[x] = v;
  }
  for (int x = gid; x < 1000; x += gsz) {
    bcat[x] = (x < 300) ? b_hh1[x] : (x < 600) ? b_hh2[x - 300]
            : (x < 900) ? b_ih2[x - 600] : b_query[x - 900];
  }
  if (gid == 0) {
    float acc = 0.f;  // kw of the all-zero hist state: dot(tanh(b_query), Wk_part)
    for (int i = 0; i < 100; i++) acc += tanhf(b_query[i]) * W_W[100 + i];
    scal[0] = acc;
  }
}

// ---------------------------------------------------------------------------
// Phase A (unchanged): per (b,t) 3-hop aggregate -> gi1[b,t,0:300]
// ---------------------------------------------------------------------------
__global__ __launch_bounds__(256) void phaseA(
    const float* Eq, const float* Ec, const int* question, const int* response, const int* mask,
    const int* qnb, const int* snb,
    const float* wih1aT, const float* erw, const float* waggT, const float* wlastT,
    const float* baggf, const float* blastf, float* gi1_all)
{
  const int t = blockIdx.x, b = blockIdx.y, tid = threadIdx.x;
  __shared__ float e0[100], ne0[100], e1[400], ne1[400];
  __shared__ float e2[1600], ne2[1600], m3[1600];
  __shared__ float sum4[400], sum1[100], emq[100];
  __shared__ int l1[4], l2[16], l3[64];

  const int qt = question[b * S_ + t];
  const int mt = mask[b * S_ + t];
  const int rt = response[b * S_ + t];

  if (mt != 0) {
    if (tid < 4) l1[tid] = qnb[qt * QN_ + tid];
    for (int x = tid; x < 100; x += 256) e0[x] = Eq[(size_t)qt * 100 + x];
    __syncthreads();
    if (tid < 16) l2[tid] = snb[l1[tid >> 2] * SN_ + (tid & 3)];
    for (int x = tid; x < 400; x += 256) e1[x] = Ec[(size_t)l1[x / 100] * 100 + (x % 100)];
    __syncthreads();
    if (tid < 64) l3[tid] = qnb[l2[tid >> 2] * QN_ + (tid & 3)];
    for (int x = tid; x < 1600; x += 256) e2[x] = Eq[(size_t)l2[x / 100] * 100 + (x % 100)];
    __syncthreads();
    for (int x = tid; x < 1600; x += 256) {
      int r = x / 100, j = x % 100;
      const int* lr = l3 + r * 4;
      float s = Ec[(size_t)lr[0] * 100 + j] + Ec[(size_t)lr[1] * 100 + j] +
                Ec[(size_t)lr[2] * 100 + j] + Ec[(size_t)lr[3] * 100 + j];
      m3[x] = e2[x] + 0.25f * s;
    }
    for (int x = tid; x < 100; x += 256)
      sum1[x] = e0[x] + 0.25f * (e1[x] + e1[100 + x] + e1[200 + x] + e1[300 + x]);
    for (int x = tid; x < 400; x += 256) {
      int k = x / 100, j = x % 100;
      const float* e2k = e2 + k * 400;
      sum4[x] = e1[x] + 0.25f * (e2k[j] + e2k[100 + j] + e2k[200 + j] + e2k[300 + j]);
    }
    __syncthreads();
    for (int o = tid; o < 2100; o += 256) {
      const float *in, *W;
      float bia;
      float* dst;
      int i = o % 100;
      if (o < 100)      { in = sum1;                           W = waggT;          bia = baggf[i];       dst = ne0 + o; }
      else if (o < 500) { in = sum4 + ((o - 100) / 100) * 100; W = waggT + 10000;  bia = baggf[100 + i]; dst = ne1 + (o - 100); }
      else              { in = m3 + ((o - 500) / 100) * 100;   W = waggT + 20000;  bia = baggf[200 + i]; dst = ne2 + (o - 500); }
      float acc = bia;
      for (int j = 0; j < 100; j++) acc += in[j] * W[j * 100 + i];
      *dst = tanhf(acc);
    }
    __syncthreads();
    for (int x = tid; x < 100; x += 256)
      sum1[x] = ne0[x] + 0.25f * (ne1[x] + ne1[100 + x] + ne1[200 + x] + ne1[300 + x]);
    for (int x = tid; x < 400; x += 256) {
      int k = x / 100, j = x % 100;
      const float* n2k = ne2 + k * 400;
      sum4[x] = ne1[x] + 0.25f * (n2k[j] + n2k[100 + j] + n2k[200 + j] + n2k[300 + j]);
    }
    __syncthreads();
    for (int o = tid; o < 500; o += 256) {
      int i = o % 100;
      if (o < 100) {
        float acc = baggf[i];
        for (int j = 0; j < 100; j++) acc += sum1[j] * waggT[j * 100 + i];
        e0[i] = tanhf(acc);
      } else {
        const float* in = sum4 + ((o - 100) / 100) * 100;
        float acc = baggf[100 + i];
        for (int j = 0; j < 100; j++) acc += in[j] * waggT[10000 + j * 100 + i];
        e1[o - 100] = tanhf(acc);
      }
    }
    __syncthreads();
    for (int x = tid; x < 100; x += 256)
      sum1[x] = e0[x] + 0.25f * (e1[x] + e1[100 + x] + e1[200 + x] + e1[300 + x]);
    __syncthreads();
    for (int o = tid; o < 100; o += 256) {
      float acc = baggf[o];
      for (int j = 0; j < 100; j++) acc += sum1[j] * waggT[j * 100 + o];
      ne0[o] = tanhf(acc);
    }
    __syncthreads();
    for (int o = tid; o < 100; o += 256) {
      float acc = blastf[o];
      for (int j = 0; j < 100; j++) acc += ne0[j] * wlastT[j * 100 + o];
      emq[o] = tanhf(acc);
    }
    __syncthreads();
  } else {
    for (int x = tid; x < 100; x += 256) emq[x] = Eq[(size_t)qt * 100 + x];
    __syncthreads();
  }

  const size_t bt = (size_t)b * T_ + t;
  for (int o = tid; o < 300; o += 256) {
    float acc = erw[rt * 300 + o];
    for (int j = 0; j < 100; j++) acc += emq[j] * wih1aT[j * 300 + o];
    gi1_all[bt * 300 + o] = acc;
  }
}

// ---------------------------------------------------------------------------
// Phase B (unchanged): qw[5] and top-10 indices per (b,t).
// ---------------------------------------------------------------------------
__global__ __launch_bounds__(128) void phaseB(
    const float* Eq, const float* Ec, const int* question, const int* cidx, const int* cmask,
    const float* wkeyT, const float* b_key, const float* W_W,
    float* qw_all, int* top10_all)
{
  const int t = blockIdx.x, b = blockIdx.y, tid = threadIdx.x;
  const size_t bt = (size_t)b * T_ + t;
  __shared__ float qcf[500];
  __shared__ float qtl[500];
  __shared__ float qwp[20];
  __shared__ float orig[128];
  __shared__ float sval[128];
  __shared__ int sidx[128];
  __shared__ int ci[4], cm[4];

  const int qn = question[b * S_ + t + 1];
  if (tid < 4) { ci[tid] = cidx[qn * KC_ + tid]; cm[tid] = cmask[qn * KC_ + tid]; }
  __syncthreads();

  for (int u = tid; u < 500; u += 128) {
    int row = u / 100, j = u % 100;
    float v;
    if (row == 0) v = Eq[(size_t)qn * 100 + j];
    else {
      int k = row - 1;
      v = cm[k] ? Ec[(size_t)ci[k] * 100 + j] : 0.f;
    }
    qcf[u] = v;
  }
  __syncthreads();
  for (int o = tid; o < 500; o += 128) {
    int q = o / 100, i = o % 100;
    float acc = b_key[i];
    const float* src = qcf + q * 100;
    for (int j = 0; j < 100; j++) acc += src[j] * wkeyT[j * 100 + i];
    qtl[o] = tanhf(acc);
  }
  __syncthreads();
  if (tid < 20) {
    int q = tid / 4, part = tid % 4;
    float acc = 0.f;
    for (int j = part * 25; j < part * 25 + 25; j++) acc += qtl[q * 100 + j] * W_W[j];
    qwp[tid] = acc;
  }
  __syncthreads();
  if (tid < 5) qw_all[bt * 5 + tid] = qwp[tid * 4] + qwp[tid * 4 + 1] + qwp[tid * 4 + 2] + qwp[tid * 4 + 3];

  if (t > RK_) {
    float sc = -__builtin_inff();
    if (tid < t) {
      int qs = question[b * S_ + tid];
      float acc = 0.f;
      for (int j = 0; j < 100; j++) acc += Eq[(size_t)qs * 100 + j] * qcf[j];
      sc = acc;
    }
    orig[tid] = sc;
    __syncthreads();
    for (int pass = 0; pass < 10; pass++) {
      sval[tid] = orig[tid];
      sidx[tid] = tid;
      __syncthreads();
      for (int offt = 64; offt > 0; offt >>= 1) {
        if (tid < offt) {
          float v2 = sval[tid + offt];
          int i2 = sidx[tid + offt];
          if (v2 > sval[tid] || (v2 == sval[tid] && i2 < sidx[tid])) { sval[tid] = v2; sidx[tid] = i2; }
        }
        __syncthreads();
      }
      if (tid == 0) top10_all[bt * 10 + pass] = sidx[0];
      if (tid == sidx[0]) orig[tid] = -__builtin_inff();
      __syncthreads();
    }
  }
}

// ---------------------------------------------------------------------------
// mat rows helper: 4-lane-group dot over the swizzled weight image.
// Group g computes rows r = r0+g, r0+g+128, ... < r1. Lane sub holds the
// source slice src[sub*25 .. +25] in registers (hr[28], pad zeros).
// ---------------------------------------------------------------------------
__device__ __forceinline__ void mat_rows(
    const float* __restrict__ wcat, const float* __restrict__ bres,
    int r0, int r1, const float hr[28], float* dst, int dstOff, int grp, int sub)
{
  for (int r = r0 + grp; r < r1; r += 128) {
    const float4* wp = (const float4*)(wcat + (size_t)r * 112 + sub * 28);
    float a = 0.f;
#pragma unroll
    for (int c = 0; c < 7; ++c) {
      float4 w = wp[c];
      a = fmaf(w.x, hr[4 * c], a);
      a = fmaf(w.y, hr[4 * c + 1], a);
      a = fmaf(w.z, hr[4 * c + 2], a);
      a = fmaf(w.w, hr[4 * c + 3], a);
    }
    a += __shfl_xor(a, 1);
    a += __shfl_xor(a, 2);
    if (sub == 0) dst[r - dstOff] = a + bres[r];
  }
}

// ---------------------------------------------------------------------------
// Sequential scan v4: 512 threads, 128 blocks (1 row each). Weights streamed
// per step from ONE shared L2-resident swizzled image (no scratch, no pin).
// All 128 4-lane groups work in every matvec phase; source vectors live in
// 25 lane-registers (one conflict-free LDS broadcast per phase). LDS ~18 KB.
// ---------------------------------------------------------------------------
__global__ __launch_bounds__(512) void seqk(
    const float* wcat, const float* bcat,
    const float* gi1_all, const float* qw_all, const int* top10_all,
    const float* W_W, const float* b_W,
    const float* Eq, const float* Ec, const int* question, const int* cidx, const int* cmask,
    const float* h1_init, const float* h2_init, const float* scal,
    float* g2h, float* out)
{
  const int b = blockIdx.x, tid = threadIdx.x;
  const int grp = tid >> 2, sub = tid & 3;

  __shared__ __align__(16) float h1[100], h2[100], h1n[100], g2v[100];
  __shared__ float gh[600], gi2v[300], kqs[100];
  __shared__ float gi1d[2][300];
  __shared__ float qcd[2][500];
  __shared__ float qwd[2][5];
  __shared__ int topd[2][10];
  __shared__ float kwhist[128];
  __shared__ float ogs[55];
  __shared__ float pqS[5];
  __shared__ float bres[1100];   // bcat[1000] + Wk_part[100]
  __shared__ int cidS[8];
  __shared__ int qnS, qn0S;
  __shared__ float kwcur;

  for (int x = tid; x < 1000; x += 512) bres[x] = bcat[x];
  if (tid < 100) bres[1000 + tid] = W_W[100 + tid];

  const float bWv = b_W[0];
  const float kw0 = scal[0];
  float* g2hb = g2h + (size_t)b * (T_ * 100);

  if (tid < 100) {
    h1[tid] = h1_init[b * 100 + tid];
    h2[tid] = h2_init[b * 100 + tid];
    g2hb[tid] = 0.f;  // history row 0 stays zero
  }
  if (tid < 128) kwhist[tid] = kw0;
  if (tid >= 300 && tid < 450) {
    int i = 2 * (tid - 300);
    const float* g0 = gi1_all + (size_t)b * T_ * 300;
    gi1d[0][i] = g0[i]; gi1d[0][i + 1] = g0[i + 1];
  }
  if (tid >= 450 && tid < 455) qwd[0][tid - 450] = qw_all[(size_t)b * T_ * 5 + (tid - 450)];
  if (tid == 473) qnS = question[b * S_ + 2];
  if (tid < 8) {
    int qn0 = question[b * S_ + 1];
    if (tid == 0) qn0S = qn0;
    cidS[tid] = (tid < 4) ? cidx[qn0 * KC_ + tid] : cmask[qn0 * KC_ + tid - 4];
  }
  __syncthreads();
  if (tid < 250) {
    int qn0 = qn0S;
#pragma unroll
    for (int e = 0; e < 2; ++e) {
      int idx = 2 * tid + e;
      int q = idx / 100, j = idx % 100;
      float v;
      if (q == 0) v = Eq[(size_t)qn0 * 100 + j];
      else v = cidS[4 + q - 1] ? Ec[(size_t)cidS[q - 1] * 100 + j] : 0.f;
      qcd[0][idx] = v;
    }
  }
  __syncthreads();

  for (int t = 0; t < T_; ++t) {
    const size_t bt = (size_t)b * T_ + t;
    const int cur = t & 1, nxt = cur ^ 1;
    const bool pf = (t + 1) < T_;

    // ---- S1: gh (600 rows, all groups) + prefetch issue ----
    float hr[28];
    hr[25] = hr[26] = hr[27] = 0.f;
#pragma unroll
    for (int c = 0; c < 25; ++c) hr[c] = h1[sub * 25 + c];
    mat_rows(wcat, bres, 0, 300, hr, gh, 0, grp, sub);
#pragma unroll
    for (int c = 0; c < 25; ++c) hr[c] = h2[sub * 25 + c];
    mat_rows(wcat, bres, 300, 600, hr, gh, 0, grp, sub);

    float pgi0 = 0.f, pgi1 = 0.f, pqw = 0.f;
    int ptop = 0, pci = 0, pqn2 = 0;
    if (pf) {
      if (tid >= 300 && tid < 450) {
        int i = 2 * (tid - 300);
        const float* g1 = gi1_all + (bt + 1) * 300;
        pgi0 = g1[i]; pgi1 = g1[i + 1];
      } else if (tid >= 450 && tid < 455) {
        pqw = qw_all[(bt + 1) * 5 + (tid - 450)];
      } else if (tid >= 455 && tid < 465) {
        if ((t + 1) > RK_) ptop = top10_all[(bt + 1) * 10 + (tid - 455)];
      } else if (tid >= 465 && tid < 473) {
        int k = tid - 465;
        int qn = qnS;
        pci = (k < 4) ? cidx[qn * KC_ + k] : cmask[qn * KC_ + k - 4];
      } else if (tid == 473) {
        if (t + 3 < S_) pqn2 = question[b * S_ + t + 3];
      }
    }
    __syncthreads();  // b1: gh visible

    // ---- S2: GRU1 -> h1n | publish cidS(t+1) ----
    if (tid < 100) {
      int j = tid;
      float rg = sigmf(gi1d[cur][j] + gh[j]);
      float z  = sigmf(gi1d[cur][100 + j] + gh[100 + j]);
      float n  = tanhf(gi1d[cur][200 + j] + rg * gh[200 + j]);
      h1n[j] = (1.f - z) * n + z * h1[j];
    } else if (tid >= 465 && tid < 473 && pf) {
      cidS[tid - 465] = pci;
    }
    __syncthreads();  // b2: h1n + cidS visible

    // ---- S3: gi2 (300 rows, all groups) + qc gather issue ----
#pragma unroll
    for (int c = 0; c < 25; ++c) hr[c] = h1n[sub * 25 + c];
    mat_rows(wcat, bres, 600, 900, hr, gi2v, 600, grp, sub);

    float pqc0 = 0.f, pqc1 = 0.f;
    if (pf && tid < 250) {
      int qn = qnS;
#pragma unroll
      for (int e = 0; e < 2; ++e) {
        int idx = 2 * tid + e;
        int q = idx / 100, j = idx % 100;
        float v;
        if (q == 0) v = Eq[(size_t)qn * 100 + j];
        else v = cidS[4 + q - 1] ? Ec[(size_t)cidS[q - 1] * 100 + j] : 0.f;
        if (e == 0) pqc0 = v; else pqc1 = v;
      }
    }
    __syncthreads();  // b3: gi2 visible

    // ---- S4: GRU2 -> g2v ----
    if (tid < 100) {
      int j = tid;
      float rg = sigmf(gi2v[j] + gh[300 + j]);
      float z  = sigmf(gi2v[100 + j] + gh[400 + j]);
      float n  = tanhf(gi2v[200 + j] + rg * gh[500 + j]);
      g2v[j] = (1.f - z) * n + z * h2[j];
    }
    __syncthreads();  // b4: g2v visible

    // ---- S5: og (groups 0-54) | W_query -> kqs (groups 64-127) ----
#pragma unroll
    for (int c = 0; c < 25; ++c) hr[c] = g2v[sub * 25 + c];
    if (grp < 55) {
      int s = grp / 5, q = grp % 5;
      const float* qcr = &qcd[cur][q * 100 + sub * 25];
      float a = 0.f;
      if (s == 0) {
#pragma unroll
        for (int c = 0; c < 25; ++c) a = fmaf(qcr[c], hr[c], a);
      } else {
        bool valid = (t > RK_) || (s - 1 < t);
        if (valid) {
          int idx = (t > RK_) ? topd[cur][s - 1] : (s - 1);
          const float* hrow = g2hb + (size_t)idx * 100 + sub * 25;
#pragma unroll
          for (int c = 0; c < 25; ++c) a = fmaf(qcr[c], hrow[c], a);
        }
      }
      a += __shfl_xor(a, 1);
      a += __shfl_xor(a, 2);
      if (sub == 0) ogs[grp] = a;
    } else if (grp >= 64) {
#pragma unroll
      for (int it = 0; it < 2; ++it) {
        int r = 900 + (grp - 64) + it * 64;
        if (r < 1000) {
          const float4* wp = (const float4*)(wcat + (size_t)r * 112 + sub * 28);
          float a = 0.f;
#pragma unroll
          for (int c = 0; c < 7; ++c) {
            float4 w = wp[c];
            a = fmaf(w.x, hr[4 * c], a);
            a = fmaf(w.y, hr[4 * c + 1], a);
            a = fmaf(w.z, hr[4 * c + 2], a);
            a = fmaf(w.w, hr[4 * c + 3], a);
          }
          a += __shfl_xor(a, 1);
          a += __shfl_xor(a, 2);
          if (sub == 0) kqs[r - 900] = tanhf(a + bres[r]) * bres[1000 + (r - 900)];
        }
      }
    }
    __syncthreads();  // b5: ogs + kqs visible

    // ---- S6: kw reduce (wave 0) ----
    if (tid < 64) {
      float v = (tid < 50) ? (kqs[tid] + kqs[tid + 50]) : 0.f;
      v += __shfl_xor(v, 1);
      v += __shfl_xor(v, 2);
      v += __shfl_xor(v, 4);
      v += __shfl_xor(v, 8);
      v += __shfl_xor(v, 16);
      v += __shfl_xor(v, 32);
      if (tid == 0) kwcur = v;
    }
    __syncthreads();  // b6: kwcur visible

    // ---- S7: softmax | state updates | dbuf commits ----
    if (tid < 5) {
      const int q = tid;
      const float qw = qwd[cur][q];
      float tmp[11];
      float m = -__builtin_inff();
#pragma unroll
      for (int s = 0; s < 11; ++s) {
        float kws;
        bool valid;
        if (s == 0) { kws = kwcur; valid = true; }
        else if (t > RK_) { kws = kwhist[topd[cur][s - 1]]; valid = true; }
        else { valid = (s - 1 < t); kws = kwhist[s - 1]; }
        float tv = valid ? (qw + kws + bWv) : NEGV;
        tmp[s] = tv;
        m = fmaxf(m, tv);
      }
      float den = 0.f, num = 0.f;
#pragma unroll
      for (int s = 0; s < 11; ++s) {
        float e = expf(tmp[s] - m);
        den += e;
        num += e * ogs[s * 5 + q];
      }
      pqS[q] = num / den;
    } else if (tid == 8) {
      if (t > 0) kwhist[t] = kwcur;
    }
    if (tid >= 100 && tid < 200) {
      h1[tid - 100] = h1n[tid - 100];
    } else if (tid >= 200 && tid < 300) {
      if (t > 0) {
        int j = tid - 200;
        h2[j] = g2v[j];
        g2hb[t * 100 + j] = g2v[j];
      }
    }
    if (pf) {
      if (tid < 250) {
        qcd[nxt][2 * tid] = pqc0;
        qcd[nxt][2 * tid + 1] = pqc1;
      } else if (tid >= 300 && tid < 450) {
        int i = 2 * (tid - 300);
        gi1d[nxt][i] = pgi0; gi1d[nxt][i + 1] = pgi1;
      } else if (tid >= 450 && tid < 455) {
        qwd[nxt][tid - 450] = pqw;
      } else if (tid >= 455 && tid < 465) {
        if ((t + 1) > RK_) topd[nxt][tid - 455] = min(T_ - 1, max(0, ptop));
      } else if (tid == 473) {
        if (t + 3 < S_) qnS = pqn2;
      }
    }
    __syncthreads();  // b7: everything committed

    // ---- S8: final sum + store ----
    if (tid == 0) {
      float p = pqS[0] + pqS[1] + pqS[2] + pqS[3] + pqS[4];
      int col = (t == 0) ? 0 : (t + 1);
      out[b * S_ + col] = p;
      if (t == 0) out[b * S_ + 1] = 0.f;  // col 1 never written by ref
    }
  }
}

// ---------------------------------------------------------------------------
extern "C" void kernel_launch(void* const* d_in, const int* in_sizes, int n_in,
                              void* d_out, int out_size, void* d_ws, size_t ws_size,
                              hipStream_t stream)
{
  (void)in_sizes; (void)n_in; (void)out_size; (void)ws_size;
  const float* Eq     = (const float*)d_in[0];
  const float* Ec     = (const float*)d_in[1];
  const float* Er     = (const float*)d_in[2];
  const float* W_ih1  = (const float*)d_in[3];
  const float* W_hh1  = (const float*)d_in[4];
  const float* b_ih1  = (const float*)d_in[5];
  const float* b_hh1  = (const float*)d_in[6];
  const float* W_ih2  = (const float*)d_in[7];
  const float* W_hh2  = (const float*)d_in[8];
  const float* b_ih2  = (const float*)d_in[9];
  const float* b_hh2  = (const float*)d_in[10];
  const float* Wagg   = (const float*)d_in[11];
  const float* bagg   = (const float*)d_in[12];
  const float* W_last = (const float*)d_in[13];
  const float* b_last = (const float*)d_in[14];
  const float* W_query= (const float*)d_in[15];
  const float* b_query= (const float*)d_in[16];
  const float* W_key  = (const float*)d_in[17];
  const float* b_key  = (const float*)d_in[18];
  const float* W_W    = (const float*)d_in[19];
  const float* b_W    = (const float*)d_in[20];
  const float* h1_init= (const float*)d_in[21];
  const float* h2_init= (const float*)d_in[22];
  const int* question = (const int*)d_in[23];
  const int* response = (const int*)d_in[24];
  const int* mask     = (const int*)d_in[25];
  const int* qnb      = (const int*)d_in[26];
  const int* snb      = (const int*)d_in[27];
  const int* cidx     = (const int*)d_in[28];
  const int* cmask    = (const int*)d_in[29];
  float* out = (float*)d_out;

  char* ws = (char*)d_ws;
  size_t off = 0;
  auto alloc = [&](size_t bytes) -> void* {
    void* p = ws + off;
    off += (bytes + 255) & ~(size_t)255;
    return p;
  };
  float* wih1aT = (float*)alloc(30000 * 4);
  float* erw    = (float*)alloc(600 * 4);
  float* waggT  = (float*)alloc(30000 * 4);
  float* wlastT = (float*)alloc(10000 * 4);
  float* wkeyT  = (float*)alloc(10000 * 4);
  float* scal   = (float*)alloc(4);
  float* wcat   = (float*)alloc(112000 * 4);
  float* bcat   = (float*)alloc(1000 * 4);
  float* gi1_all = (float*)alloc((size_t)B_ * T_ * 300 * 4);
  float* qw_all  = (float*)alloc((size_t)B_ * T_ * 5 * 4);
  int*   top10   = (int*)alloc((size_t)B_ * T_ * 10 * 4);
  float* g2h     = (float*)alloc((size_t)B_ * T_ * 100 * 4);

  hipLaunchKernelGGL(setupk, dim3(128), dim3(256), 0, stream,
      Er, W_ih1, b_ih1, Wagg, W_last, W_key, b_query, W_W, W_query,
      W_hh1, W_hh2, W_ih2, b_hh1, b_hh2, b_ih2,
      wih1aT, erw, waggT, wlastT, wkeyT, scal, wcat, bcat);

  hipLaunchKernelGGL(phaseA, dim3(T_, B_), dim3(256), 0, stream,
      Eq, Ec, question, response, mask, qnb, snb,
      wih1aT, erw, waggT, wlastT, bagg, b_last, gi1_all);

  hipLaunchKernelGGL(phaseB, dim3(T_, B_), dim3(128), 0, stream,
      Eq, Ec, question, cidx, cmask, wkeyT, b_key, W_W,
      qw_all, top10);

  hipLaunchKernelGGL(seqk, dim3(B_), dim3(512), 0, stream,
      wcat, bcat, gi1_all, qw_all, top10, W_W, b_W,
      Eq, Ec, question, cidx, cmask,
      h1_init, h2_init, scal, g2h, out);
}

// Round 10
// 1871.572 us; speedup vs baseline: 2.6511x; 1.0046x over previous
//
#include <hip/hip_runtime.h>
#include <math.h>

#define B_ 128
#define S_ 128
#define T_ 127
#define D_ 100
#define QN_ 4
#define SN_ 4
#define KC_ 4
#define RK_ 10
#define NEGV -1000000000.0f

__device__ __forceinline__ float sigmf(float x) { return 1.0f / (1.0f + expf(-x)); }

// ---------------------------------------------------------------------------
// Setup: transposed weights for phaseA/B; erw fold; kw0 scalar; and the
// PADDED lane-swizzled weight image for seqk (1280 slots x 112 floats):
//   [0,384):   W_hh1 rows 0-299 (+84 zero pad)   -> gh[0:300]
//   [384,768): W_hh2 rows 0-299 (+84 pad)        -> gh[300:600]
//   [768,1152):W_ih2 rows 0-299 (+84 pad)        -> gi2
//   [1152,1280):W_query rows 0-99 (+28 pad)      -> kq
// slot layout: [sub][c], c<25 real col sub*25+c, c=25..27 zero.
// bcat[slot] = matching bias (0 on pads).
// ---------------------------------------------------------------------------
__global__ __launch_bounds__(256) void setupk(
    const float* Er, const float* W_ih1, const float* b_ih1,
    const float* Wagg, const float* W_last, const float* W_key,
    const float* b_query, const float* W_W, const float* W_query,
    const float* W_hh1, const float* W_hh2, const float* W_ih2,
    const float* b_hh1, const float* b_hh2, const float* b_ih2,
    float* wih1aT, float* erw, float* waggT, float* wlastT, float* wkeyT,
    float* scal, float* wcat, float* bcat)
{
  int gid = blockIdx.x * blockDim.x + threadIdx.x;
  int gsz = gridDim.x * blockDim.x;

  for (int x = gid; x < 30000; x += gsz) {
    int j = x / 300, i = x % 300;
    wih1aT[j * 300 + i] = W_ih1[i * 200 + j];
  }
  for (int x = gid; x < 600; x += gsz) {
    int r = x / 300, i = x % 300;
    float acc = b_ih1[i];
    for (int j = 0; j < 100; j++) acc += Er[r * 100 + j] * W_ih1[i * 200 + 100 + j];
    erw[x] = acc;
  }
  for (int x = gid; x < 30000; x += gsz) {
    int h = x / 10000, rr = x % 10000, j = rr / 100, i = rr % 100;
    waggT[h * 10000 + j * 100 + i] = Wagg[h * 10000 + i * 100 + j];
  }
  for (int x = gid; x < 10000; x += gsz) {
    int j = x / 100, i = x % 100;
    wlastT[j * 100 + i] = W_last[i * 100 + j];
    wkeyT[j * 100 + i] = W_key[i * 100 + j];
  }
  // padded swizzled weight image (1280 x 112)
  for (int x = gid; x < 143360; x += gsz) {
    int slot = x / 112, rem = x % 112, s = rem / 28, c = rem % 28;
    float v = 0.f;
    if (c < 25) {
      int col = s * 25 + c;
      int reg = slot / 384;
      int r = slot - reg * 384;
      if (slot >= 1152) { reg = 3; r = slot - 1152; }
      if (reg == 0 && r < 300)      v = W_hh1[r * 100 + col];
      else if (reg == 1 && r < 300) v = W_hh2[r * 100 + col];
      else if (reg == 2 && r < 300) v = W_ih2[r * 100 + col];
      else if (reg == 3 && r < 100) v = W_query[r * 100 + col];
    }
    wcat[x] = v;
  }
  for (int x = gid; x < 1280; x += gsz) {
    float v = 0.f;
    int reg = (x >= 1152) ? 3 : (x / 384);
    int r = (x >= 1152) ? (x - 1152) : (x - reg * 384);
    if (reg == 0 && r < 300) v = b_hh1[r];
    else if (reg == 1 && r < 300) v = b_hh2[r];
    else if (reg == 2 && r < 300) v = b_ih2[r];
    else if (reg == 3 && r < 100) v = b_query[r];
    bcat[x] = v;
  }
  if (gid == 0) {
    float acc = 0.f;  // kw of the all-zero hist state: dot(tanh(b_query), Wk_part)
    for (int i = 0; i < 100; i++) acc += tanhf(b_query[i]) * W_W[100 + i];
    scal[0] = acc;
  }
}

// ---------------------------------------------------------------------------
// Phase A (unchanged): per (b,t) 3-hop aggregate -> gi1[b,t,0:300]
// ---------------------------------------------------------------------------
__global__ __launch_bounds__(256) void phaseA(
    const float* Eq, const float* Ec, const int* question, const int* response, const int* mask,
    const int* qnb, const int* snb,
    const float* wih1aT, const float* erw, const float* waggT, const float* wlastT,
    const float* baggf, const float* blastf, float* gi1_all)
{
  const int t = blockIdx.x, b = blockIdx.y, tid = threadIdx.x;
  __shared__ float e0[100], ne0[100], e1[400], ne1[400];
  __shared__ float e2[1600], ne2[1600], m3[1600];
  __shared__ float sum4[400], sum1[100], emq[100];
  __shared__ int l1[4], l2[16], l3[64];

  const int qt = question[b * S_ + t];
  const int mt = mask[b * S_ + t];
  const int rt = response[b * S_ + t];

  if (mt != 0) {
    if (tid < 4) l1[tid] = qnb[qt * QN_ + tid];
    for (int x = tid; x < 100; x += 256) e0[x] = Eq[(size_t)qt * 100 + x];
    __syncthreads();
    if (tid < 16) l2[tid] = snb[l1[tid >> 2] * SN_ + (tid & 3)];
    for (int x = tid; x < 400; x += 256) e1[x] = Ec[(size_t)l1[x / 100] * 100 + (x % 100)];
    __syncthreads();
    if (tid < 64) l3[tid] = qnb[l2[tid >> 2] * QN_ + (tid & 3)];
    for (int x = tid; x < 1600; x += 256) e2[x] = Eq[(size_t)l2[x / 100] * 100 + (x % 100)];
    __syncthreads();
    for (int x = tid; x < 1600; x += 256) {
      int r = x / 100, j = x % 100;
      const int* lr = l3 + r * 4;
      float s = Ec[(size_t)lr[0] * 100 + j] + Ec[(size_t)lr[1] * 100 + j] +
                Ec[(size_t)lr[2] * 100 + j] + Ec[(size_t)lr[3] * 100 + j];
      m3[x] = e2[x] + 0.25f * s;
    }
    for (int x = tid; x < 100; x += 256)
      sum1[x] = e0[x] + 0.25f * (e1[x] + e1[100 + x] + e1[200 + x] + e1[300 + x]);
    for (int x = tid; x < 400; x += 256) {
      int k = x / 100, j = x % 100;
      const float* e2k = e2 + k * 400;
      sum4[x] = e1[x] + 0.25f * (e2k[j] + e2k[100 + j] + e2k[200 + j] + e2k[300 + j]);
    }
    __syncthreads();
    for (int o = tid; o < 2100; o += 256) {
      const float *in, *W;
      float bia;
      float* dst;
      int i = o % 100;
      if (o < 100)      { in = sum1;                           W = waggT;          bia = baggf[i];       dst = ne0 + o; }
      else if (o < 500) { in = sum4 + ((o - 100) / 100) * 100; W = waggT + 10000;  bia = baggf[100 + i]; dst = ne1 + (o - 100); }
      else              { in = m3 + ((o - 500) / 100) * 100;   W = waggT + 20000;  bia = baggf[200 + i]; dst = ne2 + (o - 500); }
      float acc = bia;
      for (int j = 0; j < 100; j++) acc += in[j] * W[j * 100 + i];
      *dst = tanhf(acc);
    }
    __syncthreads();
    for (int x = tid; x < 100; x += 256)
      sum1[x] = ne0[x] + 0.25f * (ne1[x] + ne1[100 + x] + ne1[200 + x] + ne1[300 + x]);
    for (int x = tid; x < 400; x += 256) {
      int k = x / 100, j = x % 100;
      const float* n2k = ne2 + k * 400;
      sum4[x] = ne1[x] + 0.25f * (n2k[j] + n2k[100 + j] + n2k[200 + j] + n2k[300 + j]);
    }
    __syncthreads();
    for (int o = tid; o < 500; o += 256) {
      int i = o % 100;
      if (o < 100) {
        float acc = baggf[i];
        for (int j = 0; j < 100; j++) acc += sum1[j] * waggT[j * 100 + i];
        e0[i] = tanhf(acc);
      } else {
        const float* in = sum4 + ((o - 100) / 100) * 100;
        float acc = baggf[100 + i];
        for (int j = 0; j < 100; j++) acc += in[j] * waggT[10000 + j * 100 + i];
        e1[o - 100] = tanhf(acc);
      }
    }
    __syncthreads();
    for (int x = tid; x < 100; x += 256)
      sum1[x] = e0[x] + 0.25f * (e1[x] + e1[100 + x] + e1[200 + x] + e1[300 + x]);
    __syncthreads();
    for (int o = tid; o < 100; o += 256) {
      float acc = baggf[o];
      for (int j = 0; j < 100; j++) acc += sum1[j] * waggT[j * 100 + o];
      ne0[o] = tanhf(acc);
    }
    __syncthreads();
    for (int o = tid; o < 100; o += 256) {
      float acc = blastf[o];
      for (int j = 0; j < 100; j++) acc += ne0[j] * wlastT[j * 100 + o];
      emq[o] = tanhf(acc);
    }
    __syncthreads();
  } else {
    for (int x = tid; x < 100; x += 256) emq[x] = Eq[(size_t)qt * 100 + x];
    __syncthreads();
  }

  const size_t bt = (size_t)b * T_ + t;
  for (int o = tid; o < 300; o += 256) {
    float acc = erw[rt * 300 + o];
    for (int j = 0; j < 100; j++) acc += emq[j] * wih1aT[j * 300 + o];
    gi1_all[bt * 300 + o] = acc;
  }
}

// ---------------------------------------------------------------------------
// Phase B (unchanged): qw[5] and top-10 indices per (b,t).
// ---------------------------------------------------------------------------
__global__ __launch_bounds__(128) void phaseB(
    const float* Eq, const float* Ec, const int* question, const int* cidx, const int* cmask,
    const float* wkeyT, const float* b_key, const float* W_W,
    float* qw_all, int* top10_all)
{
  const int t = blockIdx.x, b = blockIdx.y, tid = threadIdx.x;
  const size_t bt = (size_t)b * T_ + t;
  __shared__ float qcf[500];
  __shared__ float qtl[500];
  __shared__ float qwp[20];
  __shared__ float orig[128];
  __shared__ float sval[128];
  __shared__ int sidx[128];
  __shared__ int ci[4], cm[4];

  const int qn = question[b * S_ + t + 1];
  if (tid < 4) { ci[tid] = cidx[qn * KC_ + tid]; cm[tid] = cmask[qn * KC_ + tid]; }
  __syncthreads();

  for (int u = tid; u < 500; u += 128) {
    int row = u / 100, j = u % 100;
    float v;
    if (row == 0) v = Eq[(size_t)qn * 100 + j];
    else {
      int k = row - 1;
      v = cm[k] ? Ec[(size_t)ci[k] * 100 + j] : 0.f;
    }
    qcf[u] = v;
  }
  __syncthreads();
  for (int o = tid; o < 500; o += 128) {
    int q = o / 100, i = o % 100;
    float acc = b_key[i];
    const float* src = qcf + q * 100;
    for (int j = 0; j < 100; j++) acc += src[j] * wkeyT[j * 100 + i];
    qtl[o] = tanhf(acc);
  }
  __syncthreads();
  if (tid < 20) {
    int q = tid / 4, part = tid % 4;
    float acc = 0.f;
    for (int j = part * 25; j < part * 25 + 25; j++) acc += qtl[q * 100 + j] * W_W[j];
    qwp[tid] = acc;
  }
  __syncthreads();
  if (tid < 5) qw_all[bt * 5 + tid] = qwp[tid * 4] + qwp[tid * 4 + 1] + qwp[tid * 4 + 2] + qwp[tid * 4 + 3];

  if (t > RK_) {
    float sc = -__builtin_inff();
    if (tid < t) {
      int qs = question[b * S_ + tid];
      float acc = 0.f;
      for (int j = 0; j < 100; j++) acc += Eq[(size_t)qs * 100 + j] * qcf[j];
      sc = acc;
    }
    orig[tid] = sc;
    __syncthreads();
    for (int pass = 0; pass < 10; pass++) {
      sval[tid] = orig[tid];
      sidx[tid] = tid;
      __syncthreads();
      for (int offt = 64; offt > 0; offt >>= 1) {
        if (tid < offt) {
          float v2 = sval[tid + offt];
          int i2 = sidx[tid + offt];
          if (v2 > sval[tid] || (v2 == sval[tid] && i2 < sidx[tid])) { sval[tid] = v2; sidx[tid] = i2; }
        }
        __syncthreads();
      }
      if (tid == 0) top10_all[bt * 10 + pass] = sidx[0];
      if (tid == sidx[0]) orig[tid] = -__builtin_inff();
      __syncthreads();
    }
  }
}

// ---------------------------------------------------------------------------
// mat_region: fixed trip count NIT, double-buffered weight loads (load iter
// i+1 before computing iter i -> 14 float4 in flight). Slots base+grp+128*i;
// real rows r<nreal get dst[r] = dot + bres[base+r].
// ---------------------------------------------------------------------------
template<int NIT>
__device__ __forceinline__ void mat_region(
    const float* __restrict__ wimg, const float* __restrict__ bres,
    int base, int nreal, const float hr[28], float* dst, int grp, int sub)
{
  float4 wbuf[2][7];
  {
    const float4* wp = (const float4*)(wimg + (size_t)(base + grp) * 112 + sub * 28);
#pragma unroll
    for (int c = 0; c < 7; ++c) wbuf[0][c] = wp[c];
  }
#pragma unroll
  for (int i = 0; i < NIT; ++i) {
    if (i + 1 < NIT) {
      const float4* wp = (const float4*)(wimg + (size_t)(base + grp + 128 * (i + 1)) * 112 + sub * 28);
#pragma unroll
      for (int c = 0; c < 7; ++c) wbuf[(i + 1) & 1][c] = wp[c];
    }
    float a = 0.f;
#pragma unroll
    for (int c = 0; c < 7; ++c) {
      float4 w = wbuf[i & 1][c];
      a = fmaf(w.x, hr[4 * c], a);
      a = fmaf(w.y, hr[4 * c + 1], a);
      a = fmaf(w.z, hr[4 * c + 2], a);
      a = fmaf(w.w, hr[4 * c + 3], a);
    }
    a += __shfl_xor(a, 1);
    a += __shfl_xor(a, 2);
    int r = grp + 128 * i;
    if (sub == 0 && r < nreal) dst[r] = a + bres[base + r];
  }
}

__device__ __forceinline__ void load_slice(float hr[28], const float* src, int sub) {
#pragma unroll
  for (int c = 0; c < 25; ++c) hr[c] = src[sub * 25 + c];
  hr[25] = hr[26] = hr[27] = 0.f;
}

// ---------------------------------------------------------------------------
// Sequential scan v5b: 512 threads, 128 blocks. All t+1 global prefetch at
// step TOP (2-step qn/cid lookahead); padded weight regions with fixed trip
// counts + double-buffered loads; g2hist in LDS; merged tail phase.
// [R10 fix: topd prefetch lanes 509-518 were out of range for 512 threads
//  (lanes 512+ don't exist -> topd[3..9] never committed); moved to 440-449.]
// ---------------------------------------------------------------------------
__global__ __launch_bounds__(512) void seqk(
    const float* wcat, const float* bcat,
    const float* gi1_all, const float* qw_all, const int* top10_all,
    const float* W_W, const float* b_W,
    const float* Eq, const float* Ec, const int* question, const int* cidx, const int* cmask,
    const float* h1_init, const float* h2_init, const float* scal,
    float* out)
{
  const int b = blockIdx.x, tid = threadIdx.x;
  const int grp = tid >> 2, sub = tid & 3;

  __shared__ float g2hist[T_ * 100];   // 50.8 KB, row 0 = zeros
  __shared__ __align__(16) float h1[100], h2[100], h1n[100], g2v[100];
  __shared__ float gh[600], gi2v[300], kqs[100];
  __shared__ float gi1d[2][300];
  __shared__ float qcd[2][500];
  __shared__ float qwd[2][5];
  __shared__ int topd[2][10];
  __shared__ float kwhist[128];
  __shared__ float ogs[55];
  __shared__ float bresS[1280];
  __shared__ float wkS[100];
  __shared__ int cidS[8], cid0S[8];
  __shared__ int qn1S, qnS;

  for (int x = tid; x < 1280; x += 512) bresS[x] = bcat[x];
  if (tid < 100) wkS[tid] = W_W[100 + tid];

  const float bWv = b_W[0];
  const float kw0 = scal[0];

  if (tid < 100) {
    h1[tid] = h1_init[b * 100 + tid];
    h2[tid] = h2_init[b * 100 + tid];
    g2hist[tid] = 0.f;
  }
  if (tid < 128) kwhist[tid] = kw0;
  if (tid < 300) gi1d[0][tid] = gi1_all[(size_t)b * T_ * 300 + tid];
  if (tid >= 300 && tid < 305) qwd[0][tid - 300] = qw_all[(size_t)b * T_ * 5 + (tid - 300)];
  if (tid == 306) { qn1S = question[b * S_ + 2]; qnS = question[b * S_ + 3]; }
  if (tid >= 320 && tid < 328) {
    int k = tid - 320, qn0 = question[b * S_ + 1];
    cid0S[k] = (k < 4) ? cidx[qn0 * KC_ + k] : cmask[qn0 * KC_ + k - 4];
  }
  if (tid >= 328 && tid < 336) {
    int k = tid - 328, qn1 = question[b * S_ + 2];
    cidS[k] = (k < 4) ? cidx[qn1 * KC_ + k] : cmask[qn1 * KC_ + k - 4];
  }
  __syncthreads();
  if (tid < 500) {
    int q = tid / 100, j = tid % 100;
    int qn0 = question[b * S_ + 1];
    qcd[0][tid] = (q == 0) ? Eq[(size_t)qn0 * 100 + j]
                           : (cid0S[4 + q - 1] ? Ec[(size_t)cid0S[q - 1] * 100 + j] : 0.f);
  }
  __syncthreads();

  for (int t = 0; t < T_; ++t) {
    const size_t bt = (size_t)b * T_ + t;
    const int cur = t & 1, nxt = cur ^ 1;
    const bool pf = (t + 1) < T_;
    const int qn1 = qn1S, qn2 = qnS;  // stable (committed last step, barrier since)

    // ---- TOP: issue ALL t+1 prefetch (latency overlaps S1/S3 below) ----
    float pqc = 0.f, pgi = 0.f, pqw = 0.f;
    int ptop = 0, pci = 0, pqn = 0;
    if (pf) {
      if (tid < 500) {
        int q = tid / 100, j = tid % 100;
        pqc = (q == 0) ? Eq[(size_t)qn1 * 100 + j]
                       : (cidS[4 + q - 1] ? Ec[(size_t)cidS[q - 1] * 100 + j] : 0.f);
      }
      if (tid < 300) pgi = gi1_all[(bt + 1) * 300 + tid];
      if (tid >= 504 && tid < 509) pqw = qw_all[(bt + 1) * 5 + (tid - 504)];
      if (tid >= 440 && tid < 450 && (t + 1) > RK_) ptop = top10_all[(bt + 1) * 10 + (tid - 440)];
      if (tid >= 480 && tid < 488 && (t + 2) < T_) {
        int k = tid - 480;
        pci = (k < 4) ? cidx[qn2 * KC_ + k] : cmask[qn2 * KC_ + k - 4];
      }
      if (tid == 488) pqn = question[b * S_ + min(t + 4, S_ - 1)];
    }

    // ---- S1: gh = [Whh1@h1+b ; Whh2@h2+b] ----
    float hr[28];
    load_slice(hr, h1, sub);
    mat_region<3>(wcat, bresS, 0, 300, hr, gh, grp, sub);
    load_slice(hr, h2, sub);
    mat_region<3>(wcat, bresS, 384, 300, hr, gh + 300, grp, sub);
    __syncthreads();  // b1

    // ---- S2: GRU1 -> h1n ----
    if (tid < 100) {
      int j = tid;
      float rg = sigmf(gi1d[cur][j] + gh[j]);
      float z  = sigmf(gi1d[cur][100 + j] + gh[100 + j]);
      float n  = tanhf(gi1d[cur][200 + j] + rg * gh[200 + j]);
      h1n[j] = (1.f - z) * n + z * h1[j];
    }
    __syncthreads();  // b2

    // ---- S3: gi2 = Wih2@h1n + b ----
    load_slice(hr, h1n, sub);
    mat_region<3>(wcat, bresS, 768, 300, hr, gi2v, grp, sub);
    __syncthreads();  // b3

    // ---- S4: GRU2 -> g2v ----
    if (tid < 100) {
      int j = tid;
      float rg = sigmf(gi2v[j] + gh[300 + j]);
      float z  = sigmf(gi2v[100 + j] + gh[400 + j]);
      float n  = tanhf(gi2v[200 + j] + rg * gh[500 + j]);
      g2v[j] = (1.f - z) * n + z * h2[j];
    }
    __syncthreads();  // b4

    // ---- S5: W_query loads first (latency), then og (LDS), then kq dot ----
    load_slice(hr, g2v, sub);
    float4 wc[7];
    {
      const float4* wp = (const float4*)(wcat + (size_t)(1152 + grp) * 112 + sub * 28);
#pragma unroll
      for (int c = 0; c < 7; ++c) wc[c] = wp[c];
    }
    if (grp < 55) {
      int s = grp / 5, q = grp % 5;
      const float* qcr = &qcd[cur][q * 100 + sub * 25];
      float a = 0.f;
      if (s == 0) {
#pragma unroll
        for (int c = 0; c < 25; ++c) a = fmaf(qcr[c], hr[c], a);
      } else {
        bool valid = (t > RK_) || (s - 1 < t);
        if (valid) {
          int idx = (t > RK_) ? topd[cur][s - 1] : (s - 1);
          const float* hrow = &g2hist[idx * 100 + sub * 25];
#pragma unroll
          for (int c = 0; c < 25; ++c) a = fmaf(qcr[c], hrow[c], a);
        }
      }
      a += __shfl_xor(a, 1);
      a += __shfl_xor(a, 2);
      if (sub == 0) ogs[grp] = a;
    }
    {
      float a = 0.f;
#pragma unroll
      for (int c = 0; c < 7; ++c) {
        float4 w = wc[c];
        a = fmaf(w.x, hr[4 * c], a);
        a = fmaf(w.y, hr[4 * c + 1], a);
        a = fmaf(w.z, hr[4 * c + 2], a);
        a = fmaf(w.w, hr[4 * c + 3], a);
      }
      a += __shfl_xor(a, 1);
      a += __shfl_xor(a, 2);
      if (sub == 0 && grp < 100) kqs[grp] = tanhf(a + bresS[1152 + grp]) * wkS[grp];
    }
    __syncthreads();  // b5

    // ---- FINAL: commits + wave-0 kw/softmax/store ----
    if (pf) {
      if (tid < 500) qcd[nxt][tid] = pqc;
      if (tid < 300) gi1d[nxt][tid] = pgi;
      if (tid >= 504 && tid < 509) qwd[nxt][tid - 504] = pqw;
      if (tid >= 440 && tid < 450 && (t + 1) > RK_) topd[nxt][tid - 440] = min(T_ - 1, max(0, ptop));
      if (tid >= 480 && tid < 488 && (t + 2) < T_) cidS[tid - 480] = pci;
      if (tid == 488) { qn1S = qn2; qnS = pqn; }
    }
    if (tid >= 100 && tid < 200) {
      h1[tid - 100] = h1n[tid - 100];
    } else if (tid >= 200 && tid < 300) {
      if (t > 0) {
        int j = tid - 200;
        h2[j] = g2v[j];
        g2hist[t * 100 + j] = g2v[j];
      }
    }
    if (tid < 64) {
      float v = (tid < 50) ? (kqs[tid] + kqs[tid + 50]) : 0.f;
      v += __shfl_xor(v, 1);
      v += __shfl_xor(v, 2);
      v += __shfl_xor(v, 4);
      v += __shfl_xor(v, 8);
      v += __shfl_xor(v, 16);
      v += __shfl_xor(v, 32);
      const float kw = v;  // all 64 lanes
      float pq = 0.f;
      if (tid < 5) {
        const float qw = qwd[cur][tid];
        float tmp[11];
        float m = -__builtin_inff();
#pragma unroll
        for (int s = 0; s < 11; ++s) {
          float kws;
          bool valid;
          if (s == 0) { kws = kw; valid = true; }
          else if (t > RK_) { kws = kwhist[topd[cur][s - 1]]; valid = true; }
          else { valid = (s - 1 < t); kws = kwhist[s - 1]; }
          float tv = valid ? (qw + kws + bWv) : NEGV;
          tmp[s] = tv;
          m = fmaxf(m, tv);
        }
        float den = 0.f, num = 0.f;
#pragma unroll
        for (int s = 0; s < 11; ++s) {
          float e = expf(tmp[s] - m);
          den += e;
          num += e * ogs[s * 5 + tid];
        }
        pq = num / den;
      }
      if (tid == 5 && t > 0) kwhist[t] = kw;
      float sp = pq;
      sp += __shfl_xor(sp, 1);
      sp += __shfl_xor(sp, 2);
      sp += __shfl_xor(sp, 4);
      if (tid == 0) {
        int col = (t == 0) ? 0 : (t + 1);
        out[b * S_ + col] = sp;
        if (t == 0) out[b * S_ + 1] = 0.f;  // col 1 never written by ref
      }
    }
    __syncthreads();  // b6
  }
}

// ---------------------------------------------------------------------------
extern "C" void kernel_launch(void* const* d_in, const int* in_sizes, int n_in,
                              void* d_out, int out_size, void* d_ws, size_t ws_size,
                              hipStream_t stream)
{
  (void)in_sizes; (void)n_in; (void)out_size; (void)ws_size;
  const float* Eq     = (const float*)d_in[0];
  const float* Ec     = (const float*)d_in[1];
  const float* Er     = (const float*)d_in[2];
  const float* W_ih1  = (const float*)d_in[3];
  const float* W_hh1  = (const float*)d_in[4];
  const float* b_ih1  = (const float*)d_in[5];
  const float* b_hh1  = (const float*)d_in[6];
  const float* W_ih2  = (const float*)d_in[7];
  const float* W_hh2  = (const float*)d_in[8];
  const float* b_ih2  = (const float*)d_in[9];
  const float* b_hh2  = (const float*)d_in[10];
  const float* Wagg   = (const float*)d_in[11];
  const float* bagg   = (const float*)d_in[12];
  const float* W_last = (const float*)d_in[13];
  const float* b_last = (const float*)d_in[14];
  const float* W_query= (const float*)d_in[15];
  const float* b_query= (const float*)d_in[16];
  const float* W_key  = (const float*)d_in[17];
  const float* b_key  = (const float*)d_in[18];
  const float* W_W    = (const float*)d_in[19];
  const float* b_W    = (const float*)d_in[20];
  const float* h1_init= (const float*)d_in[21];
  const float* h2_init= (const float*)d_in[22];
  const int* question = (const int*)d_in[23];
  const int* response = (const int*)d_in[24];
  const int* mask     = (const int*)d_in[25];
  const int* qnb      = (const int*)d_in[26];
  const int* snb      = (const int*)d_in[27];
  const int* cidx     = (const int*)d_in[28];
  const int* cmask    = (const int*)d_in[29];
  float* out = (float*)d_out;

  char* ws = (char*)d_ws;
  size_t off = 0;
  auto alloc = [&](size_t bytes) -> void* {
    void* p = ws + off;
    off += (bytes + 255) & ~(size_t)255;
    return p;
  };
  float* wih1aT = (float*)alloc(30000 * 4);
  float* erw    = (float*)alloc(600 * 4);
  float* waggT  = (float*)alloc(30000 * 4);
  float* wlastT = (float*)alloc(10000 * 4);
  float* wkeyT  = (float*)alloc(10000 * 4);
  float* scal   = (float*)alloc(4);
  float* wcat   = (float*)alloc(143360 * 4);
  float* bcat   = (float*)alloc(1280 * 4);
  float* gi1_all = (float*)alloc((size_t)B_ * T_ * 300 * 4);
  float* qw_all  = (float*)alloc((size_t)B_ * T_ * 5 * 4);
  int*   top10   = (int*)alloc((size_t)B_ * T_ * 10 * 4);

  hipLaunchKernelGGL(setupk, dim3(128), dim3(256), 0, stream,
      Er, W_ih1, b_ih1, Wagg, W_last, W_key, b_query, W_W, W_query,
      W_hh1, W_hh2, W_ih2, b_hh1, b_hh2, b_ih2,
      wih1aT, erw, waggT, wlastT, wkeyT, scal, wcat, bcat);

  hipLaunchKernelGGL(phaseA, dim3(T_, B_), dim3(256), 0, stream,
      Eq, Ec, question, response, mask, qnb, snb,
      wih1aT, erw, waggT, wlastT, bagg, b_last, gi1_all);

  hipLaunchKernelGGL(phaseB, dim3(T_, B_), dim3(128), 0, stream,
      Eq, Ec, question, cidx, cmask, wkeyT, b_key, W_W,
      qw_all, top10);

  hipLaunchKernelGGL(seqk, dim3(B_), dim3(512), 0, stream,
      wcat, bcat, gi1_all, qw_all, top10, W_W, b_W,
      Eq, Ec, question, cidx, cmask,
      h1_init, h2_init, scal, out);
}

// Round 11
// 1846.873 us; speedup vs baseline: 2.6866x; 1.0134x over previous
//
#include <hip/hip_runtime.h>
#include <hip/hip_bf16.h>
#include <math.h>

typedef unsigned int u32;

#define B_ 128
#define S_ 128
#define T_ 127
#define D_ 100
#define QN_ 4
#define SN_ 4
#define KC_ 4
#define RK_ 10
#define NEGV -1000000000.0f

__device__ __forceinline__ float sigmf(float x) { return 1.0f / (1.0f + expf(-x)); }

__device__ __forceinline__ u32 f2bfbits(float x) {
  __hip_bfloat16 h = __float2bfloat16(x);
  unsigned short s;
  __builtin_memcpy(&s, &h, 2);
  return (u32)s;
}

// ---------------------------------------------------------------------------
// Setup: transposed f32 weights for phaseA/B; erw fold; kw0 scalar; and the
// bf16 lane-swizzled weight image for seqk (1280 slots x 64 u32 = 256B/row):
//   [0,384):   W_hh1 rows 0-299 (+84 pad)   [384,768): W_hh2 (+84 pad)
//   [768,1152):W_ih2 (+84 pad)              [1152,1280): W_query rows 0-99 (+28)
// slot = [sub(4)][k(16 u32)]; u32 k packs bf16 of row cols (sub*25+2k, +2k+1)
// (cols >= sub*25+25 are zero). bcat[slot] = f32 bias (0 on pads).
// ---------------------------------------------------------------------------
__global__ __launch_bounds__(256) void setupk(
    const float* Er, const float* W_ih1, const float* b_ih1,
    const float* Wagg, const float* W_last, const float* W_key,
    const float* b_query, const float* W_W, const float* W_query,
    const float* W_hh1, const float* W_hh2, const float* W_ih2,
    const float* b_hh1, const float* b_hh2, const float* b_ih2,
    float* wih1aT, float* erw, float* waggT, float* wlastT, float* wkeyT,
    float* scal, u32* wcat16, float* bcat)
{
  int gid = blockIdx.x * blockDim.x + threadIdx.x;
  int gsz = gridDim.x * blockDim.x;

  for (int x = gid; x < 30000; x += gsz) {
    int j = x / 300, i = x % 300;
    wih1aT[j * 300 + i] = W_ih1[i * 200 + j];
  }
  for (int x = gid; x < 600; x += gsz) {
    int r = x / 300, i = x % 300;
    float acc = b_ih1[i];
    for (int j = 0; j < 100; j++) acc += Er[r * 100 + j] * W_ih1[i * 200 + 100 + j];
    erw[x] = acc;
  }
  for (int x = gid; x < 30000; x += gsz) {
    int h = x / 10000, rr = x % 10000, j = rr / 100, i = rr % 100;
    waggT[h * 10000 + j * 100 + i] = Wagg[h * 10000 + i * 100 + j];
  }
  for (int x = gid; x < 10000; x += gsz) {
    int j = x / 100, i = x % 100;
    wlastT[j * 100 + i] = W_last[i * 100 + j];
    wkeyT[j * 100 + i] = W_key[i * 100 + j];
  }
  // bf16 swizzled weight image (1280 slots x 64 u32)
  for (int x = gid; x < 81920; x += gsz) {
    int slot = x / 64, rem = x % 64, sbu = rem / 16, k = rem % 16;
    int reg = (slot >= 1152) ? 3 : (slot / 384);
    int r = (slot >= 1152) ? (slot - 1152) : (slot - reg * 384);
    int nr = (reg == 3) ? 100 : 300;
    u32 lo = 0, hi = 0;
    if (r < nr) {
      const float* src = (reg == 0) ? (W_hh1 + (size_t)r * 100)
                       : (reg == 1) ? (W_hh2 + (size_t)r * 100)
                       : (reg == 2) ? (W_ih2 + (size_t)r * 100)
                                    : (W_query + (size_t)r * 100);
      int e0 = 2 * k, e1 = 2 * k + 1;
      if (e0 < 25) lo = f2bfbits(src[sbu * 25 + e0]);
      if (e1 < 25) hi = f2bfbits(src[sbu * 25 + e1]);
    }
    wcat16[x] = (hi << 16) | lo;
  }
  for (int x = gid; x < 1280; x += gsz) {
    float v = 0.f;
    int reg = (x >= 1152) ? 3 : (x / 384);
    int r = (x >= 1152) ? (x - 1152) : (x - reg * 384);
    if (reg == 0 && r < 300) v = b_hh1[r];
    else if (reg == 1 && r < 300) v = b_hh2[r];
    else if (reg == 2 && r < 300) v = b_ih2[r];
    else if (reg == 3 && r < 100) v = b_query[r];
    bcat[x] = v;
  }
  if (gid == 0) {
    float acc = 0.f;  // kw of the all-zero hist state: dot(tanh(b_query), Wk_part)
    for (int i = 0; i < 100; i++) acc += tanhf(b_query[i]) * W_W[100 + i];
    scal[0] = acc;
  }
}

// ---------------------------------------------------------------------------
// Phase A (unchanged): per (b,t) 3-hop aggregate -> gi1[b,t,0:300]
// ---------------------------------------------------------------------------
__global__ __launch_bounds__(256) void phaseA(
    const float* Eq, const float* Ec, const int* question, const int* response, const int* mask,
    const int* qnb, const int* snb,
    const float* wih1aT, const float* erw, const float* waggT, const float* wlastT,
    const float* baggf, const float* blastf, float* gi1_all)
{
  const int t = blockIdx.x, b = blockIdx.y, tid = threadIdx.x;
  __shared__ float e0[100], ne0[100], e1[400], ne1[400];
  __shared__ float e2[1600], ne2[1600], m3[1600];
  __shared__ float sum4[400], sum1[100], emq[100];
  __shared__ int l1[4], l2[16], l3[64];

  const int qt = question[b * S_ + t];
  const int mt = mask[b * S_ + t];
  const int rt = response[b * S_ + t];

  if (mt != 0) {
    if (tid < 4) l1[tid] = qnb[qt * QN_ + tid];
    for (int x = tid; x < 100; x += 256) e0[x] = Eq[(size_t)qt * 100 + x];
    __syncthreads();
    if (tid < 16) l2[tid] = snb[l1[tid >> 2] * SN_ + (tid & 3)];
    for (int x = tid; x < 400; x += 256) e1[x] = Ec[(size_t)l1[x / 100] * 100 + (x % 100)];
    __syncthreads();
    if (tid < 64) l3[tid] = qnb[l2[tid >> 2] * QN_ + (tid & 3)];
    for (int x = tid; x < 1600; x += 256) e2[x] = Eq[(size_t)l2[x / 100] * 100 + (x % 100)];
    __syncthreads();
    for (int x = tid; x < 1600; x += 256) {
      int r = x / 100, j = x % 100;
      const int* lr = l3 + r * 4;
      float s = Ec[(size_t)lr[0] * 100 + j] + Ec[(size_t)lr[1] * 100 + j] +
                Ec[(size_t)lr[2] * 100 + j] + Ec[(size_t)lr[3] * 100 + j];
      m3[x] = e2[x] + 0.25f * s;
    }
    for (int x = tid; x < 100; x += 256)
      sum1[x] = e0[x] + 0.25f * (e1[x] + e1[100 + x] + e1[200 + x] + e1[300 + x]);
    for (int x = tid; x < 400; x += 256) {
      int k = x / 100, j = x % 100;
      const float* e2k = e2 + k * 400;
      sum4[x] = e1[x] + 0.25f * (e2k[j] + e2k[100 + j] + e2k[200 + j] + e2k[300 + j]);
    }
    __syncthreads();
    for (int o = tid; o < 2100; o += 256) {
      const float *in, *W;
      float bia;
      float* dst;
      int i = o % 100;
      if (o < 100)      { in = sum1;                           W = waggT;          bia = baggf[i];       dst = ne0 + o; }
      else if (o < 500) { in = sum4 + ((o - 100) / 100) * 100; W = waggT + 10000;  bia = baggf[100 + i]; dst = ne1 + (o - 100); }
      else              { in = m3 + ((o - 500) / 100) * 100;   W = waggT + 20000;  bia = baggf[200 + i]; dst = ne2 + (o - 500); }
      float acc = bia;
      for (int j = 0; j < 100; j++) acc += in[j] * W[j * 100 + i];
      *dst = tanhf(acc);
    }
    __syncthreads();
    for (int x = tid; x < 100; x += 256)
      sum1[x] = ne0[x] + 0.25f * (ne1[x] + ne1[100 + x] + ne1[200 + x] + ne1[300 + x]);
    for (int x = tid; x < 400; x += 256) {
      int k = x / 100, j = x % 100;
      const float* n2k = ne2 + k * 400;
      sum4[x] = ne1[x] + 0.25f * (n2k[j] + n2k[100 + j] + n2k[200 + j] + n2k[300 + j]);
    }
    __syncthreads();
    for (int o = tid; o < 500; o += 256) {
      int i = o % 100;
      if (o < 100) {
        float acc = baggf[i];
        for (int j = 0; j < 100; j++) acc += sum1[j] * waggT[j * 100 + i];
        e0[i] = tanhf(acc);
      } else {
        const float* in = sum4 + ((o - 100) / 100) * 100;
        float acc = baggf[100 + i];
        for (int j = 0; j < 100; j++) acc += in[j] * waggT[10000 + j * 100 + i];
        e1[o - 100] = tanhf(acc);
      }
    }
    __syncthreads();
    for (int x = tid; x < 100; x += 256)
      sum1[x] = e0[x] + 0.25f * (e1[x] + e1[100 + x] + e1[200 + x] + e1[300 + x]);
    __syncthreads();
    for (int o = tid; o < 100; o += 256) {
      float acc = baggf[o];
      for (int j = 0; j < 100; j++) acc += sum1[j] * waggT[j * 100 + o];
      ne0[o] = tanhf(acc);
    }
    __syncthreads();
    for (int o = tid; o < 100; o += 256) {
      float acc = blastf[o];
      for (int j = 0; j < 100; j++) acc += ne0[j] * wlastT[j * 100 + o];
      emq[o] = tanhf(acc);
    }
    __syncthreads();
  } else {
    for (int x = tid; x < 100; x += 256) emq[x] = Eq[(size_t)qt * 100 + x];
    __syncthreads();
  }

  const size_t bt = (size_t)b * T_ + t;
  for (int o = tid; o < 300; o += 256) {
    float acc = erw[rt * 300 + o];
    for (int j = 0; j < 100; j++) acc += emq[j] * wih1aT[j * 300 + o];
    gi1_all[bt * 300 + o] = acc;
  }
}

// ---------------------------------------------------------------------------
// Phase B (unchanged): qw[5] and top-10 indices per (b,t).
// ---------------------------------------------------------------------------
__global__ __launch_bounds__(128) void phaseB(
    const float* Eq, const float* Ec, const int* question, const int* cidx, const int* cmask,
    const float* wkeyT, const float* b_key, const float* W_W,
    float* qw_all, int* top10_all)
{
  const int t = blockIdx.x, b = blockIdx.y, tid = threadIdx.x;
  const size_t bt = (size_t)b * T_ + t;
  __shared__ float qcf[500];
  __shared__ float qtl[500];
  __shared__ float qwp[20];
  __shared__ float orig[128];
  __shared__ float sval[128];
  __shared__ int sidx[128];
  __shared__ int ci[4], cm[4];

  const int qn = question[b * S_ + t + 1];
  if (tid < 4) { ci[tid] = cidx[qn * KC_ + tid]; cm[tid] = cmask[qn * KC_ + tid]; }
  __syncthreads();

  for (int u = tid; u < 500; u += 128) {
    int row = u / 100, j = u % 100;
    float v;
    if (row == 0) v = Eq[(size_t)qn * 100 + j];
    else {
      int k = row - 1;
      v = cm[k] ? Ec[(size_t)ci[k] * 100 + j] : 0.f;
    }
    qcf[u] = v;
  }
  __syncthreads();
  for (int o = tid; o < 500; o += 128) {
    int q = o / 100, i = o % 100;
    float acc = b_key[i];
    const float* src = qcf + q * 100;
    for (int j = 0; j < 100; j++) acc += src[j] * wkeyT[j * 100 + i];
    qtl[o] = tanhf(acc);
  }
  __syncthreads();
  if (tid < 20) {
    int q = tid / 4, part = tid % 4;
    float acc = 0.f;
    for (int j = part * 25; j < part * 25 + 25; j++) acc += qtl[q * 100 + j] * W_W[j];
    qwp[tid] = acc;
  }
  __syncthreads();
  if (tid < 5) qw_all[bt * 5 + tid] = qwp[tid * 4] + qwp[tid * 4 + 1] + qwp[tid * 4 + 2] + qwp[tid * 4 + 3];

  if (t > RK_) {
    float sc = -__builtin_inff();
    if (tid < t) {
      int qs = question[b * S_ + tid];
      float acc = 0.f;
      for (int j = 0; j < 100; j++) acc += Eq[(size_t)qs * 100 + j] * qcf[j];
      sc = acc;
    }
    orig[tid] = sc;
    __syncthreads();
    for (int pass = 0; pass < 10; pass++) {
      sval[tid] = orig[tid];
      sidx[tid] = tid;
      __syncthreads();
      for (int offt = 64; offt > 0; offt >>= 1) {
        if (tid < offt) {
          float v2 = sval[tid + offt];
          int i2 = sidx[tid + offt];
          if (v2 > sval[tid] || (v2 == sval[tid] && i2 < sidx[tid])) { sval[tid] = v2; sidx[tid] = i2; }
        }
        __syncthreads();
      }
      if (tid == 0) top10_all[bt * 10 + pass] = sidx[0];
      if (tid == sidx[0]) orig[tid] = -__builtin_inff();
      __syncthreads();
    }
  }
}

// ---------------------------------------------------------------------------
// mat_region_bf16: fixed trip count NIT; ALL iterations' weights loaded
// upfront (NIT*4 uint4 in flight -> one latency wait per region), bf16
// unpack via shift/mask, f32 accumulate. Slots base+grp+128*i.
// ---------------------------------------------------------------------------
template<int NIT>
__device__ __forceinline__ void mat_region_bf16(
    const uint4* __restrict__ wimg, const float* __restrict__ bres,
    int base, int nreal, const float hr[32], float* dst, int grp, int sub)
{
  uint4 wb[NIT][4];
#pragma unroll
  for (int i = 0; i < NIT; ++i) {
    const uint4* wp = wimg + (size_t)(base + grp + 128 * i) * 16 + sub * 4;
#pragma unroll
    for (int c = 0; c < 4; ++c) wb[i][c] = wp[c];
  }
#pragma unroll
  for (int i = 0; i < NIT; ++i) {
    float a = 0.f;
#pragma unroll
    for (int c = 0; c < 4; ++c) {
      uint4 w = wb[i][c];
      const int e = c * 8;
      a = fmaf(__uint_as_float(w.x << 16),         hr[e + 0], a);
      a = fmaf(__uint_as_float(w.x & 0xffff0000u), hr[e + 1], a);
      a = fmaf(__uint_as_float(w.y << 16),         hr[e + 2], a);
      a = fmaf(__uint_as_float(w.y & 0xffff0000u), hr[e + 3], a);
      a = fmaf(__uint_as_float(w.z << 16),         hr[e + 4], a);
      a = fmaf(__uint_as_float(w.z & 0xffff0000u), hr[e + 5], a);
      a = fmaf(__uint_as_float(w.w << 16),         hr[e + 6], a);
      a = fmaf(__uint_as_float(w.w & 0xffff0000u), hr[e + 7], a);
    }
    a += __shfl_xor(a, 1);
    a += __shfl_xor(a, 2);
    int r = grp + 128 * i;
    if (sub == 0 && r < nreal) dst[r] = a + bres[base + r];
  }
}

__device__ __forceinline__ void load_slice32(float hr[32], const float* src, int sub) {
#pragma unroll
  for (int c = 0; c < 25; ++c) hr[c] = src[sub * 25 + c];
#pragma unroll
  for (int c = 25; c < 32; ++c) hr[c] = 0.f;
}

// ---------------------------------------------------------------------------
// Sequential scan v6: structure identical to the passing R10 version, but the
// weight stream is the bf16 image (256 B/row, 4 uint4 loads/row, upfront
// region loads) -> ~half the L2 line traffic per step.
// ---------------------------------------------------------------------------
__global__ __launch_bounds__(512) void seqk(
    const u32* wcat16, const float* bcat,
    const float* gi1_all, const float* qw_all, const int* top10_all,
    const float* W_W, const float* b_W,
    const float* Eq, const float* Ec, const int* question, const int* cidx, const int* cmask,
    const float* h1_init, const float* h2_init, const float* scal,
    float* out)
{
  const int b = blockIdx.x, tid = threadIdx.x;
  const int grp = tid >> 2, sub = tid & 3;
  const uint4* wimg = (const uint4*)wcat16;

  __shared__ float g2hist[T_ * 100];   // 50.8 KB, row 0 = zeros
  __shared__ __align__(16) float h1[100], h2[100], h1n[100], g2v[100];
  __shared__ float gh[600], gi2v[300], kqs[100];
  __shared__ float gi1d[2][300];
  __shared__ float qcd[2][500];
  __shared__ float qwd[2][5];
  __shared__ int topd[2][10];
  __shared__ float kwhist[128];
  __shared__ float ogs[55];
  __shared__ float bresS[1280];
  __shared__ float wkS[100];
  __shared__ int cidS[8], cid0S[8];
  __shared__ int qn1S, qnS;

  for (int x = tid; x < 1280; x += 512) bresS[x] = bcat[x];
  if (tid < 100) wkS[tid] = W_W[100 + tid];

  const float bWv = b_W[0];
  const float kw0 = scal[0];

  if (tid < 100) {
    h1[tid] = h1_init[b * 100 + tid];
    h2[tid] = h2_init[b * 100 + tid];
    g2hist[tid] = 0.f;
  }
  if (tid < 128) kwhist[tid] = kw0;
  if (tid < 300) gi1d[0][tid] = gi1_all[(size_t)b * T_ * 300 + tid];
  if (tid >= 300 && tid < 305) qwd[0][tid - 300] = qw_all[(size_t)b * T_ * 5 + (tid - 300)];
  if (tid == 306) { qn1S = question[b * S_ + 2]; qnS = question[b * S_ + 3]; }
  if (tid >= 320 && tid < 328) {
    int k = tid - 320, qn0 = question[b * S_ + 1];
    cid0S[k] = (k < 4) ? cidx[qn0 * KC_ + k] : cmask[qn0 * KC_ + k - 4];
  }
  if (tid >= 328 && tid < 336) {
    int k = tid - 328, qn1 = question[b * S_ + 2];
    cidS[k] = (k < 4) ? cidx[qn1 * KC_ + k] : cmask[qn1 * KC_ + k - 4];
  }
  __syncthreads();
  if (tid < 500) {
    int q = tid / 100, j = tid % 100;
    int qn0 = question[b * S_ + 1];
    qcd[0][tid] = (q == 0) ? Eq[(size_t)qn0 * 100 + j]
                           : (cid0S[4 + q - 1] ? Ec[(size_t)cid0S[q - 1] * 100 + j] : 0.f);
  }
  __syncthreads();

  for (int t = 0; t < T_; ++t) {
    const size_t bt = (size_t)b * T_ + t;
    const int cur = t & 1, nxt = cur ^ 1;
    const bool pf = (t + 1) < T_;
    const int qn1 = qn1S, qn2 = qnS;  // stable (committed last step, barrier since)

    // ---- TOP: issue ALL t+1 prefetch (latency overlaps S1/S3 below) ----
    float pqc = 0.f, pgi = 0.f, pqw = 0.f;
    int ptop = 0, pci = 0, pqn = 0;
    if (pf) {
      if (tid < 500) {
        int q = tid / 100, j = tid % 100;
        pqc = (q == 0) ? Eq[(size_t)qn1 * 100 + j]
                       : (cidS[4 + q - 1] ? Ec[(size_t)cidS[q - 1] * 100 + j] : 0.f);
      }
      if (tid < 300) pgi = gi1_all[(bt + 1) * 300 + tid];
      if (tid >= 504 && tid < 509) pqw = qw_all[(bt + 1) * 5 + (tid - 504)];
      if (tid >= 440 && tid < 450 && (t + 1) > RK_) ptop = top10_all[(bt + 1) * 10 + (tid - 440)];
      if (tid >= 480 && tid < 488 && (t + 2) < T_) {
        int k = tid - 480;
        pci = (k < 4) ? cidx[qn2 * KC_ + k] : cmask[qn2 * KC_ + k - 4];
      }
      if (tid == 488) pqn = question[b * S_ + min(t + 4, S_ - 1)];
    }

    // ---- S1: gh = [Whh1@h1+b ; Whh2@h2+b] ----
    float hr[32];
    load_slice32(hr, h1, sub);
    mat_region_bf16<3>(wimg, bresS, 0, 300, hr, gh, grp, sub);
    load_slice32(hr, h2, sub);
    mat_region_bf16<3>(wimg, bresS, 384, 300, hr, gh + 300, grp, sub);
    __syncthreads();  // b1

    // ---- S2: GRU1 -> h1n ----
    if (tid < 100) {
      int j = tid;
      float rg = sigmf(gi1d[cur][j] + gh[j]);
      float z  = sigmf(gi1d[cur][100 + j] + gh[100 + j]);
      float n  = tanhf(gi1d[cur][200 + j] + rg * gh[200 + j]);
      h1n[j] = (1.f - z) * n + z * h1[j];
    }
    __syncthreads();  // b2

    // ---- S3: gi2 = Wih2@h1n + b ----
    load_slice32(hr, h1n, sub);
    mat_region_bf16<3>(wimg, bresS, 768, 300, hr, gi2v, grp, sub);
    __syncthreads();  // b3

    // ---- S4: GRU2 -> g2v ----
    if (tid < 100) {
      int j = tid;
      float rg = sigmf(gi2v[j] + gh[300 + j]);
      float z  = sigmf(gi2v[100 + j] + gh[400 + j]);
      float n  = tanhf(gi2v[200 + j] + rg * gh[500 + j]);
      g2v[j] = (1.f - z) * n + z * h2[j];
    }
    __syncthreads();  // b4

    // ---- S5: W_query loads first (latency), then og (LDS), then kq dot ----
    load_slice32(hr, g2v, sub);
    uint4 wc[4];
    {
      const uint4* wp = wimg + (size_t)(1152 + grp) * 16 + sub * 4;
#pragma unroll
      for (int c = 0; c < 4; ++c) wc[c] = wp[c];
    }
    if (grp < 55) {
      int s = grp / 5, q = grp % 5;
      const float* qcr = &qcd[cur][q * 100 + sub * 25];
      float a = 0.f;
      if (s == 0) {
#pragma unroll
        for (int c = 0; c < 25; ++c) a = fmaf(qcr[c], hr[c], a);
      } else {
        bool valid = (t > RK_) || (s - 1 < t);
        if (valid) {
          int idx = (t > RK_) ? topd[cur][s - 1] : (s - 1);
          const float* hrow = &g2hist[idx * 100 + sub * 25];
#pragma unroll
          for (int c = 0; c < 25; ++c) a = fmaf(qcr[c], hrow[c], a);
        }
      }
      a += __shfl_xor(a, 1);
      a += __shfl_xor(a, 2);
      if (sub == 0) ogs[grp] = a;
    }
    {
      float a = 0.f;
#pragma unroll
      for (int c = 0; c < 4; ++c) {
        uint4 w = wc[c];
        const int e = c * 8;
        a = fmaf(__uint_as_float(w.x << 16),         hr[e + 0], a);
        a = fmaf(__uint_as_float(w.x & 0xffff0000u), hr[e + 1], a);
        a = fmaf(__uint_as_float(w.y << 16),         hr[e + 2], a);
        a = fmaf(__uint_as_float(w.y & 0xffff0000u), hr[e + 3], a);
        a = fmaf(__uint_as_float(w.z << 16),         hr[e + 4], a);
        a = fmaf(__uint_as_float(w.z & 0xffff0000u), hr[e + 5], a);
        a = fmaf(__uint_as_float(w.w << 16),         hr[e + 6], a);
        a = fmaf(__uint_as_float(w.w & 0xffff0000u), hr[e + 7], a);
      }
      a += __shfl_xor(a, 1);
      a += __shfl_xor(a, 2);
      if (sub == 0 && grp < 100) kqs[grp] = tanhf(a + bresS[1152 + grp]) * wkS[grp];
    }
    __syncthreads();  // b5

    // ---- FINAL: commits + wave-0 kw/softmax/store ----
    if (pf) {
      if (tid < 500) qcd[nxt][tid] = pqc;
      if (tid < 300) gi1d[nxt][tid] = pgi;
      if (tid >= 504 && tid < 509) qwd[nxt][tid - 504] = pqw;
      if (tid >= 440 && tid < 450 && (t + 1) > RK_) topd[nxt][tid - 440] = min(T_ - 1, max(0, ptop));
      if (tid >= 480 && tid < 488 && (t + 2) < T_) cidS[tid - 480] = pci;
      if (tid == 488) { qn1S = qn2; qnS = pqn; }
    }
    if (tid >= 100 && tid < 200) {
      h1[tid - 100] = h1n[tid - 100];
    } else if (tid >= 200 && tid < 300) {
      if (t > 0) {
        int j = tid - 200;
        h2[j] = g2v[j];
        g2hist[t * 100 + j] = g2v[j];
      }
    }
    if (tid < 64) {
      float v = (tid < 50) ? (kqs[tid] + kqs[tid + 50]) : 0.f;
      v += __shfl_xor(v, 1);
      v += __shfl_xor(v, 2);
      v += __shfl_xor(v, 4);
      v += __shfl_xor(v, 8);
      v += __shfl_xor(v, 16);
      v += __shfl_xor(v, 32);
      const float kw = v;  // all 64 lanes
      float pq = 0.f;
      if (tid < 5) {
        const float qw = qwd[cur][tid];
        float tmp[11];
        float m = -__builtin_inff();
#pragma unroll
        for (int s = 0; s < 11; ++s) {
          float kws;
          bool valid;
          if (s == 0) { kws = kw; valid = true; }
          else if (t > RK_) { kws = kwhist[topd[cur][s - 1]]; valid = true; }
          else { valid = (s - 1 < t); kws = kwhist[s - 1]; }
          float tv = valid ? (qw + kws + bWv) : NEGV;
          tmp[s] = tv;
          m = fmaxf(m, tv);
        }
        float den = 0.f, num = 0.f;
#pragma unroll
        for (int s = 0; s < 11; ++s) {
          float e = expf(tmp[s] - m);
          den += e;
          num += e * ogs[s * 5 + tid];
        }
        pq = num / den;
      }
      if (tid == 5 && t > 0) kwhist[t] = kw;
      float sp = pq;
      sp += __shfl_xor(sp, 1);
      sp += __shfl_xor(sp, 2);
      sp += __shfl_xor(sp, 4);
      if (tid == 0) {
        int col = (t == 0) ? 0 : (t + 1);
        out[b * S_ + col] = sp;
        if (t == 0) out[b * S_ + 1] = 0.f;  // col 1 never written by ref
      }
    }
    __syncthreads();  // b6
  }
}

// ---------------------------------------------------------------------------
extern "C" void kernel_launch(void* const* d_in, const int* in_sizes, int n_in,
                              void* d_out, int out_size, void* d_ws, size_t ws_size,
                              hipStream_t stream)
{
  (void)in_sizes; (void)n_in; (void)out_size; (void)ws_size;
  const float* Eq     = (const float*)d_in[0];
  const float* Ec     = (const float*)d_in[1];
  const float* Er     = (const float*)d_in[2];
  const float* W_ih1  = (const float*)d_in[3];
  const float* W_hh1  = (const float*)d_in[4];
  const float* b_ih1  = (const float*)d_in[5];
  const float* b_hh1  = (const float*)d_in[6];
  const float* W_ih2  = (const float*)d_in[7];
  const float* W_hh2  = (const float*)d_in[8];
  const float* b_ih2  = (const float*)d_in[9];
  const float* b_hh2  = (const float*)d_in[10];
  const float* Wagg   = (const float*)d_in[11];
  const float* bagg   = (const float*)d_in[12];
  const float* W_last = (const float*)d_in[13];
  const float* b_last = (const float*)d_in[14];
  const float* W_query= (const float*)d_in[15];
  const float* b_query= (const float*)d_in[16];
  const float* W_key  = (const float*)d_in[17];
  const float* b_key  = (const float*)d_in[18];
  const float* W_W    = (const float*)d_in[19];
  const float* b_W    = (const float*)d_in[20];
  const float* h1_init= (const float*)d_in[21];
  const float* h2_init= (const float*)d_in[22];
  const int* question = (const int*)d_in[23];
  const int* response = (const int*)d_in[24];
  const int* mask     = (const int*)d_in[25];
  const int* qnb      = (const int*)d_in[26];
  const int* snb      = (const int*)d_in[27];
  const int* cidx     = (const int*)d_in[28];
  const int* cmask    = (const int*)d_in[29];
  float* out = (float*)d_out;

  char* ws = (char*)d_ws;
  size_t off = 0;
  auto alloc = [&](size_t bytes) -> void* {
    void* p = ws + off;
    off += (bytes + 255) & ~(size_t)255;
    return p;
  };
  float* wih1aT = (float*)alloc(30000 * 4);
  float* erw    = (float*)alloc(600 * 4);
  float* waggT  = (float*)alloc(30000 * 4);
  float* wlastT = (float*)alloc(10000 * 4);
  float* wkeyT  = (float*)alloc(10000 * 4);
  float* scal   = (float*)alloc(4);
  u32*   wcat16 = (u32*)alloc(81920 * 4);
  float* bcat   = (float*)alloc(1280 * 4);
  float* gi1_all = (float*)alloc((size_t)B_ * T_ * 300 * 4);
  float* qw_all  = (float*)alloc((size_t)B_ * T_ * 5 * 4);
  int*   top10   = (int*)alloc((size_t)B_ * T_ * 10 * 4);

  hipLaunchKernelGGL(setupk, dim3(128), dim3(256), 0, stream,
      Er, W_ih1, b_ih1, Wagg, W_last, W_key, b_query, W_W, W_query,
      W_hh1, W_hh2, W_ih2, b_hh1, b_hh2, b_ih2,
      wih1aT, erw, waggT, wlastT, wkeyT, scal, wcat16, bcat);

  hipLaunchKernelGGL(phaseA, dim3(T_, B_), dim3(256), 0, stream,
      Eq, Ec, question, response, mask, qnb, snb,
      wih1aT, erw, waggT, wlastT, bagg, b_last, gi1_all);

  hipLaunchKernelGGL(phaseB, dim3(T_, B_), dim3(128), 0, stream,
      Eq, Ec, question, cidx, cmask, wkeyT, b_key, W_W,
      qw_all, top10);

  hipLaunchKernelGGL(seqk, dim3(B_), dim3(512), 0, stream,
      wcat16, bcat, gi1_all, qw_all, top10, W_W, b_W,
      Eq, Ec, question, cidx, cmask,
      h1_init, h2_init, scal, out);
}

// Round 12
// 1771.180 us; speedup vs baseline: 2.8014x; 1.0427x over previous
//
#include <hip/hip_runtime.h>
#include <hip/hip_bf16.h>
#include <math.h>

typedef unsigned int u32;

#define B_ 128
#define S_ 128
#define T_ 127
#define D_ 100
#define QN_ 4
#define SN_ 4
#define KC_ 4
#define RK_ 10
#define NEGV -1000000000.0f

__device__ __forceinline__ float sigmf(float x) { return 1.0f / (1.0f + expf(-x)); }

__device__ __forceinline__ u32 f2bfbits(float x) {
  __hip_bfloat16 h = __float2bfloat16(x);
  unsigned short s;
  __builtin_memcpy(&s, &h, 2);
  return (u32)s;
}

// ---------------------------------------------------------------------------
// Setup: transposed f32 weights for phaseA/B; erw fold; kw0 scalar; and the
// bf16 lane-swizzled weight image for seqk v7 (1792 slots x 64 u32 = 256B):
//   slots [0,300):    W_hh1 row = slot          (src h1)   -> gh[slot]
//   slots [300,600):  W_hh2 row = slot-300      (src h2)   -> gh[slot]
//   slots [600,1024): pad (zeros)
//   slots [1024,1324):W_ih2 row = slot-1024     (src h1n)  -> gi2[r]
//   slots [1324,1536): pad
//   slots [1536,1636):W_query row = slot-1536   (src g2v)  -> kq[r]
//   slots [1636,1792): pad
// slot bytes: [sub(4)][k(16 u32)], u32 k packs bf16 cols (sub*25+2k, +2k+1),
// cols >= 25 within a sub-slice are zero. bcat[slot] = f32 bias (0 on pads).
// ---------------------------------------------------------------------------
__global__ __launch_bounds__(256) void setupk(
    const float* Er, const float* W_ih1, const float* b_ih1,
    const float* Wagg, const float* W_last, const float* W_key,
    const float* b_query, const float* W_W, const float* W_query,
    const float* W_hh1, const float* W_hh2, const float* W_ih2,
    const float* b_hh1, const float* b_hh2, const float* b_ih2,
    float* wih1aT, float* erw, float* waggT, float* wlastT, float* wkeyT,
    float* scal, u32* wcat16, float* bcat)
{
  int gid = blockIdx.x * blockDim.x + threadIdx.x;
  int gsz = gridDim.x * blockDim.x;

  for (int x = gid; x < 30000; x += gsz) {
    int j = x / 300, i = x % 300;
    wih1aT[j * 300 + i] = W_ih1[i * 200 + j];
  }
  for (int x = gid; x < 600; x += gsz) {
    int r = x / 300, i = x % 300;
    float acc = b_ih1[i];
    for (int j = 0; j < 100; j++) acc += Er[r * 100 + j] * W_ih1[i * 200 + 100 + j];
    erw[x] = acc;
  }
  for (int x = gid; x < 30000; x += gsz) {
    int h = x / 10000, rr = x % 10000, j = rr / 100, i = rr % 100;
    waggT[h * 10000 + j * 100 + i] = Wagg[h * 10000 + i * 100 + j];
  }
  for (int x = gid; x < 10000; x += gsz) {
    int j = x / 100, i = x % 100;
    wlastT[j * 100 + i] = W_last[i * 100 + j];
    wkeyT[j * 100 + i] = W_key[i * 100 + j];
  }
  // bf16 swizzled weight image (1792 slots x 64 u32)
  for (int x = gid; x < 114688; x += gsz) {
    int slot = x / 64, rem = x % 64, sbu = rem / 16, k = rem % 16;
    const float* src = nullptr;
    if (slot < 300)                       src = W_hh1 + (size_t)slot * 100;
    else if (slot < 600)                  src = W_hh2 + (size_t)(slot - 300) * 100;
    else if (slot >= 1024 && slot < 1324) src = W_ih2 + (size_t)(slot - 1024) * 100;
    else if (slot >= 1536 && slot < 1636) src = W_query + (size_t)(slot - 1536) * 100;
    u32 lo = 0, hi = 0;
    if (src) {
      int e0 = 2 * k, e1 = 2 * k + 1;
      if (e0 < 25) lo = f2bfbits(src[sbu * 25 + e0]);
      if (e1 < 25) hi = f2bfbits(src[sbu * 25 + e1]);
    }
    wcat16[x] = (hi << 16) | lo;
  }
  for (int x = gid; x < 1792; x += gsz) {
    float v = 0.f;
    if (x < 300) v = b_hh1[x];
    else if (x < 600) v = b_hh2[x - 300];
    else if (x >= 1024 && x < 1324) v = b_ih2[x - 1024];
    else if (x >= 1536 && x < 1636) v = b_query[x - 1536];
    bcat[x] = v;
  }
  if (gid == 0) {
    float acc = 0.f;  // kw of the all-zero hist state: dot(tanh(b_query), Wk_part)
    for (int i = 0; i < 100; i++) acc += tanhf(b_query[i]) * W_W[100 + i];
    scal[0] = acc;
  }
}

// ---------------------------------------------------------------------------
// Phase A (unchanged): per (b,t) 3-hop aggregate -> gi1[b,t,0:300]
// ---------------------------------------------------------------------------
__global__ __launch_bounds__(256) void phaseA(
    const float* Eq, const float* Ec, const int* question, const int* response, const int* mask,
    const int* qnb, const int* snb,
    const float* wih1aT, const float* erw, const float* waggT, const float* wlastT,
    const float* baggf, const float* blastf, float* gi1_all)
{
  const int t = blockIdx.x, b = blockIdx.y, tid = threadIdx.x;
  __shared__ float e0[100], ne0[100], e1[400], ne1[400];
  __shared__ float e2[1600], ne2[1600], m3[1600];
  __shared__ float sum4[400], sum1[100], emq[100];
  __shared__ int l1[4], l2[16], l3[64];

  const int qt = question[b * S_ + t];
  const int mt = mask[b * S_ + t];
  const int rt = response[b * S_ + t];

  if (mt != 0) {
    if (tid < 4) l1[tid] = qnb[qt * QN_ + tid];
    for (int x = tid; x < 100; x += 256) e0[x] = Eq[(size_t)qt * 100 + x];
    __syncthreads();
    if (tid < 16) l2[tid] = snb[l1[tid >> 2] * SN_ + (tid & 3)];
    for (int x = tid; x < 400; x += 256) e1[x] = Ec[(size_t)l1[x / 100] * 100 + (x % 100)];
    __syncthreads();
    if (tid < 64) l3[tid] = qnb[l2[tid >> 2] * QN_ + (tid & 3)];
    for (int x = tid; x < 1600; x += 256) e2[x] = Eq[(size_t)l2[x / 100] * 100 + (x % 100)];
    __syncthreads();
    for (int x = tid; x < 1600; x += 256) {
      int r = x / 100, j = x % 100;
      const int* lr = l3 + r * 4;
      float s = Ec[(size_t)lr[0] * 100 + j] + Ec[(size_t)lr[1] * 100 + j] +
                Ec[(size_t)lr[2] * 100 + j] + Ec[(size_t)lr[3] * 100 + j];
      m3[x] = e2[x] + 0.25f * s;
    }
    for (int x = tid; x < 100; x += 256)
      sum1[x] = e0[x] + 0.25f * (e1[x] + e1[100 + x] + e1[200 + x] + e1[300 + x]);
    for (int x = tid; x < 400; x += 256) {
      int k = x / 100, j = x % 100;
      const float* e2k = e2 + k * 400;
      sum4[x] = e1[x] + 0.25f * (e2k[j] + e2k[100 + j] + e2k[200 + j] + e2k[300 + j]);
    }
    __syncthreads();
    for (int o = tid; o < 2100; o += 256) {
      const float *in, *W;
      float bia;
      float* dst;
      int i = o % 100;
      if (o < 100)      { in = sum1;                           W = waggT;          bia = baggf[i];       dst = ne0 + o; }
      else if (o < 500) { in = sum4 + ((o - 100) / 100) * 100; W = waggT + 10000;  bia = baggf[100 + i]; dst = ne1 + (o - 100); }
      else              { in = m3 + ((o - 500) / 100) * 100;   W = waggT + 20000;  bia = baggf[200 + i]; dst = ne2 + (o - 500); }
      float acc = bia;
      for (int j = 0; j < 100; j++) acc += in[j] * W[j * 100 + i];
      *dst = tanhf(acc);
    }
    __syncthreads();
    for (int x = tid; x < 100; x += 256)
      sum1[x] = ne0[x] + 0.25f * (ne1[x] + ne1[100 + x] + ne1[200 + x] + ne1[300 + x]);
    for (int x = tid; x < 400; x += 256) {
      int k = x / 100, j = x % 100;
      const float* n2k = ne2 + k * 400;
      sum4[x] = ne1[x] + 0.25f * (n2k[j] + n2k[100 + j] + n2k[200 + j] + n2k[300 + j]);
    }
    __syncthreads();
    for (int o = tid; o < 500; o += 256) {
      int i = o % 100;
      if (o < 100) {
        float acc = baggf[i];
        for (int j = 0; j < 100; j++) acc += sum1[j] * waggT[j * 100 + i];
        e0[i] = tanhf(acc);
      } else {
        const float* in = sum4 + ((o - 100) / 100) * 100;
        float acc = baggf[100 + i];
        for (int j = 0; j < 100; j++) acc += in[j] * waggT[10000 + j * 100 + i];
        e1[o - 100] = tanhf(acc);
      }
    }
    __syncthreads();
    for (int x = tid; x < 100; x += 256)
      sum1[x] = e0[x] + 0.25f * (e1[x] + e1[100 + x] + e1[200 + x] + e1[300 + x]);
    __syncthreads();
    for (int o = tid; o < 100; o += 256) {
      float acc = baggf[o];
      for (int j = 0; j < 100; j++) acc += sum1[j] * waggT[j * 100 + o];
      ne0[o] = tanhf(acc);
    }
    __syncthreads();
    for (int o = tid; o < 100; o += 256) {
      float acc = blastf[o];
      for (int j = 0; j < 100; j++) acc += ne0[j] * wlastT[j * 100 + o];
      emq[o] = tanhf(acc);
    }
    __syncthreads();
  } else {
    for (int x = tid; x < 100; x += 256) emq[x] = Eq[(size_t)qt * 100 + x];
    __syncthreads();
  }

  const size_t bt = (size_t)b * T_ + t;
  for (int o = tid; o < 300; o += 256) {
    float acc = erw[rt * 300 + o];
    for (int j = 0; j < 100; j++) acc += emq[j] * wih1aT[j * 300 + o];
    gi1_all[bt * 300 + o] = acc;
  }
}

// ---------------------------------------------------------------------------
// Phase B (unchanged): qw[5] and top-10 indices per (b,t).
// ---------------------------------------------------------------------------
__global__ __launch_bounds__(128) void phaseB(
    const float* Eq, const float* Ec, const int* question, const int* cidx, const int* cmask,
    const float* wkeyT, const float* b_key, const float* W_W,
    float* qw_all, int* top10_all)
{
  const int t = blockIdx.x, b = blockIdx.y, tid = threadIdx.x;
  const size_t bt = (size_t)b * T_ + t;
  __shared__ float qcf[500];
  __shared__ float qtl[500];
  __shared__ float qwp[20];
  __shared__ float orig[128];
  __shared__ float sval[128];
  __shared__ int sidx[128];
  __shared__ int ci[4], cm[4];

  const int qn = question[b * S_ + t + 1];
  if (tid < 4) { ci[tid] = cidx[qn * KC_ + tid]; cm[tid] = cmask[qn * KC_ + tid]; }
  __syncthreads();

  for (int u = tid; u < 500; u += 128) {
    int row = u / 100, j = u % 100;
    float v;
    if (row == 0) v = Eq[(size_t)qn * 100 + j];
    else {
      int k = row - 1;
      v = cm[k] ? Ec[(size_t)ci[k] * 100 + j] : 0.f;
    }
    qcf[u] = v;
  }
  __syncthreads();
  for (int o = tid; o < 500; o += 128) {
    int q = o / 100, i = o % 100;
    float acc = b_key[i];
    const float* src = qcf + q * 100;
    for (int j = 0; j < 100; j++) acc += src[j] * wkeyT[j * 100 + i];
    qtl[o] = tanhf(acc);
  }
  __syncthreads();
  if (tid < 20) {
    int q = tid / 4, part = tid % 4;
    float acc = 0.f;
    for (int j = part * 25; j < part * 25 + 25; j++) acc += qtl[q * 100 + j] * W_W[j];
    qwp[tid] = acc;
  }
  __syncthreads();
  if (tid < 5) qw_all[bt * 5 + tid] = qwp[tid * 4] + qwp[tid * 4 + 1] + qwp[tid * 4 + 2] + qwp[tid * 4 + 3];

  if (t > RK_) {
    float sc = -__builtin_inff();
    if (tid < t) {
      int qs = question[b * S_ + tid];
      float acc = 0.f;
      for (int j = 0; j < 100; j++) acc += Eq[(size_t)qs * 100 + j] * qcf[j];
      sc = acc;
    }
    orig[tid] = sc;
    __syncthreads();
    for (int pass = 0; pass < 10; pass++) {
      sval[tid] = orig[tid];
      sidx[tid] = tid;
      __syncthreads();
      for (int offt = 64; offt > 0; offt >>= 1) {
        if (tid < offt) {
          float v2 = sval[tid + offt];
          int i2 = sidx[tid + offt];
          if (v2 > sval[tid] || (v2 == sval[tid] && i2 < sidx[tid])) { sval[tid] = v2; sidx[tid] = i2; }
        }
        __syncthreads();
      }
      if (tid == 0) top10_all[bt * 10 + pass] = sidx[0];
      if (tid == sidx[0]) orig[tid] = -__builtin_inff();
      __syncthreads();
    }
  }
}

// bf16 row-dot helper: a += dot(unpack(w[0..3]), hr[0..31])
__device__ __forceinline__ float bf16_dot32(const uint4 w[4], const float hr[32]) {
  float a = 0.f;
#pragma unroll
  for (int c = 0; c < 4; ++c) {
    uint4 ww = w[c];
    const int e = c * 8;
    a = fmaf(__uint_as_float(ww.x << 16),         hr[e + 0], a);
    a = fmaf(__uint_as_float(ww.x & 0xffff0000u), hr[e + 1], a);
    a = fmaf(__uint_as_float(ww.y << 16),         hr[e + 2], a);
    a = fmaf(__uint_as_float(ww.y & 0xffff0000u), hr[e + 3], a);
    a = fmaf(__uint_as_float(ww.z << 16),         hr[e + 4], a);
    a = fmaf(__uint_as_float(ww.z & 0xffff0000u), hr[e + 5], a);
    a = fmaf(__uint_as_float(ww.w << 16),         hr[e + 6], a);
    a = fmaf(__uint_as_float(ww.w & 0xffff0000u), hr[e + 7], a);
  }
  return a;
}

// ---------------------------------------------------------------------------
// Sequential scan v7: 1024 threads (16 waves -> 4 waves/SIMD for latency
// hiding), 128 blocks. og s>=1 moved into the S1 phase (depends only on
// step-top-stable topd/qcd/g2hist). Weight regions strided for 256 groups,
// guarded double-buffered loads. 6 barriers. LDS ~71 KB.
// ---------------------------------------------------------------------------
__global__ __launch_bounds__(1024) void seqk(
    const u32* wcat16, const float* bcat,
    const float* gi1_all, const float* qw_all, const int* top10_all,
    const float* W_W, const float* b_W,
    const float* Eq, const float* Ec, const int* question, const int* cidx, const int* cmask,
    const float* h1_init, const float* h2_init, const float* scal,
    float* out)
{
  const int b = blockIdx.x, tid = threadIdx.x;
  const int grp = tid >> 2, sub = tid & 3;  // grp in [0,256)
  const uint4* wimg = (const uint4*)wcat16;

  __shared__ float g2hist[T_ * 100];   // 50.8 KB, row 0 = zeros
  __shared__ float hcomb[200];         // h1 | h2
  __shared__ __align__(16) float h1n[100], g2v[100];
  __shared__ float gh[600], gi2v[300], kqs[100];
  __shared__ float gi1d[2][300];
  __shared__ float qcd[2][500];
  __shared__ float qwd[2][5];
  __shared__ int topd[2][10];
  __shared__ float kwhist[128];
  __shared__ float ogs[55];
  __shared__ float bresS[1792];
  __shared__ float wkS[100];
  __shared__ int cidS[8], cid0S[8];
  __shared__ int qn1S, qnS;

  for (int x = tid; x < 1792; x += 1024) bresS[x] = bcat[x];
  if (tid < 100) wkS[tid] = W_W[100 + tid];

  const float bWv = b_W[0];
  const float kw0 = scal[0];

  if (tid < 100) {
    hcomb[tid] = h1_init[b * 100 + tid];
    g2hist[tid] = 0.f;
  } else if (tid < 200) {
    hcomb[tid] = h2_init[b * 100 + (tid - 100)];
  }
  if (tid < 128) kwhist[tid] = kw0;
  if (tid < 300) gi1d[0][tid] = gi1_all[(size_t)b * T_ * 300 + tid];
  if (tid >= 300 && tid < 305) qwd[0][tid - 300] = qw_all[(size_t)b * T_ * 5 + (tid - 300)];
  if (tid == 306) { qn1S = question[b * S_ + 2]; qnS = question[b * S_ + 3]; }
  if (tid >= 320 && tid < 328) {
    int k = tid - 320, qn0 = question[b * S_ + 1];
    cid0S[k] = (k < 4) ? cidx[qn0 * KC_ + k] : cmask[qn0 * KC_ + k - 4];
  }
  if (tid >= 328 && tid < 336) {
    int k = tid - 328, qn1 = question[b * S_ + 2];
    cidS[k] = (k < 4) ? cidx[qn1 * KC_ + k] : cmask[qn1 * KC_ + k - 4];
  }
  __syncthreads();
  if (tid < 500) {
    int q = tid / 100, j = tid % 100;
    int qn0 = question[b * S_ + 1];
    qcd[0][tid] = (q == 0) ? Eq[(size_t)qn0 * 100 + j]
                           : (cid0S[4 + q - 1] ? Ec[(size_t)cid0S[q - 1] * 100 + j] : 0.f);
  }
  __syncthreads();

  for (int t = 0; t < T_; ++t) {
    const size_t bt = (size_t)b * T_ + t;
    const int cur = t & 1, nxt = cur ^ 1;
    const bool pf = (t + 1) < T_;
    const int qn1 = qn1S, qn2 = qnS;  // stable (committed last step, barrier since)

    // ---- TOP: issue ALL t+1 prefetch (latency overlaps S1 below) ----
    float pqc = 0.f, pgi = 0.f, pqw = 0.f;
    int ptop = 0, pci = 0, pqn = 0;
    if (pf) {
      if (tid < 500) {
        int q = tid / 100, j = tid % 100;
        pqc = (q == 0) ? Eq[(size_t)qn1 * 100 + j]
                       : (cidS[4 + q - 1] ? Ec[(size_t)cidS[q - 1] * 100 + j] : 0.f);
      }
      if (tid < 300) pgi = gi1_all[(bt + 1) * 300 + tid];
      if (tid >= 504 && tid < 509) pqw = qw_all[(bt + 1) * 5 + (tid - 504)];
      if (tid >= 440 && tid < 450 && (t + 1) > RK_) ptop = top10_all[(bt + 1) * 10 + (tid - 440)];
      if (tid >= 480 && tid < 488 && (t + 2) < T_) {
        int k = tid - 480;
        pci = (k < 4) ? cidx[qn2 * KC_ + k] : cmask[qn2 * KC_ + k - 4];
      }
      if (tid == 488) pqn = question[b * S_ + min(t + 4, S_ - 1)];
    }

    // ---- S1: gh (groups 0-191) | og s>=1 (groups 192-241) ----
    if (tid < 768) {
      float hr[32];
      hr[25] = hr[26] = hr[27] = hr[28] = hr[29] = hr[30] = hr[31] = 0.f;
      uint4 wb[2][4];
      {
        const uint4* wp = wimg + (size_t)grp * 16 + sub * 4;  // slot = grp (i=0, always real)
#pragma unroll
        for (int c = 0; c < 4; ++c) wb[0][c] = wp[c];
      }
#pragma unroll
      for (int i = 0; i < 4; ++i) {
        const int slot = grp + 192 * i;
        if (i + 1 < 4) {
          int sl2 = grp + 192 * (i + 1);
          if (sl2 < 600) {
            const uint4* wp = wimg + (size_t)sl2 * 16 + sub * 4;
#pragma unroll
            for (int c = 0; c < 4; ++c) wb[(i + 1) & 1][c] = wp[c];
          }
        }
        if (slot < 600) {
          const int off = (slot < 300) ? 0 : 100;
#pragma unroll
          for (int c = 0; c < 25; ++c) hr[c] = hcomb[off + sub * 25 + c];
          float a = bf16_dot32(wb[i & 1], hr);
          a += __shfl_xor(a, 1);
          a += __shfl_xor(a, 2);
          if (sub == 0) gh[slot] = a + bresS[slot];
        }
      }
    } else if (tid < 968) {
      int d = grp - 192;  // 0..49
      int s = 1 + d / 5, q = d % 5;
      bool valid = (t > RK_) || (s - 1 < t);
      float a = 0.f;
      if (valid) {
        int idx = (t > RK_) ? topd[cur][s - 1] : (s - 1);
        const float* qcr = &qcd[cur][q * 100 + sub * 25];
        const float* hrow = &g2hist[idx * 100 + sub * 25];
#pragma unroll
        for (int c = 0; c < 25; ++c) a = fmaf(qcr[c], hrow[c], a);
      }
      a += __shfl_xor(a, 1);
      a += __shfl_xor(a, 2);
      if (sub == 0) ogs[s * 5 + q] = a;
    }
    __syncthreads();  // b1

    // ---- S2: GRU1 -> h1n ----
    if (tid < 100) {
      int j = tid;
      float rg = sigmf(gi1d[cur][j] + gh[j]);
      float z  = sigmf(gi1d[cur][100 + j] + gh[100 + j]);
      float n  = tanhf(gi1d[cur][200 + j] + rg * gh[200 + j]);
      h1n[j] = (1.f - z) * n + z * hcomb[j];
    }
    __syncthreads();  // b2

    // ---- S3: gi2 = Wih2@h1n + b (all 256 groups, NIT=2 guarded) ----
    {
      float hr[32];
      hr[25] = hr[26] = hr[27] = hr[28] = hr[29] = hr[30] = hr[31] = 0.f;
#pragma unroll
      for (int c = 0; c < 25; ++c) hr[c] = h1n[sub * 25 + c];
      uint4 wb[2][4];
      {
        const uint4* wp = wimg + (size_t)(1024 + grp) * 16 + sub * 4;
#pragma unroll
        for (int c = 0; c < 4; ++c) wb[0][c] = wp[c];
      }
      if (grp < 44) {
        const uint4* wp = wimg + (size_t)(1024 + grp + 256) * 16 + sub * 4;
#pragma unroll
        for (int c = 0; c < 4; ++c) wb[1][c] = wp[c];
      }
#pragma unroll
      for (int i = 0; i < 2; ++i) {
        int r = grp + 256 * i;
        if (r < 300) {
          float a = bf16_dot32(wb[i], hr);
          a += __shfl_xor(a, 1);
          a += __shfl_xor(a, 2);
          if (sub == 0) gi2v[r] = a + bresS[1024 + r];
        }
      }
    }
    __syncthreads();  // b3

    // ---- S4: GRU2 -> g2v ----
    if (tid < 100) {
      int j = tid;
      float rg = sigmf(gi2v[j] + gh[300 + j]);
      float z  = sigmf(gi2v[100 + j] + gh[400 + j]);
      float n  = tanhf(gi2v[200 + j] + rg * gh[500 + j]);
      g2v[j] = (1.f - z) * n + z * hcomb[100 + j];
    }
    __syncthreads();  // b4

    // ---- S5: kq (groups 0-99) | og s=0 (groups 100-104) ----
    if (grp < 100) {
      float hr[32];
      hr[25] = hr[26] = hr[27] = hr[28] = hr[29] = hr[30] = hr[31] = 0.f;
#pragma unroll
      for (int c = 0; c < 25; ++c) hr[c] = g2v[sub * 25 + c];
      uint4 wc[4];
      {
        const uint4* wp = wimg + (size_t)(1536 + grp) * 16 + sub * 4;
#pragma unroll
        for (int c = 0; c < 4; ++c) wc[c] = wp[c];
      }
      float a = bf16_dot32(wc, hr);
      a += __shfl_xor(a, 1);
      a += __shfl_xor(a, 2);
      if (sub == 0) kqs[grp] = tanhf(a + bresS[1536 + grp]) * wkS[grp];
    } else if (grp < 105) {
      int q = grp - 100;
      const float* qcr = &qcd[cur][q * 100 + sub * 25];
      float a = 0.f;
#pragma unroll
      for (int c = 0; c < 25; ++c) a = fmaf(qcr[c], g2v[sub * 25 + c], a);
      a += __shfl_xor(a, 1);
      a += __shfl_xor(a, 2);
      if (sub == 0) ogs[q] = a;
    }
    __syncthreads();  // b5

    // ---- S6: commits + state updates + wave-0 kw/softmax/store ----
    if (pf) {
      if (tid < 500) qcd[nxt][tid] = pqc;
      if (tid < 300) gi1d[nxt][tid] = pgi;
      if (tid >= 504 && tid < 509) qwd[nxt][tid - 504] = pqw;
      if (tid >= 440 && tid < 450 && (t + 1) > RK_) topd[nxt][tid - 440] = min(T_ - 1, max(0, ptop));
      if (tid >= 480 && tid < 488 && (t + 2) < T_) cidS[tid - 480] = pci;
      if (tid == 488) { qn1S = qn2; qnS = pqn; }
    }
    if (tid >= 100 && tid < 200) {
      hcomb[tid - 100] = h1n[tid - 100];
    } else if (tid >= 200 && tid < 300) {
      if (t > 0) {
        int j = tid - 200;
        hcomb[100 + j] = g2v[j];
        g2hist[t * 100 + j] = g2v[j];
      }
    }
    if (tid < 64) {
      float v = (tid < 50) ? (kqs[tid] + kqs[tid + 50]) : 0.f;
      v += __shfl_xor(v, 1);
      v += __shfl_xor(v, 2);
      v += __shfl_xor(v, 4);
      v += __shfl_xor(v, 8);
      v += __shfl_xor(v, 16);
      v += __shfl_xor(v, 32);
      const float kw = v;  // all 64 lanes
      float pq = 0.f;
      if (tid < 5) {
        const float qw = qwd[cur][tid];
        float tmp[11];
        float m = -__builtin_inff();
#pragma unroll
        for (int s = 0; s < 11; ++s) {
          float kws;
          bool valid;
          if (s == 0) { kws = kw; valid = true; }
          else if (t > RK_) { kws = kwhist[topd[cur][s - 1]]; valid = true; }
          else { valid = (s - 1 < t); kws = kwhist[s - 1]; }
          float tv = valid ? (qw + kws + bWv) : NEGV;
          tmp[s] = tv;
          m = fmaxf(m, tv);
        }
        float den = 0.f, num = 0.f;
#pragma unroll
        for (int s = 0; s < 11; ++s) {
          float e = expf(tmp[s] - m);
          den += e;
          num += e * ogs[s * 5 + tid];
        }
        pq = num / den;
      }
      if (tid == 5 && t > 0) kwhist[t] = kw;
      float sp = pq;
      sp += __shfl_xor(sp, 1);
      sp += __shfl_xor(sp, 2);
      sp += __shfl_xor(sp, 4);
      if (tid == 0) {
        int col = (t == 0) ? 0 : (t + 1);
        out[b * S_ + col] = sp;
        if (t == 0) out[b * S_ + 1] = 0.f;  // col 1 never written by ref
      }
    }
    __syncthreads();  // b6
  }
}

// ---------------------------------------------------------------------------
extern "C" void kernel_launch(void* const* d_in, const int* in_sizes, int n_in,
                              void* d_out, int out_size, void* d_ws, size_t ws_size,
                              hipStream_t stream)
{
  (void)in_sizes; (void)n_in; (void)out_size; (void)ws_size;
  const float* Eq     = (const float*)d_in[0];
  const float* Ec     = (const float*)d_in[1];
  const float* Er     = (const float*)d_in[2];
  const float* W_ih1  = (const float*)d_in[3];
  const float* W_hh1  = (const float*)d_in[4];
  const float* b_ih1  = (const float*)d_in[5];
  const float* b_hh1  = (const float*)d_in[6];
  const float* W_ih2  = (const float*)d_in[7];
  const float* W_hh2  = (const float*)d_in[8];
  const float* b_ih2  = (const float*)d_in[9];
  const float* b_hh2  = (const float*)d_in[10];
  const float* Wagg   = (const float*)d_in[11];
  const float* bagg   = (const float*)d_in[12];
  const float* W_last = (const float*)d_in[13];
  const float* b_last = (const float*)d_in[14];
  const float* W_query= (const float*)d_in[15];
  const float* b_query= (const float*)d_in[16];
  const float* W_key  = (const float*)d_in[17];
  const float* b_key  = (const float*)d_in[18];
  const float* W_W    = (const float*)d_in[19];
  const float* b_W    = (const float*)d_in[20];
  const float* h1_init= (const float*)d_in[21];
  const float* h2_init= (const float*)d_in[22];
  const int* question = (const int*)d_in[23];
  const int* response = (const int*)d_in[24];
  const int* mask     = (const int*)d_in[25];
  const int* qnb      = (const int*)d_in[26];
  const int* snb      = (const int*)d_in[27];
  const int* cidx     = (const int*)d_in[28];
  const int* cmask    = (const int*)d_in[29];
  float* out = (float*)d_out;

  char* ws = (char*)d_ws;
  size_t off = 0;
  auto alloc = [&](size_t bytes) -> void* {
    void* p = ws + off;
    off += (bytes + 255) & ~(size_t)255;
    return p;
  };
  float* wih1aT = (float*)alloc(30000 * 4);
  float* erw    = (float*)alloc(600 * 4);
  float* waggT  = (float*)alloc(30000 * 4);
  float* wlastT = (float*)alloc(10000 * 4);
  float* wkeyT  = (float*)alloc(10000 * 4);
  float* scal   = (float*)alloc(4);
  u32*   wcat16 = (u32*)alloc(114688 * 4);
  float* bcat   = (float*)alloc(1792 * 4);
  float* gi1_all = (float*)alloc((size_t)B_ * T_ * 300 * 4);
  float* qw_all  = (float*)alloc((size_t)B_ * T_ * 5 * 4);
  int*   top10   = (int*)alloc((size_t)B_ * T_ * 10 * 4);

  hipLaunchKernelGGL(setupk, dim3(128), dim3(256), 0, stream,
      Er, W_ih1, b_ih1, Wagg, W_last, W_key, b_query, W_W, W_query,
      W_hh1, W_hh2, W_ih2, b_hh1, b_hh2, b_ih2,
      wih1aT, erw, waggT, wlastT, wkeyT, scal, wcat16, bcat);

  hipLaunchKernelGGL(phaseA, dim3(T_, B_), dim3(256), 0, stream,
      Eq, Ec, question, response, mask, qnb, snb,
      wih1aT, erw, waggT, wlastT, bagg, b_last, gi1_all);

  hipLaunchKernelGGL(phaseB, dim3(T_, B_), dim3(128), 0, stream,
      Eq, Ec, question, cidx, cmask, wkeyT, b_key, W_W,
      qw_all, top10);

  hipLaunchKernelGGL(seqk, dim3(B_), dim3(1024), 0, stream,
      wcat16, bcat, gi1_all, qw_all, top10, W_W, b_W,
      Eq, Ec, question, cidx, cmask,
      h1_init, h2_init, scal, out);
}

// Round 13
// 1636.583 us; speedup vs baseline: 3.0318x; 1.0822x over previous
//
#include <hip/hip_runtime.h>
#include <hip/hip_bf16.h>
#include <math.h>

typedef unsigned int u32;

#define B_ 128
#define S_ 128
#define T_ 127
#define D_ 100
#define QN_ 4
#define SN_ 4
#define KC_ 4
#define RK_ 10
#define NEGV -1000000000.0f

__device__ __forceinline__ float sigmf(float x) { return 1.0f / (1.0f + expf(-x)); }

__device__ __forceinline__ u32 f2bfbits(float x) {
  __hip_bfloat16 h = __float2bfloat16(x);
  unsigned short s;
  __builtin_memcpy(&s, &h, 2);
  return (u32)s;
}

// ---------------------------------------------------------------------------
// Setup (unchanged from R12): transposed f32 weights for phaseA/B; erw fold;
// kw0 scalar; bf16 lane-swizzled weight image (1792 slots x 64 u32 = 256B):
//   [0,300): W_hh1 | [300,600): W_hh2 | [1024,1324): W_ih2 | [1536,1636): W_query
// slot bytes: [sub(4)][k(16 u32)], u32 k packs bf16 cols (sub*25+2k, +2k+1).
// ---------------------------------------------------------------------------
__global__ __launch_bounds__(256) void setupk(
    const float* Er, const float* W_ih1, const float* b_ih1,
    const float* Wagg, const float* W_last, const float* W_key,
    const float* b_query, const float* W_W, const float* W_query,
    const float* W_hh1, const float* W_hh2, const float* W_ih2,
    const float* b_hh1, const float* b_hh2, const float* b_ih2,
    float* wih1aT, float* erw, float* waggT, float* wlastT, float* wkeyT,
    float* scal, u32* wcat16, float* bcat)
{
  int gid = blockIdx.x * blockDim.x + threadIdx.x;
  int gsz = gridDim.x * blockDim.x;

  for (int x = gid; x < 30000; x += gsz) {
    int j = x / 300, i = x % 300;
    wih1aT[j * 300 + i] = W_ih1[i * 200 + j];
  }
  for (int x = gid; x < 600; x += gsz) {
    int r = x / 300, i = x % 300;
    float acc = b_ih1[i];
    for (int j = 0; j < 100; j++) acc += Er[r * 100 + j] * W_ih1[i * 200 + 100 + j];
    erw[x] = acc;
  }
  for (int x = gid; x < 30000; x += gsz) {
    int h = x / 10000, rr = x % 10000, j = rr / 100, i = rr % 100;
    waggT[h * 10000 + j * 100 + i] = Wagg[h * 10000 + i * 100 + j];
  }
  for (int x = gid; x < 10000; x += gsz) {
    int j = x / 100, i = x % 100;
    wlastT[j * 100 + i] = W_last[i * 100 + j];
    wkeyT[j * 100 + i] = W_key[i * 100 + j];
  }
  for (int x = gid; x < 114688; x += gsz) {
    int slot = x / 64, rem = x % 64, sbu = rem / 16, k = rem % 16;
    const float* src = nullptr;
    if (slot < 300)                       src = W_hh1 + (size_t)slot * 100;
    else if (slot < 600)                  src = W_hh2 + (size_t)(slot - 300) * 100;
    else if (slot >= 1024 && slot < 1324) src = W_ih2 + (size_t)(slot - 1024) * 100;
    else if (slot >= 1536 && slot < 1636) src = W_query + (size_t)(slot - 1536) * 100;
    u32 lo = 0, hi = 0;
    if (src) {
      int e0 = 2 * k, e1 = 2 * k + 1;
      if (e0 < 25) lo = f2bfbits(src[sbu * 25 + e0]);
      if (e1 < 25) hi = f2bfbits(src[sbu * 25 + e1]);
    }
    wcat16[x] = (hi << 16) | lo;
  }
  for (int x = gid; x < 1792; x += gsz) {
    float v = 0.f;
    if (x < 300) v = b_hh1[x];
    else if (x < 600) v = b_hh2[x - 300];
    else if (x >= 1024 && x < 1324) v = b_ih2[x - 1024];
    else if (x >= 1536 && x < 1636) v = b_query[x - 1536];
    bcat[x] = v;
  }
  if (gid == 0) {
    float acc = 0.f;  // kw of the all-zero hist state: dot(tanh(b_query), Wk_part)
    for (int i = 0; i < 100; i++) acc += tanhf(b_query[i]) * W_W[100 + i];
    scal[0] = acc;
  }
}

// ---------------------------------------------------------------------------
// Phase A (unchanged): per (b,t) 3-hop aggregate -> gi1[b,t,0:300]
// ---------------------------------------------------------------------------
__global__ __launch_bounds__(256) void phaseA(
    const float* Eq, const float* Ec, const int* question, const int* response, const int* mask,
    const int* qnb, const int* snb,
    const float* wih1aT, const float* erw, const float* waggT, const float* wlastT,
    const float* baggf, const float* blastf, float* gi1_all)
{
  const int t = blockIdx.x, b = blockIdx.y, tid = threadIdx.x;
  __shared__ float e0[100], ne0[100], e1[400], ne1[400];
  __shared__ float e2[1600], ne2[1600], m3[1600];
  __shared__ float sum4[400], sum1[100], emq[100];
  __shared__ int l1[4], l2[16], l3[64];

  const int qt = question[b * S_ + t];
  const int mt = mask[b * S_ + t];
  const int rt = response[b * S_ + t];

  if (mt != 0) {
    if (tid < 4) l1[tid] = qnb[qt * QN_ + tid];
    for (int x = tid; x < 100; x += 256) e0[x] = Eq[(size_t)qt * 100 + x];
    __syncthreads();
    if (tid < 16) l2[tid] = snb[l1[tid >> 2] * SN_ + (tid & 3)];
    for (int x = tid; x < 400; x += 256) e1[x] = Ec[(size_t)l1[x / 100] * 100 + (x % 100)];
    __syncthreads();
    if (tid < 64) l3[tid] = qnb[l2[tid >> 2] * QN_ + (tid & 3)];
    for (int x = tid; x < 1600; x += 256) e2[x] = Eq[(size_t)l2[x / 100] * 100 + (x % 100)];
    __syncthreads();
    for (int x = tid; x < 1600; x += 256) {
      int r = x / 100, j = x % 100;
      const int* lr = l3 + r * 4;
      float s = Ec[(size_t)lr[0] * 100 + j] + Ec[(size_t)lr[1] * 100 + j] +
                Ec[(size_t)lr[2] * 100 + j] + Ec[(size_t)lr[3] * 100 + j];
      m3[x] = e2[x] + 0.25f * s;
    }
    for (int x = tid; x < 100; x += 256)
      sum1[x] = e0[x] + 0.25f * (e1[x] + e1[100 + x] + e1[200 + x] + e1[300 + x]);
    for (int x = tid; x < 400; x += 256) {
      int k = x / 100, j = x % 100;
      const float* e2k = e2 + k * 400;
      sum4[x] = e1[x] + 0.25f * (e2k[j] + e2k[100 + j] + e2k[200 + j] + e2k[300 + j]);
    }
    __syncthreads();
    for (int o = tid; o < 2100; o += 256) {
      const float *in, *W;
      float bia;
      float* dst;
      int i = o % 100;
      if (o < 100)      { in = sum1;                           W = waggT;          bia = baggf[i];       dst = ne0 + o; }
      else if (o < 500) { in = sum4 + ((o - 100) / 100) * 100; W = waggT + 10000;  bia = baggf[100 + i]; dst = ne1 + (o - 100); }
      else              { in = m3 + ((o - 500) / 100) * 100;   W = waggT + 20000;  bia = baggf[200 + i]; dst = ne2 + (o - 500); }
      float acc = bia;
      for (int j = 0; j < 100; j++) acc += in[j] * W[j * 100 + i];
      *dst = tanhf(acc);
    }
    __syncthreads();
    for (int x = tid; x < 100; x += 256)
      sum1[x] = ne0[x] + 0.25f * (ne1[x] + ne1[100 + x] + ne1[200 + x] + ne1[300 + x]);
    for (int x = tid; x < 400; x += 256) {
      int k = x / 100, j = x % 100;
      const float* n2k = ne2 + k * 400;
      sum4[x] = ne1[x] + 0.25f * (n2k[j] + n2k[100 + j] + n2k[200 + j] + n2k[300 + j]);
    }
    __syncthreads();
    for (int o = tid; o < 500; o += 256) {
      int i = o % 100;
      if (o < 100) {
        float acc = baggf[i];
        for (int j = 0; j < 100; j++) acc += sum1[j] * waggT[j * 100 + i];
        e0[i] = tanhf(acc);
      } else {
        const float* in = sum4 + ((o - 100) / 100) * 100;
        float acc = baggf[100 + i];
        for (int j = 0; j < 100; j++) acc += in[j] * waggT[10000 + j * 100 + i];
        e1[o - 100] = tanhf(acc);
      }
    }
    __syncthreads();
    for (int x = tid; x < 100; x += 256)
      sum1[x] = e0[x] + 0.25f * (e1[x] + e1[100 + x] + e1[200 + x] + e1[300 + x]);
    __syncthreads();
    for (int o = tid; o < 100; o += 256) {
      float acc = baggf[o];
      for (int j = 0; j < 100; j++) acc += sum1[j] * waggT[j * 100 + o];
      ne0[o] = tanhf(acc);
    }
    __syncthreads();
    for (int o = tid; o < 100; o += 256) {
      float acc = blastf[o];
      for (int j = 0; j < 100; j++) acc += ne0[j] * wlastT[j * 100 + o];
      emq[o] = tanhf(acc);
    }
    __syncthreads();
  } else {
    for (int x = tid; x < 100; x += 256) emq[x] = Eq[(size_t)qt * 100 + x];
    __syncthreads();
  }

  const size_t bt = (size_t)b * T_ + t;
  for (int o = tid; o < 300; o += 256) {
    float acc = erw[rt * 300 + o];
    for (int j = 0; j < 100; j++) acc += emq[j] * wih1aT[j * 300 + o];
    gi1_all[bt * 300 + o] = acc;
  }
}

// ---------------------------------------------------------------------------
// Phase B (unchanged): qw[5] and top-10 indices per (b,t).
// ---------------------------------------------------------------------------
__global__ __launch_bounds__(128) void phaseB(
    const float* Eq, const float* Ec, const int* question, const int* cidx, const int* cmask,
    const float* wkeyT, const float* b_key, const float* W_W,
    float* qw_all, int* top10_all)
{
  const int t = blockIdx.x, b = blockIdx.y, tid = threadIdx.x;
  const size_t bt = (size_t)b * T_ + t;
  __shared__ float qcf[500];
  __shared__ float qtl[500];
  __shared__ float qwp[20];
  __shared__ float orig[128];
  __shared__ float sval[128];
  __shared__ int sidx[128];
  __shared__ int ci[4], cm[4];

  const int qn = question[b * S_ + t + 1];
  if (tid < 4) { ci[tid] = cidx[qn * KC_ + tid]; cm[tid] = cmask[qn * KC_ + tid]; }
  __syncthreads();

  for (int u = tid; u < 500; u += 128) {
    int row = u / 100, j = u % 100;
    float v;
    if (row == 0) v = Eq[(size_t)qn * 100 + j];
    else {
      int k = row - 1;
      v = cm[k] ? Ec[(size_t)ci[k] * 100 + j] : 0.f;
    }
    qcf[u] = v;
  }
  __syncthreads();
  for (int o = tid; o < 500; o += 128) {
    int q = o / 100, i = o % 100;
    float acc = b_key[i];
    const float* src = qcf + q * 100;
    for (int j = 0; j < 100; j++) acc += src[j] * wkeyT[j * 100 + i];
    qtl[o] = tanhf(acc);
  }
  __syncthreads();
  if (tid < 20) {
    int q = tid / 4, part = tid % 4;
    float acc = 0.f;
    for (int j = part * 25; j < part * 25 + 25; j++) acc += qtl[q * 100 + j] * W_W[j];
    qwp[tid] = acc;
  }
  __syncthreads();
  if (tid < 5) qw_all[bt * 5 + tid] = qwp[tid * 4] + qwp[tid * 4 + 1] + qwp[tid * 4 + 2] + qwp[tid * 4 + 3];

  if (t > RK_) {
    float sc = -__builtin_inff();
    if (tid < t) {
      int qs = question[b * S_ + tid];
      float acc = 0.f;
      for (int j = 0; j < 100; j++) acc += Eq[(size_t)qs * 100 + j] * qcf[j];
      sc = acc;
    }
    orig[tid] = sc;
    __syncthreads();
    for (int pass = 0; pass < 10; pass++) {
      sval[tid] = orig[tid];
      sidx[tid] = tid;
      __syncthreads();
      for (int offt = 64; offt > 0; offt >>= 1) {
        if (tid < offt) {
          float v2 = sval[tid + offt];
          int i2 = sidx[tid + offt];
          if (v2 > sval[tid] || (v2 == sval[tid] && i2 < sidx[tid])) { sval[tid] = v2; sidx[tid] = i2; }
        }
        __syncthreads();
      }
      if (tid == 0) top10_all[bt * 10 + pass] = sidx[0];
      if (tid == sidx[0]) orig[tid] = -__builtin_inff();
      __syncthreads();
    }
  }
}

// bf16 row-dot helper: dot(unpack(w[0..3]), hr[0..31])
__device__ __forceinline__ float bf16_dot32(const uint4 w[4], const float hr[32]) {
  float a = 0.f;
#pragma unroll
  for (int c = 0; c < 4; ++c) {
    uint4 ww = w[c];
    const int e = c * 8;
    a = fmaf(__uint_as_float(ww.x << 16),         hr[e + 0], a);
    a = fmaf(__uint_as_float(ww.x & 0xffff0000u), hr[e + 1], a);
    a = fmaf(__uint_as_float(ww.y << 16),         hr[e + 2], a);
    a = fmaf(__uint_as_float(ww.y & 0xffff0000u), hr[e + 3], a);
    a = fmaf(__uint_as_float(ww.z << 16),         hr[e + 4], a);
    a = fmaf(__uint_as_float(ww.z & 0xffff0000u), hr[e + 5], a);
    a = fmaf(__uint_as_float(ww.w << 16),         hr[e + 6], a);
    a = fmaf(__uint_as_float(ww.w & 0xffff0000u), hr[e + 7], a);
  }
  return a;
}

// ---------------------------------------------------------------------------
// Sequential scan v8: 1024 threads, 3 barriers/step. The 4-lane group that
// computes all three gate-rows (j, j+100, j+200) applies the GRU nonlinearity
// locally -> the matvec->combine barrier disappears.
//   S1: Whh1 3-dot+GRU1->h1n | Whh2 3-dot->gh2 | og s>=1   -> b1
//   S3: Wih2 3-dot+GRU2->g2v | h1 copy                      -> b2
//   S5: kq | og s=0 | ALL commits + h2/g2hist updates       -> b3
//   S6: wave-0 kw/softmax/store (no trailing barrier; ogs dbuf by parity)
// ---------------------------------------------------------------------------
__global__ __launch_bounds__(1024) void seqk(
    const u32* wcat16, const float* bcat,
    const float* gi1_all, const float* qw_all, const int* top10_all,
    const float* W_W, const float* b_W,
    const float* Eq, const float* Ec, const int* question, const int* cidx, const int* cmask,
    const float* h1_init, const float* h2_init, const float* scal,
    float* out)
{
  const int b = blockIdx.x, tid = threadIdx.x;
  const int grp = tid >> 2, sub = tid & 3;  // grp in [0,256)
  const int ptid = tid - 424;               // prefetch lane index
  const uint4* wimg = (const uint4*)wcat16;

  __shared__ float g2hist[T_ * 100];   // 50.8 KB, row 0 = zeros
  __shared__ float hcomb[200];         // h1 | h2
  __shared__ __align__(16) float h1n[100], g2v[100];
  __shared__ float gh2[300], kqs[100];
  __shared__ float gi1d[2][300];
  __shared__ float qcd[2][500];
  __shared__ float qwd[2][5];
  __shared__ int topd[2][10];
  __shared__ float kwhist[128];
  __shared__ float ogs[2][55];
  __shared__ float bresS[1792];
  __shared__ float wkS[100];
  __shared__ int cidS[8], cid0S[8];
  __shared__ int qn1S, qnS;

  for (int x = tid; x < 1792; x += 1024) bresS[x] = bcat[x];
  if (tid < 100) wkS[tid] = W_W[100 + tid];

  const float bWv = b_W[0];
  const float kw0 = scal[0];

  if (tid < 100) {
    hcomb[tid] = h1_init[b * 100 + tid];
    g2hist[tid] = 0.f;
  } else if (tid < 200) {
    hcomb[tid] = h2_init[b * 100 + (tid - 100)];
  }
  if (tid < 128) kwhist[tid] = kw0;
  if (tid < 300) gi1d[0][tid] = gi1_all[(size_t)b * T_ * 300 + tid];
  if (tid >= 300 && tid < 305) qwd[0][tid - 300] = qw_all[(size_t)b * T_ * 5 + (tid - 300)];
  if (tid == 306) { qn1S = question[b * S_ + 2]; qnS = question[b * S_ + 3]; }
  if (tid >= 320 && tid < 328) {
    int k = tid - 320, qn0 = question[b * S_ + 1];
    cid0S[k] = (k < 4) ? cidx[qn0 * KC_ + k] : cmask[qn0 * KC_ + k - 4];
  }
  if (tid >= 328 && tid < 336) {
    int k = tid - 328, qn1 = question[b * S_ + 2];
    cidS[k] = (k < 4) ? cidx[qn1 * KC_ + k] : cmask[qn1 * KC_ + k - 4];
  }
  __syncthreads();
  if (tid < 500) {
    int q = tid / 100, j = tid % 100;
    int qn0 = question[b * S_ + 1];
    qcd[0][tid] = (q == 0) ? Eq[(size_t)qn0 * 100 + j]
                           : (cid0S[4 + q - 1] ? Ec[(size_t)cid0S[q - 1] * 100 + j] : 0.f);
  }
  __syncthreads();

  for (int t = 0; t < T_; ++t) {
    const size_t bt = (size_t)b * T_ + t;
    const int cur = t & 1, nxt = cur ^ 1;
    const bool pf = (t + 1) < T_;
    const int qn1 = qn1S, qn2 = qnS;  // stable (committed prior S5, barrier since)

    // ---- TOP: issue ALL t+1 prefetch on tids >= 424 (latency hides under S1) ----
    float pqc = 0.f, pgi = 0.f, pqw = 0.f;
    int ptop = 0, pci = 0, pqn = 0;
    if (pf) {
      if (ptid >= 0 && ptid < 500) {
        int q = ptid / 100, j = ptid % 100;
        pqc = (q == 0) ? Eq[(size_t)qn1 * 100 + j]
                       : (cidS[4 + q - 1] ? Ec[(size_t)cidS[q - 1] * 100 + j] : 0.f);
      }
      if (ptid >= 0 && ptid < 300) pgi = gi1_all[(bt + 1) * 300 + ptid];
      if (tid >= 924 && tid < 929) pqw = qw_all[(bt + 1) * 5 + (tid - 924)];
      if (tid >= 929 && tid < 939 && (t + 1) > RK_) ptop = top10_all[(bt + 1) * 10 + (tid - 929)];
      if (tid >= 939 && tid < 947 && (t + 2) < T_) {
        int k = tid - 939;
        pci = (k < 4) ? cidx[qn2 * KC_ + k] : cmask[qn2 * KC_ + k - 4];
      }
      if (tid == 947) pqn = question[b * S_ + min(t + 4, S_ - 1)];
    }

    // ---- S1: fused gh1+GRU1 (grp<100) | gh2 (grp<200) | og s>=1 (grp<250) ----
    if (grp < 200) {
      const bool g1 = (grp < 100);
      const int j = g1 ? grp : (grp - 100);
      const int s0 = g1 ? j : (300 + j);
      uint4 w0[4], w1[4], w2[4];
      {
        const uint4* p0 = wimg + (size_t)s0 * 16 + sub * 4;
        const uint4* p1 = wimg + (size_t)(s0 + 100) * 16 + sub * 4;
        const uint4* p2 = wimg + (size_t)(s0 + 200) * 16 + sub * 4;
#pragma unroll
        for (int c = 0; c < 4; ++c) { w0[c] = p0[c]; w1[c] = p1[c]; w2[c] = p2[c]; }
      }
      float hr[32];
#pragma unroll
      for (int c = 25; c < 32; ++c) hr[c] = 0.f;
      const int off = g1 ? 0 : 100;
#pragma unroll
      for (int c = 0; c < 25; ++c) hr[c] = hcomb[off + sub * 25 + c];
      float a0 = bf16_dot32(w0, hr);
      float a1 = bf16_dot32(w1, hr);
      float a2 = bf16_dot32(w2, hr);
      a0 += __shfl_xor(a0, 1); a0 += __shfl_xor(a0, 2);
      a1 += __shfl_xor(a1, 1); a1 += __shfl_xor(a1, 2);
      a2 += __shfl_xor(a2, 1); a2 += __shfl_xor(a2, 2);
      if (sub == 0) {
        if (g1) {
          float g0 = a0 + bresS[j], gg1 = a1 + bresS[100 + j], gg2 = a2 + bresS[200 + j];
          float rg = sigmf(gi1d[cur][j] + g0);
          float z  = sigmf(gi1d[cur][100 + j] + gg1);
          float n  = tanhf(gi1d[cur][200 + j] + rg * gg2);
          h1n[j] = (1.f - z) * n + z * hcomb[j];
        } else {
          gh2[j]       = a0 + bresS[300 + j];
          gh2[100 + j] = a1 + bresS[400 + j];
          gh2[200 + j] = a2 + bresS[500 + j];
        }
      }
    } else if (grp < 250) {
      int d = grp - 200;  // 0..49
      int s = 1 + d / 5, q = d % 5;
      bool valid = (t > RK_) || (s - 1 < t);
      float a = 0.f;
      if (valid) {
        int idx = (t > RK_) ? topd[cur][s - 1] : (s - 1);
        const float* qcr = &qcd[cur][q * 100 + sub * 25];
        const float* hrow = &g2hist[idx * 100 + sub * 25];
#pragma unroll
        for (int c = 0; c < 25; ++c) a = fmaf(qcr[c], hrow[c], a);
      }
      a += __shfl_xor(a, 1);
      a += __shfl_xor(a, 2);
      if (sub == 0) ogs[cur][s * 5 + q] = a;
    }
    __syncthreads();  // b1: h1n, gh2, ogs[cur][5..54] visible

    // ---- S3: fused gi2+GRU2 -> g2v (grp<100) | h1 copy (tid 400-499) ----
    if (grp < 100) {
      const int j = grp;
      uint4 w0[4], w1[4], w2[4];
      {
        const uint4* p0 = wimg + (size_t)(1024 + j) * 16 + sub * 4;
        const uint4* p1 = wimg + (size_t)(1124 + j) * 16 + sub * 4;
        const uint4* p2 = wimg + (size_t)(1224 + j) * 16 + sub * 4;
#pragma unroll
        for (int c = 0; c < 4; ++c) { w0[c] = p0[c]; w1[c] = p1[c]; w2[c] = p2[c]; }
      }
      float hr[32];
#pragma unroll
      for (int c = 25; c < 32; ++c) hr[c] = 0.f;
#pragma unroll
      for (int c = 0; c < 25; ++c) hr[c] = h1n[sub * 25 + c];
      float a0 = bf16_dot32(w0, hr);
      float a1 = bf16_dot32(w1, hr);
      float a2 = bf16_dot32(w2, hr);
      a0 += __shfl_xor(a0, 1); a0 += __shfl_xor(a0, 2);
      a1 += __shfl_xor(a1, 1); a1 += __shfl_xor(a1, 2);
      a2 += __shfl_xor(a2, 1); a2 += __shfl_xor(a2, 2);
      if (sub == 0) {
        float i_r = a0 + bresS[1024 + j], i_z = a1 + bresS[1124 + j], i_n = a2 + bresS[1224 + j];
        float rg = sigmf(i_r + gh2[j]);
        float z  = sigmf(i_z + gh2[100 + j]);
        float n  = tanhf(i_n + rg * gh2[200 + j]);
        g2v[j] = (1.f - z) * n + z * hcomb[100 + j];
      }
    } else if (tid >= 400 && tid < 500) {
      hcomb[tid - 400] = h1n[tid - 400];  // h1 <- h1n (h1n visible after b1)
    }
    __syncthreads();  // b2: g2v visible

    // ---- S5: kq (grp<100) | og s=0 (grp<105) | commits + h2/g2hist (tid>=424) ----
    if (grp < 100) {
      float hr[32];
#pragma unroll
      for (int c = 25; c < 32; ++c) hr[c] = 0.f;
#pragma unroll
      for (int c = 0; c < 25; ++c) hr[c] = g2v[sub * 25 + c];
      uint4 wc[4];
      {
        const uint4* wp = wimg + (size_t)(1536 + grp) * 16 + sub * 4;
#pragma unroll
        for (int c = 0; c < 4; ++c) wc[c] = wp[c];
      }
      float a = bf16_dot32(wc, hr);
      a += __shfl_xor(a, 1);
      a += __shfl_xor(a, 2);
      if (sub == 0) kqs[grp] = tanhf(a + bresS[1536 + grp]) * wkS[grp];
    } else if (grp < 105) {
      int q = grp - 100;
      const float* qcr = &qcd[cur][q * 100 + sub * 25];
      float a = 0.f;
#pragma unroll
      for (int c = 0; c < 25; ++c) a = fmaf(qcr[c], g2v[sub * 25 + c], a);
      a += __shfl_xor(a, 1);
      a += __shfl_xor(a, 2);
      if (sub == 0) ogs[cur][q] = a;
    }
    if (ptid >= 0) {
      if (pf) {
        if (ptid < 500) qcd[nxt][ptid] = pqc;
        if (ptid < 300) gi1d[nxt][ptid] = pgi;
        if (tid >= 924 && tid < 929) qwd[nxt][tid - 924] = pqw;
        if (tid >= 929 && tid < 939 && (t + 1) > RK_) topd[nxt][tid - 929] = min(T_ - 1, max(0, ptop));
        if (tid >= 939 && tid < 947 && (t + 2) < T_) cidS[tid - 939] = pci;
        if (tid == 947) { qn1S = qn2; qnS = pqn; }
      }
      if (t > 0 && ptid < 100) {
        hcomb[100 + ptid] = g2v[ptid];
        g2hist[t * 100 + ptid] = g2v[ptid];
      }
    }
    __syncthreads();  // b3: kqs, ogs, commits, state updates visible

    // ---- S6: wave-0 kw reduce + softmax + store (no trailing barrier) ----
    if (tid < 64) {
      float v = (tid < 50) ? (kqs[tid] + kqs[tid + 50]) : 0.f;
      v += __shfl_xor(v, 1);
      v += __shfl_xor(v, 2);
      v += __shfl_xor(v, 4);
      v += __shfl_xor(v, 8);
      v += __shfl_xor(v, 16);
      v += __shfl_xor(v, 32);
      const float kw = v;  // all 64 lanes
      float pq = 0.f;
      if (tid < 5) {
        const float qw = qwd[cur][tid];
        float tmp[11];
        float m = -__builtin_inff();
#pragma unroll
        for (int s = 0; s < 11; ++s) {
          float kws;
          bool valid;
          if (s == 0) { kws = kw; valid = true; }
          else if (t > RK_) { kws = kwhist[topd[cur][s - 1]]; valid = true; }
          else { valid = (s - 1 < t); kws = kwhist[s - 1]; }
          float tv = valid ? (qw + kws + bWv) : NEGV;
          tmp[s] = tv;
          m = fmaxf(m, tv);
        }
        float den = 0.f, num = 0.f;
#pragma unroll
        for (int s = 0; s < 11; ++s) {
          float e = expf(tmp[s] - m);
          den += e;
          num += e * ogs[cur][s * 5 + tid];
        }
        pq = num / den;
      }
      if (tid == 5 && t > 0) kwhist[t] = kw;  // read only by wave 0 (program order)
      float sp = pq;
      sp += __shfl_xor(sp, 1);
      sp += __shfl_xor(sp, 2);
      sp += __shfl_xor(sp, 4);
      if (tid == 0) {
        int col = (t == 0) ? 0 : (t + 1);
        out[b * S_ + col] = sp;
        if (t == 0) out[b * S_ + 1] = 0.f;  // col 1 never written by ref
      }
    }
    // no barrier: next step's S1 writes (h1n/gh2/ogs[nxt]) are race-free vs S6
    // (ogs parity-dbuf; kqs/qwd/topd[cur]/kwhist only touched by wave 0 or
    //  behind next step's b2 which requires wave 0 to pass b1 first)
  }
}

// ---------------------------------------------------------------------------
extern "C" void kernel_launch(void* const* d_in, const int* in_sizes, int n_in,
                              void* d_out, int out_size, void* d_ws, size_t ws_size,
                              hipStream_t stream)
{
  (void)in_sizes; (void)n_in; (void)out_size; (void)ws_size;
  const float* Eq     = (const float*)d_in[0];
  const float* Ec     = (const float*)d_in[1];
  const float* Er     = (const float*)d_in[2];
  const float* W_ih1  = (const float*)d_in[3];
  const float* W_hh1  = (const float*)d_in[4];
  const float* b_ih1  = (const float*)d_in[5];
  const float* b_hh1  = (const float*)d_in[6];
  const float* W_ih2  = (const float*)d_in[7];
  const float* W_hh2  = (const float*)d_in[8];
  const float* b_ih2  = (const float*)d_in[9];
  const float* b_hh2  = (const float*)d_in[10];
  const float* Wagg   = (const float*)d_in[11];
  const float* bagg   = (const float*)d_in[12];
  const float* W_last = (const float*)d_in[13];
  const float* b_last = (const float*)d_in[14];
  const float* W_query= (const float*)d_in[15];
  const float* b_query= (const float*)d_in[16];
  const float* W_key  = (const float*)d_in[17];
  const float* b_key  = (const float*)d_in[18];
  const float* W_W    = (const float*)d_in[19];
  const float* b_W    = (const float*)d_in[20];
  const float* h1_init= (const float*)d_in[21];
  const float* h2_init= (const float*)d_in[22];
  const int* question = (const int*)d_in[23];
  const int* response = (const int*)d_in[24];
  const int* mask     = (const int*)d_in[25];
  const int* qnb      = (const int*)d_in[26];
  const int* snb      = (const int*)d_in[27];
  const int* cidx     = (const int*)d_in[28];
  const int* cmask    = (const int*)d_in[29];
  float* out = (float*)d_out;

  char* ws = (char*)d_ws;
  size_t off = 0;
  auto alloc = [&](size_t bytes) -> void* {
    void* p = ws + off;
    off += (bytes + 255) & ~(size_t)255;
    return p;
  };
  float* wih1aT = (float*)alloc(30000 * 4);
  float* erw    = (float*)alloc(600 * 4);
  float* waggT  = (float*)alloc(30000 * 4);
  float* wlastT = (float*)alloc(10000 * 4);
  float* wkeyT  = (float*)alloc(10000 * 4);
  float* scal   = (float*)alloc(4);
  u32*   wcat16 = (u32*)alloc(114688 * 4);
  float* bcat   = (float*)alloc(1792 * 4);
  float* gi1_all = (float*)alloc((size_t)B_ * T_ * 300 * 4);
  float* qw_all  = (float*)alloc((size_t)B_ * T_ * 5 * 4);
  int*   top10   = (int*)alloc((size_t)B_ * T_ * 10 * 4);

  hipLaunchKernelGGL(setupk, dim3(128), dim3(256), 0, stream,
      Er, W_ih1, b_ih1, Wagg, W_last, W_key, b_query, W_W, W_query,
      W_hh1, W_hh2, W_ih2, b_hh1, b_hh2, b_ih2,
      wih1aT, erw, waggT, wlastT, wkeyT, scal, wcat16, bcat);

  hipLaunchKernelGGL(phaseA, dim3(T_, B_), dim3(256), 0, stream,
      Eq, Ec, question, response, mask, qnb, snb,
      wih1aT, erw, waggT, wlastT, bagg, b_last, gi1_all);

  hipLaunchKernelGGL(phaseB, dim3(T_, B_), dim3(128), 0, stream,
      Eq, Ec, question, cidx, cmask, wkeyT, b_key, W_W,
      qw_all, top10);

  hipLaunchKernelGGL(seqk, dim3(B_), dim3(1024), 0, stream,
      wcat16, bcat, gi1_all, qw_all, top10, W_W, b_W,
      Eq, Ec, question, cidx, cmask,
      h1_init, h2_init, scal, out);
}